// Round 1
// baseline (867.185 us; speedup 1.0000x reference)
//
#include <hip/hip_runtime.h>
#include <hip/hip_bf16.h>
#include <math.h>

#define SLOPE 0.2f

static __device__ __forceinline__ float lrelu(float v) { return v > 0.f ? v : SLOPE * v; }

// ---------------- CSR build (dst-sorted edge list, self loops appended) ----------------

__global__ void count_kernel(const int* __restrict__ ei, int* __restrict__ cnt, int E, int N) {
  int i = blockIdx.x * blockDim.x + threadIdx.x;
  int ET = E + N;
  if (i >= ET) return;
  int d = (i < E) ? ei[E + i] : (i - E);
  atomicAdd(&cnt[d], 1);
}

__global__ void scan_kernel(int* __restrict__ rowptr, int* __restrict__ cursor, int N) {
  __shared__ int sums[1024];
  int tid = threadIdx.x;
  int chunk = (N + 1023) >> 10;
  int beg = tid * chunk;
  int end = beg + chunk; if (end > N) end = N;
  int s = 0;
  for (int i = beg; i < end; ++i) s += rowptr[i];
  sums[tid] = s;
  __syncthreads();
  for (int off = 1; off < 1024; off <<= 1) {
    int add = (tid >= off) ? sums[tid - off] : 0;
    __syncthreads();
    sums[tid] += add;
    __syncthreads();
  }
  int run = sums[tid] - s;  // exclusive prefix of this thread's chunk
  for (int i = beg; i < end; ++i) {
    int c = rowptr[i];
    rowptr[i] = run;
    cursor[i] = run;
    run += c;
  }
  if (tid == 1023) rowptr[N] = sums[1023];
}

__global__ void scatter_kernel(const int* __restrict__ ei, int* __restrict__ cursor,
                               int* __restrict__ esrc, int* __restrict__ edst, int E, int N) {
  int i = blockIdx.x * blockDim.x + threadIdx.x;
  int ET = E + N;
  if (i >= ET) return;
  int s, d;
  if (i < E) { s = ei[i]; d = ei[E + i]; } else { s = i - E; d = i - E; }
  int pos = atomicAdd(&cursor[d], 1);
  esrc[pos] = s;
  edst[pos] = d;
}

// ---------------- GEMM: H[N,OC] = X[N,128] @ W[128,OC] ----------------
// One block per 16 rows; X loads are block-uniform (scalarizable), W loads coalesced.

template<int OC>
__global__ __launch_bounds__(OC) void gemm_kernel(const float* __restrict__ X,
                                                  const float* __restrict__ W,
                                                  float* __restrict__ H, int N) {
  const int K = 128;
  const int ROWS = 16;
  int tid = threadIdx.x;
  long n0 = (long)blockIdx.x * ROWS;
  float acc[ROWS];
#pragma unroll
  for (int r = 0; r < ROWS; ++r) acc[r] = 0.f;
  const float* Xb = X + n0 * K;
  for (int k4 = 0; k4 < K / 4; ++k4) {
    float w0 = W[(k4 * 4 + 0) * OC + tid];
    float w1 = W[(k4 * 4 + 1) * OC + tid];
    float w2 = W[(k4 * 4 + 2) * OC + tid];
    float w3 = W[(k4 * 4 + 3) * OC + tid];
#pragma unroll
    for (int r = 0; r < ROWS; ++r) {
      float4 xv = *(const float4*)(Xb + r * K + k4 * 4);
      acc[r] = fmaf(xv.x, w0, acc[r]);
      acc[r] = fmaf(xv.y, w1, acc[r]);
      acc[r] = fmaf(xv.z, w2, acc[r]);
      acc[r] = fmaf(xv.w, w3, acc[r]);
    }
  }
#pragma unroll
  for (int r = 0; r < ROWS; ++r) H[(n0 + r) * OC + tid] = acc[r];
}

// ---------------- attention coefficients per node ----------------

// 4 heads of 32: als[n,h] = dot(h[n, h*32:(h+1)*32], a_s[h]); same for ald.
__global__ void al_kernel4(const float* __restrict__ h, const float* __restrict__ a_s,
                           const float* __restrict__ a_d, float* __restrict__ als,
                           float* __restrict__ ald) {
  int tid = threadIdx.x;                  // 0..255, 2 nodes per block
  int n = blockIdx.x * 2 + (tid >> 7);
  int c = tid & 127;
  int hd = c >> 5, l = c & 31;
  float hv = h[(long)n * 128 + c];
  float vs = hv * a_s[hd * 32 + l];
  float vd = hv * a_d[hd * 32 + l];
#pragma unroll
  for (int off = 16; off >= 1; off >>= 1) {
    vs += __shfl_xor(vs, off);
    vd += __shfl_xor(vd, off);
  }
  if (l == 0) { als[n * 4 + hd] = vs; ald[n * 4 + hd] = vd; }
}

// single head of 64
__global__ void al_kernel1(const float* __restrict__ h, const float* __restrict__ a_s,
                           const float* __restrict__ a_d, float* __restrict__ als,
                           float* __restrict__ ald) {
  int tid = threadIdx.x;                  // 0..255, 4 nodes per block
  int n = blockIdx.x * 4 + (tid >> 6);
  int l = tid & 63;
  float hv = h[(long)n * 64 + l];
  float vs = hv * a_s[l];
  float vd = hv * a_d[l];
#pragma unroll
  for (int off = 32; off >= 1; off >>= 1) {
    vs += __shfl_xor(vs, off);
    vd += __shfl_xor(vd, off);
  }
  if (l == 0) { als[n] = vs; ald[n] = vd; }
}

// ---------------- per-edge attention logits (CSR order) ----------------

__global__ void edge_att4(const int* __restrict__ esrc, const int* __restrict__ edst,
                          const float* __restrict__ als, const float* __restrict__ ald,
                          float* __restrict__ ev, int ET) {
  int i = blockIdx.x * blockDim.x + threadIdx.x;
  if (i >= ET) return;
  int s = esrc[i], d = edst[i];
  float4 a = *(const float4*)(als + (long)s * 4);
  float4 b = *(const float4*)(ald + (long)d * 4);
  float4 o;
  o.x = lrelu(a.x + b.x);
  o.y = lrelu(a.y + b.y);
  o.z = lrelu(a.z + b.z);
  o.w = lrelu(a.w + b.w);
  *(float4*)(ev + (long)i * 4) = o;
}

__global__ void edge_att1(const int* __restrict__ esrc, const int* __restrict__ edst,
                          const float* __restrict__ als, const float* __restrict__ ald,
                          float* __restrict__ ev, int ET) {
  int i = blockIdx.x * blockDim.x + threadIdx.x;
  if (i >= ET) return;
  ev[i] = lrelu(als[esrc[i]] + ald[edst[i]]);
}

// ---------------- per-node softmax + weighted aggregation ----------------

// 4 heads x 32 feats, block = 128 threads = one dst node; fused +bias + relu
__global__ void aggregate128(const float* __restrict__ h, const float* __restrict__ ev,
                             const int* __restrict__ rowptr, const int* __restrict__ esrc,
                             const float* __restrict__ bias, float* __restrict__ out) {
  int n = blockIdx.x;
  int tid = threadIdx.x;     // 0..127
  int hd = tid >> 5;
  int beg = rowptr[n], end = rowptr[n + 1];
  float m = -1e30f;
  for (int e = beg; e < end; ++e) m = fmaxf(m, ev[(long)e * 4 + hd]);
  float den = 0.f, acc = 0.f;
  for (int e = beg; e < end; ++e) {
    float w = __expf(ev[(long)e * 4 + hd] - m);
    den += w;
    int s = esrc[e];
    acc = fmaf(h[(long)s * 128 + tid], w, acc);
  }
  float o = acc / den + bias[tid];
  out[(long)n * 128 + tid] = fmaxf(o, 0.f);   // both layers 1 and 2 have ReLU after
}

// 1 head x 64 feats, block = 64 threads = one dst node; fused +bias + log_softmax
__global__ void aggregate64_lsm(const float* __restrict__ h, const float* __restrict__ ev,
                                const int* __restrict__ rowptr, const int* __restrict__ esrc,
                                const float* __restrict__ bias, float* __restrict__ out) {
  int n = blockIdx.x;
  int tid = threadIdx.x;     // 0..63
  int beg = rowptr[n], end = rowptr[n + 1];
  float m = -1e30f;
  for (int e = beg; e < end; ++e) m = fmaxf(m, ev[e]);
  float den = 0.f, acc = 0.f;
  for (int e = beg; e < end; ++e) {
    float w = __expf(ev[e] - m);
    den += w;
    int s = esrc[e];
    acc = fmaf(h[(long)s * 64 + tid], w, acc);
  }
  float val = acc / den + bias[tid];
  // log_softmax over the 64 lanes (= 64 classes)
  float mx = val;
#pragma unroll
  for (int off = 32; off >= 1; off >>= 1) mx = fmaxf(mx, __shfl_xor(mx, off));
  float ex = __expf(val - mx);
  float sum = ex;
#pragma unroll
  for (int off = 32; off >= 1; off >>= 1) sum += __shfl_xor(sum, off);
  out[(long)n * 64 + tid] = val - mx - __logf(sum);
}

// ---------------- launch ----------------

extern "C" void kernel_launch(void* const* d_in, const int* in_sizes, int n_in,
                              void* d_out, int out_size, void* d_ws, size_t ws_size,
                              hipStream_t stream) {
  const float* x   = (const float*)d_in[0];
  const int*   ei  = (const int*)d_in[1];
  const float* w1  = (const float*)d_in[2];
  const float* as1 = (const float*)d_in[3];
  const float* ad1 = (const float*)d_in[4];
  const float* b1  = (const float*)d_in[5];
  const float* w2  = (const float*)d_in[6];
  const float* as2 = (const float*)d_in[7];
  const float* ad2 = (const float*)d_in[8];
  const float* b2  = (const float*)d_in[9];
  const float* w3  = (const float*)d_in[10];
  const float* as3 = (const float*)d_in[11];
  const float* ad3 = (const float*)d_in[12];
  const float* b3  = (const float*)d_in[13];
  float* out = (float*)d_out;

  const int N = in_sizes[0] / 128;
  const int E = in_sizes[1] / 2;
  const int ET = E + N;

  char* ws = (char*)d_ws;
  size_t off = 0;
  auto alloc = [&](size_t bytes) -> void* {
    void* p = ws + off;
    off += (bytes + 255) & ~(size_t)255;
    return p;
  };
  float* bufA  = (float*)alloc((size_t)N * 128 * 4);
  float* bufB  = (float*)alloc((size_t)N * 128 * 4);
  float* als   = (float*)alloc((size_t)N * 4 * 4);
  float* ald   = (float*)alloc((size_t)N * 4 * 4);
  float* ev    = (float*)alloc((size_t)ET * 4 * 4);
  int* rowptr  = (int*)alloc((size_t)(N + 1) * 4);
  int* cursor  = (int*)alloc((size_t)N * 4);
  int* esrc    = (int*)alloc((size_t)ET * 4);
  int* edst    = (int*)alloc((size_t)ET * 4);

  const int tpb = 256;
  const int egrid = (ET + tpb - 1) / tpb;

  // CSR build (once per launch; edge_index identical for all 3 layers)
  hipMemsetAsync(rowptr, 0, (size_t)(N + 1) * 4, stream);
  count_kernel<<<egrid, tpb, 0, stream>>>(ei, rowptr, E, N);
  scan_kernel<<<1, 1024, 0, stream>>>(rowptr, cursor, N);
  scatter_kernel<<<egrid, tpb, 0, stream>>>(ei, cursor, esrc, edst, E, N);

  // ---- layer 1: x[N,128] -> bufB[N,128] ----
  gemm_kernel<128><<<N / 16, 128, 0, stream>>>(x, w1, bufA, N);
  al_kernel4<<<N / 2, 256, 0, stream>>>(bufA, as1, ad1, als, ald);
  edge_att4<<<egrid, tpb, 0, stream>>>(esrc, edst, als, ald, ev, ET);
  aggregate128<<<N, 128, 0, stream>>>(bufA, ev, rowptr, esrc, b1, bufB);

  // ---- layer 2: bufB -> bufB (via bufA) ----
  gemm_kernel<128><<<N / 16, 128, 0, stream>>>(bufB, w2, bufA, N);
  al_kernel4<<<N / 2, 256, 0, stream>>>(bufA, as2, ad2, als, ald);
  edge_att4<<<egrid, tpb, 0, stream>>>(esrc, edst, als, ald, ev, ET);
  aggregate128<<<N, 128, 0, stream>>>(bufA, ev, rowptr, esrc, b2, bufB);

  // ---- layer 3: bufB[N,128] -> out[N,64] ----
  gemm_kernel<64><<<N / 16, 64, 0, stream>>>(bufB, w3, bufA, N);
  al_kernel1<<<N / 4, 256, 0, stream>>>(bufA, as3, ad3, als, ald);
  edge_att1<<<egrid, tpb, 0, stream>>>(esrc, edst, als, ald, ev, ET);
  aggregate64_lsm<<<N, 64, 0, stream>>>(bufA, ev, rowptr, esrc, b3, out);
}

// Round 3
// 563.752 us; speedup vs baseline: 1.5382x; 1.5382x over previous
//
#include <hip/hip_runtime.h>
#include <hip/hip_bf16.h>
#include <math.h>

#define SLOPE 0.2f

static __device__ __forceinline__ float lrelu(float v) { return v > 0.f ? v : SLOPE * v; }

// ---------------- CSR build (dst-sorted edge list, self loops appended) ----------------

__global__ void count_kernel(const int* __restrict__ ei, int* __restrict__ cnt, int E, int N) {
  int i = blockIdx.x * blockDim.x + threadIdx.x;
  int ET = E + N;
  if (i >= ET) return;
  int d = (i < E) ? ei[E + i] : (i - E);
  atomicAdd(&cnt[d], 1);
}

__global__ void scan_kernel(int* __restrict__ rowptr, int* __restrict__ cursor, int N) {
  __shared__ int sums[1024];
  int tid = threadIdx.x;
  int chunk = (N + 1023) >> 10;
  int beg = tid * chunk;
  int end = beg + chunk; if (end > N) end = N;
  int s = 0;
  for (int i = beg; i < end; ++i) s += rowptr[i];
  sums[tid] = s;
  __syncthreads();
  for (int off = 1; off < 1024; off <<= 1) {
    int add = (tid >= off) ? sums[tid - off] : 0;
    __syncthreads();
    sums[tid] += add;
    __syncthreads();
  }
  int run = sums[tid] - s;  // exclusive prefix of this thread's chunk
  for (int i = beg; i < end; ++i) {
    int c = rowptr[i];
    rowptr[i] = run;
    cursor[i] = run;
    run += c;
  }
  if (tid == 1023) rowptr[N] = sums[1023];
}

__global__ void scatter_kernel(const int* __restrict__ ei, int* __restrict__ cursor,
                               int* __restrict__ esrc, int E, int N) {
  int i = blockIdx.x * blockDim.x + threadIdx.x;
  int ET = E + N;
  if (i >= ET) return;
  int s, d;
  if (i < E) { s = ei[i]; d = ei[E + i]; } else { s = i - E; d = i - E; }
  int pos = atomicAdd(&cursor[d], 1);
  esrc[pos] = s;
}

// ---------------- GEMM: H[N,OC] = X[N,128] @ W[128,OC] ----------------
// Block = 256 threads computes a 64-row x OC-col tile. X tile staged transposed
// in LDS (stride 68 -> conflict-free, b128-aligned). Per thread: RPT rows x 4 cols.

template<int OC>
__global__ __launch_bounds__(256) void gemm_tile(const float* __restrict__ X,
                                                 const float* __restrict__ W,
                                                 float* __restrict__ H, int N) {
  const int K = 128;
  const int CT = OC / 4;             // col-threads: 32 (OC=128) / 16 (OC=64)
  const int RPT = 64 / (256 / CT);   // rows per thread: 8 / 4
  __shared__ float xs[K][68];
  int tid = threadIdx.x;
  long row0 = (long)blockIdx.x * 64;
#pragma unroll
  for (int i = 0; i < 8; ++i) {
    int flat = i * 256 + tid;        // float4 index in 64x128 tile
    int r = flat >> 5;
    int kc = flat & 31;
    long row = row0 + r;
    long rr = row < N ? row : (long)(N - 1);
    float4 xv = *(const float4*)(X + rr * K + kc * 4);
    xs[kc * 4 + 0][r] = xv.x;
    xs[kc * 4 + 1][r] = xv.y;
    xs[kc * 4 + 2][r] = xv.z;
    xs[kc * 4 + 3][r] = xv.w;
  }
  __syncthreads();
  int ct = tid % CT;
  int rg = tid / CT;
  int c0 = ct * 4;
  int r0 = rg * RPT;
  float acc[RPT][4];
#pragma unroll
  for (int i = 0; i < RPT; ++i)
    for (int j = 0; j < 4; ++j) acc[i][j] = 0.f;
#pragma unroll 4
  for (int k = 0; k < K; ++k) {
    float4 wv = *(const float4*)(W + (long)k * OC + c0);
    const float4* xr = (const float4*)(&xs[k][r0]);
#pragma unroll
    for (int i4 = 0; i4 < RPT / 4; ++i4) {
      float4 xv = xr[i4];
      float xa[4] = {xv.x, xv.y, xv.z, xv.w};
#pragma unroll
      for (int j = 0; j < 4; ++j) {
        int i = i4 * 4 + j;
        acc[i][0] = fmaf(xa[j], wv.x, acc[i][0]);
        acc[i][1] = fmaf(xa[j], wv.y, acc[i][1]);
        acc[i][2] = fmaf(xa[j], wv.z, acc[i][2]);
        acc[i][3] = fmaf(xa[j], wv.w, acc[i][3]);
      }
    }
  }
#pragma unroll
  for (int i = 0; i < RPT; ++i) {
    long row = row0 + r0 + i;
    if (row < N) {
      float4 o = {acc[i][0], acc[i][1], acc[i][2], acc[i][3]};
      *(float4*)(H + row * OC + c0) = o;
    }
  }
}

// ---------------- attention coefficients per node ----------------

// 4 heads x 32: block 256 = 8 nodes x 32 lanes, float4 loads, shuffle reduce.
__global__ void al_kernel4(const float* __restrict__ h, const float* __restrict__ a_s,
                           const float* __restrict__ a_d, float* __restrict__ als,
                           float* __restrict__ ald, int N) {
  int tid = threadIdx.x;
  int n = blockIdx.x * 8 + (tid >> 5);
  int sl = tid & 31, hd = sl >> 3;
  if (n >= N) return;
  float4 hv = *(const float4*)(h + (long)n * 128 + sl * 4);
  float4 sv = *(const float4*)(a_s + hd * 32 + (sl & 7) * 4);
  float4 dv = *(const float4*)(a_d + hd * 32 + (sl & 7) * 4);
  float vs = hv.x * sv.x + hv.y * sv.y + hv.z * sv.z + hv.w * sv.w;
  float vd = hv.x * dv.x + hv.y * dv.y + hv.z * dv.z + hv.w * dv.w;
#pragma unroll
  for (int off = 1; off <= 4; off <<= 1) {
    vs += __shfl_xor(vs, off);
    vd += __shfl_xor(vd, off);
  }
  if ((sl & 7) == 0) { als[(long)n * 4 + hd] = vs; ald[(long)n * 4 + hd] = vd; }
}

// single head of 64: block 256 = 16 nodes x 16 lanes
__global__ void al_kernel1(const float* __restrict__ h, const float* __restrict__ a_s,
                           const float* __restrict__ a_d, float* __restrict__ als,
                           float* __restrict__ ald, int N) {
  int tid = threadIdx.x;
  int n = blockIdx.x * 16 + (tid >> 4);
  int sl = tid & 15;
  if (n >= N) return;
  float4 hv = *(const float4*)(h + (long)n * 64 + sl * 4);
  float4 sv = *(const float4*)(a_s + sl * 4);
  float4 dv = *(const float4*)(a_d + sl * 4);
  float vs = hv.x * sv.x + hv.y * sv.y + hv.z * sv.z + hv.w * sv.w;
  float vd = hv.x * dv.x + hv.y * dv.y + hv.z * dv.z + hv.w * dv.w;
#pragma unroll
  for (int off = 1; off <= 8; off <<= 1) {
    vs += __shfl_xor(vs, off);
    vd += __shfl_xor(vd, off);
  }
  if (sl == 0) { als[n] = vs; ald[n] = vd; }
}

// ---------------- fused single-pass aggregation (online softmax) ----------------

// 4 heads x 32 feats. Block 128 = 4 edge-slots x 32 lanes; each slot gathers a
// full 512B h[src] row per edge (float4/lane). Online softmax per slot, then
// LDS combine across slots. Fused +bias +relu.
__global__ __launch_bounds__(128) void gat_agg128(const float* __restrict__ h,
    const float* __restrict__ als, const float* __restrict__ ald,
    const int* __restrict__ rowptr, const int* __restrict__ esrc,
    const float* __restrict__ bias, float* __restrict__ out) {
  int n = blockIdx.x;
  int tid = threadIdx.x;
  int slot = tid >> 5, sl = tid & 31, hd = sl >> 3;
  int beg = rowptr[n], end = rowptr[n + 1];
  float aldv = ald[(long)n * 4 + hd];
  float m = -1e30f, den = 0.f;
  float4 acc = {0.f, 0.f, 0.f, 0.f};

  int e = beg + slot;
  int s = 0; float alv = 0.f; float4 hv = {0.f, 0.f, 0.f, 0.f};
  if (e < end) {
    s = esrc[e];
    alv = als[(long)s * 4 + hd];
    hv = *(const float4*)(h + (long)s * 128 + sl * 4);
  }
  while (e < end) {
    int en = e + 4;
    int sn = 0; float alvn = 0.f; float4 hvn = {0.f, 0.f, 0.f, 0.f};
    if (en < end) {
      sn = esrc[en];
      alvn = als[(long)sn * 4 + hd];
      hvn = *(const float4*)(h + (long)sn * 128 + sl * 4);
    }
    float el = lrelu(alv + aldv);
    float mn = fmaxf(m, el);
    float c = __expf(m - mn);
    float p = __expf(el - mn);
    den = fmaf(den, c, p);
    acc.x = fmaf(acc.x, c, p * hv.x);
    acc.y = fmaf(acc.y, c, p * hv.y);
    acc.z = fmaf(acc.z, c, p * hv.z);
    acc.w = fmaf(acc.w, c, p * hv.w);
    m = mn;
    e = en; alv = alvn; hv = hvn;
  }

  __shared__ float sacc[4][32][4];
  __shared__ float smx[4][4], sden[4][4];
  *(float4*)&sacc[slot][sl][0] = acc;
  if ((sl & 7) == 0) { smx[slot][hd] = m; sden[slot][hd] = den; }
  __syncthreads();
  if (tid < 32) {
    int hh = tid >> 3;
    float mg = fmaxf(fmaxf(smx[0][hh], smx[1][hh]), fmaxf(smx[2][hh], smx[3][hh]));
    float d = 0.f;
    float4 a = {0.f, 0.f, 0.f, 0.f};
#pragma unroll
    for (int s2 = 0; s2 < 4; ++s2) {
      float c = __expf(smx[s2][hh] - mg);
      d = fmaf(sden[s2][hh], c, d);
      a.x = fmaf(sacc[s2][tid][0], c, a.x);
      a.y = fmaf(sacc[s2][tid][1], c, a.y);
      a.z = fmaf(sacc[s2][tid][2], c, a.z);
      a.w = fmaf(sacc[s2][tid][3], c, a.w);
    }
    float inv = 1.f / d;
    float4 bv = *(const float4*)(bias + tid * 4);
    float4 o;
    o.x = fmaxf(fmaf(a.x, inv, bv.x), 0.f);
    o.y = fmaxf(fmaf(a.y, inv, bv.y), 0.f);
    o.z = fmaxf(fmaf(a.z, inv, bv.z), 0.f);
    o.w = fmaxf(fmaf(a.w, inv, bv.w), 0.f);
    *(float4*)(out + (long)n * 128 + tid * 4) = o;
  }
}

// 1 head x 64 feats. Block 64 = 1 wave = 4 slots x 16 lanes; shuffle combine;
// fused +bias + log_softmax over the 64 classes.
__global__ __launch_bounds__(64) void gat_agg64_lsm(const float* __restrict__ h,
    const float* __restrict__ als, const float* __restrict__ ald,
    const int* __restrict__ rowptr, const int* __restrict__ esrc,
    const float* __restrict__ bias, float* __restrict__ out) {
  int n = blockIdx.x;
  int tid = threadIdx.x;
  int slot = tid >> 4, sl = tid & 15;
  int beg = rowptr[n], end = rowptr[n + 1];
  float aldv = ald[n];
  float m = -1e30f, den = 0.f;
  float4 acc = {0.f, 0.f, 0.f, 0.f};

  int e = beg + slot;
  int s = 0; float alv = 0.f; float4 hv = {0.f, 0.f, 0.f, 0.f};
  if (e < end) {
    s = esrc[e];
    alv = als[s];
    hv = *(const float4*)(h + (long)s * 64 + sl * 4);
  }
  while (e < end) {
    int en = e + 4;
    int sn = 0; float alvn = 0.f; float4 hvn = {0.f, 0.f, 0.f, 0.f};
    if (en < end) {
      sn = esrc[en];
      alvn = als[sn];
      hvn = *(const float4*)(h + (long)sn * 64 + sl * 4);
    }
    float el = lrelu(alv + aldv);
    float mn = fmaxf(m, el);
    float c = __expf(m - mn);
    float p = __expf(el - mn);
    den = fmaf(den, c, p);
    acc.x = fmaf(acc.x, c, p * hv.x);
    acc.y = fmaf(acc.y, c, p * hv.y);
    acc.z = fmaf(acc.z, c, p * hv.z);
    acc.w = fmaf(acc.w, c, p * hv.w);
    m = mn;
    e = en; alv = alvn; hv = hvn;
  }

  // combine across the 4 slots (xor 16/32 preserves sl)
  float mg = m;
  mg = fmaxf(mg, __shfl_xor(mg, 16));
  mg = fmaxf(mg, __shfl_xor(mg, 32));
  float c = __expf(m - mg);
  den *= c; acc.x *= c; acc.y *= c; acc.z *= c; acc.w *= c;
  den += __shfl_xor(den, 16); den += __shfl_xor(den, 32);
  acc.x += __shfl_xor(acc.x, 16); acc.x += __shfl_xor(acc.x, 32);
  acc.y += __shfl_xor(acc.y, 16); acc.y += __shfl_xor(acc.y, 32);
  acc.z += __shfl_xor(acc.z, 16); acc.z += __shfl_xor(acc.z, 32);
  acc.w += __shfl_xor(acc.w, 16); acc.w += __shfl_xor(acc.w, 32);
  float inv = 1.f / den;
  float4 bv = *(const float4*)(bias + sl * 4);
  float v0 = fmaf(acc.x, inv, bv.x);
  float v1 = fmaf(acc.y, inv, bv.y);
  float v2 = fmaf(acc.z, inv, bv.z);
  float v3 = fmaf(acc.w, inv, bv.w);
  // log_softmax over 64 classes
  float lm = fmaxf(fmaxf(v0, v1), fmaxf(v2, v3));
#pragma unroll
  for (int off = 1; off <= 8; off <<= 1) lm = fmaxf(lm, __shfl_xor(lm, off));
  float es = __expf(v0 - lm) + __expf(v1 - lm) + __expf(v2 - lm) + __expf(v3 - lm);
#pragma unroll
  for (int off = 1; off <= 8; off <<= 1) es += __shfl_xor(es, off);
  float lse = lm + __logf(es);
  if (tid < 16) {
    float4 o = {v0 - lse, v1 - lse, v2 - lse, v3 - lse};
    *(float4*)(out + (long)n * 64 + sl * 4) = o;
  }
}

// ---------------- launch ----------------

extern "C" void kernel_launch(void* const* d_in, const int* in_sizes, int n_in,
                              void* d_out, int out_size, void* d_ws, size_t ws_size,
                              hipStream_t stream) {
  const float* x   = (const float*)d_in[0];
  const int*   ei  = (const int*)d_in[1];
  const float* w1  = (const float*)d_in[2];
  const float* as1 = (const float*)d_in[3];
  const float* ad1 = (const float*)d_in[4];
  const float* b1  = (const float*)d_in[5];
  const float* w2  = (const float*)d_in[6];
  const float* as2 = (const float*)d_in[7];
  const float* ad2 = (const float*)d_in[8];
  const float* b2  = (const float*)d_in[9];
  const float* w3  = (const float*)d_in[10];
  const float* as3 = (const float*)d_in[11];
  const float* ad3 = (const float*)d_in[12];
  const float* b3  = (const float*)d_in[13];
  float* out = (float*)d_out;

  const int N = in_sizes[0] / 128;
  const int E = in_sizes[1] / 2;
  const int ET = E + N;

  char* ws = (char*)d_ws;
  size_t off = 0;
  auto alloc = [&](size_t bytes) -> void* {
    void* p = ws + off;
    off += (bytes + 255) & ~(size_t)255;
    return p;
  };
  float* bufA  = (float*)alloc((size_t)N * 128 * 4);
  float* bufB  = (float*)alloc((size_t)N * 128 * 4);
  float* als   = (float*)alloc((size_t)N * 4 * 4);
  float* ald   = (float*)alloc((size_t)N * 4 * 4);
  int* rowptr  = (int*)alloc((size_t)(N + 1) * 4);
  int* cursor  = (int*)alloc((size_t)N * 4);
  int* esrc    = (int*)alloc((size_t)ET * 4);

  const int tpb = 256;
  const int egrid = (ET + tpb - 1) / tpb;
  const int ggrid = (N + 63) / 64;

  // CSR build (once per launch; edge_index identical for all 3 layers)
  hipMemsetAsync(rowptr, 0, (size_t)(N + 1) * 4, stream);
  count_kernel<<<egrid, tpb, 0, stream>>>(ei, rowptr, E, N);
  scan_kernel<<<1, 1024, 0, stream>>>(rowptr, cursor, N);
  scatter_kernel<<<egrid, tpb, 0, stream>>>(ei, cursor, esrc, E, N);

  // ---- layer 1: x[N,128] -> bufB[N,128] ----
  gemm_tile<128><<<ggrid, 256, 0, stream>>>(x, w1, bufA, N);
  al_kernel4<<<(N + 7) / 8, 256, 0, stream>>>(bufA, as1, ad1, als, ald, N);
  gat_agg128<<<N, 128, 0, stream>>>(bufA, als, ald, rowptr, esrc, b1, bufB);

  // ---- layer 2: bufB -> bufB (via bufA) ----
  gemm_tile<128><<<ggrid, 256, 0, stream>>>(bufB, w2, bufA, N);
  al_kernel4<<<(N + 7) / 8, 256, 0, stream>>>(bufA, as2, ad2, als, ald, N);
  gat_agg128<<<N, 128, 0, stream>>>(bufA, als, ald, rowptr, esrc, b2, bufB);

  // ---- layer 3: bufB[N,128] -> out[N,64] ----
  gemm_tile<64><<<ggrid, 256, 0, stream>>>(bufB, w3, bufA, N);
  al_kernel1<<<(N + 15) / 16, 256, 0, stream>>>(bufA, as3, ad3, als, ald, N);
  gat_agg64_lsm<<<N, 64, 0, stream>>>(bufA, als, ald, rowptr, esrc, b3, out);
}

// Round 4
// 461.792 us; speedup vs baseline: 1.8779x; 1.2208x over previous
//
#include <hip/hip_runtime.h>
#include <hip/hip_bf16.h>
#include <math.h>

#define SLOPE 0.2f

static __device__ __forceinline__ float lrelu(float v) { return v > 0.f ? v : SLOPE * v; }

// ---------------- CSR build (dst-sorted edge list, self loops appended) ----------------

__global__ void count_kernel(const int* __restrict__ ei, int* __restrict__ cnt, int E, int N) {
  int i = blockIdx.x * blockDim.x + threadIdx.x;
  int ET = E + N;
  if (i >= ET) return;
  int d = (i < E) ? ei[E + i] : (i - E);
  atomicAdd(&cnt[d], 1);
}

// ---- hierarchical exclusive scan of cnt[0..N-1] -> rowptr[0..N] ----
// Stage 1: 1024 elements per block (256 thr x int4). Partial exclusive scans
// into rowptr, block totals into bsum.
__global__ __launch_bounds__(256) void scan_blocks(const int* __restrict__ cnt,
                                                   int* __restrict__ rowptr,
                                                   int* __restrict__ bsum, int N) {
  int tid = threadIdx.x;
  int base = blockIdx.x * 1024 + tid * 4;
  int4 c = {0, 0, 0, 0};
  if (base + 3 < N) {
    c = *(const int4*)(cnt + base);
  } else {
    if (base + 0 < N) c.x = cnt[base + 0];
    if (base + 1 < N) c.y = cnt[base + 1];
    if (base + 2 < N) c.z = cnt[base + 2];
    if (base + 3 < N) c.w = cnt[base + 3];
  }
  int s = c.x + c.y + c.z + c.w;
  int lane = tid & 63, wid = tid >> 6;
  int pre = s;
#pragma unroll
  for (int off = 1; off < 64; off <<= 1) {
    int t = __shfl_up(pre, off);
    if (lane >= off) pre += t;
  }
  __shared__ int wsum[4];
  if (lane == 63) wsum[wid] = pre;
  __syncthreads();
  int woff = 0;
#pragma unroll
  for (int w = 0; w < 4; ++w) woff += (w < wid) ? wsum[w] : 0;
  int excl = woff + pre - s;   // exclusive prefix of this thread's 4 elements
  if (base + 0 < N) rowptr[base + 0] = excl;
  if (base + 1 < N) rowptr[base + 1] = excl + c.x;
  if (base + 2 < N) rowptr[base + 2] = excl + c.x + c.y;
  if (base + 3 < N) rowptr[base + 3] = excl + c.x + c.y + c.z;
  if (tid == 255) bsum[blockIdx.x] = wsum[0] + wsum[1] + wsum[2] + wsum[3];
}

// Stage 2: exclusive scan of nb block sums (nb <= 1024), one block.
__global__ __launch_bounds__(1024) void scan_sums(int* __restrict__ bsum, int nb) {
  __shared__ int sh[1024];
  int tid = threadIdx.x;
  int v = (tid < nb) ? bsum[tid] : 0;
  sh[tid] = v;
  __syncthreads();
  for (int off = 1; off < 1024; off <<= 1) {
    int add = (tid >= off) ? sh[tid - off] : 0;
    __syncthreads();
    sh[tid] += add;
    __syncthreads();
  }
  if (tid < nb) bsum[tid] = sh[tid] - v;  // exclusive
}

// Stage 3: add block offsets; emit rowptr + cursor; owner of element N-1 writes rowptr[N].
__global__ __launch_bounds__(256) void scan_add(const int* __restrict__ cnt,
                                                int* __restrict__ rowptr,
                                                int* __restrict__ cursor,
                                                const int* __restrict__ bsum, int N) {
  int tid = threadIdx.x;
  int base = blockIdx.x * 1024 + tid * 4;
  if (base >= N) return;
  int off = bsum[blockIdx.x];
  if (base + 3 < N) {
    int4 r = *(const int4*)(rowptr + base);
    r.x += off; r.y += off; r.z += off; r.w += off;
    *(int4*)(rowptr + base) = r;
    *(int4*)(cursor + base) = r;
    if (base + 4 == N) rowptr[N] = r.w + cnt[N - 1];
  } else {
    for (int j = 0; j < 4 && base + j < N; ++j) {
      int r = rowptr[base + j] + off;
      rowptr[base + j] = r;
      cursor[base + j] = r;
      if (base + j == N - 1) rowptr[N] = r + cnt[N - 1];
    }
  }
}

__global__ void scatter_kernel(const int* __restrict__ ei, int* __restrict__ cursor,
                               int* __restrict__ esrc, int E, int N) {
  int i = blockIdx.x * blockDim.x + threadIdx.x;
  int ET = E + N;
  if (i >= ET) return;
  int s, d;
  if (i < E) { s = ei[i]; d = ei[E + i]; } else { s = i - E; d = i - E; }
  int pos = atomicAdd(&cursor[d], 1);
  esrc[pos] = s;
}

// ---------------- GEMM: H[N,OC] = X[N,128] @ W[128,OC] ----------------
// Block = 256 threads computes a 64-row x OC-col tile. X tile staged transposed
// in LDS (stride 68 -> conflict-free, b128-aligned). Per thread: RPT rows x 4 cols.

template<int OC>
__global__ __launch_bounds__(256) void gemm_tile(const float* __restrict__ X,
                                                 const float* __restrict__ W,
                                                 float* __restrict__ H, int N) {
  const int K = 128;
  const int CT = OC / 4;             // col-threads: 32 (OC=128) / 16 (OC=64)
  const int RPT = 64 / (256 / CT);   // rows per thread: 8 / 4
  __shared__ float xs[K][68];
  int tid = threadIdx.x;
  long row0 = (long)blockIdx.x * 64;
#pragma unroll
  for (int i = 0; i < 8; ++i) {
    int flat = i * 256 + tid;        // float4 index in 64x128 tile
    int r = flat >> 5;
    int kc = flat & 31;
    long row = row0 + r;
    long rr = row < N ? row : (long)(N - 1);
    float4 xv = *(const float4*)(X + rr * K + kc * 4);
    xs[kc * 4 + 0][r] = xv.x;
    xs[kc * 4 + 1][r] = xv.y;
    xs[kc * 4 + 2][r] = xv.z;
    xs[kc * 4 + 3][r] = xv.w;
  }
  __syncthreads();
  int ct = tid % CT;
  int rg = tid / CT;
  int c0 = ct * 4;
  int r0 = rg * RPT;
  float acc[RPT][4];
#pragma unroll
  for (int i = 0; i < RPT; ++i)
    for (int j = 0; j < 4; ++j) acc[i][j] = 0.f;
#pragma unroll 4
  for (int k = 0; k < K; ++k) {
    float4 wv = *(const float4*)(W + (long)k * OC + c0);
    const float4* xr = (const float4*)(&xs[k][r0]);
#pragma unroll
    for (int i4 = 0; i4 < RPT / 4; ++i4) {
      float4 xv = xr[i4];
      float xa[4] = {xv.x, xv.y, xv.z, xv.w};
#pragma unroll
      for (int j = 0; j < 4; ++j) {
        int i = i4 * 4 + j;
        acc[i][0] = fmaf(xa[j], wv.x, acc[i][0]);
        acc[i][1] = fmaf(xa[j], wv.y, acc[i][1]);
        acc[i][2] = fmaf(xa[j], wv.z, acc[i][2]);
        acc[i][3] = fmaf(xa[j], wv.w, acc[i][3]);
      }
    }
  }
#pragma unroll
  for (int i = 0; i < RPT; ++i) {
    long row = row0 + r0 + i;
    if (row < N) {
      float4 o = {acc[i][0], acc[i][1], acc[i][2], acc[i][3]};
      *(float4*)(H + row * OC + c0) = o;
    }
  }
}

// ---------------- attention coefficients per node ----------------

// 4 heads x 32: block 256 = 8 nodes x 32 lanes, float4 loads, shuffle reduce.
__global__ void al_kernel4(const float* __restrict__ h, const float* __restrict__ a_s,
                           const float* __restrict__ a_d, float* __restrict__ als,
                           float* __restrict__ ald, int N) {
  int tid = threadIdx.x;
  int n = blockIdx.x * 8 + (tid >> 5);
  int sl = tid & 31, hd = sl >> 3;
  if (n >= N) return;
  float4 hv = *(const float4*)(h + (long)n * 128 + sl * 4);
  float4 sv = *(const float4*)(a_s + hd * 32 + (sl & 7) * 4);
  float4 dv = *(const float4*)(a_d + hd * 32 + (sl & 7) * 4);
  float vs = hv.x * sv.x + hv.y * sv.y + hv.z * sv.z + hv.w * sv.w;
  float vd = hv.x * dv.x + hv.y * dv.y + hv.z * dv.z + hv.w * dv.w;
#pragma unroll
  for (int off = 1; off <= 4; off <<= 1) {
    vs += __shfl_xor(vs, off);
    vd += __shfl_xor(vd, off);
  }
  if ((sl & 7) == 0) { als[(long)n * 4 + hd] = vs; ald[(long)n * 4 + hd] = vd; }
}

// single head of 64: block 256 = 16 nodes x 16 lanes
__global__ void al_kernel1(const float* __restrict__ h, const float* __restrict__ a_s,
                           const float* __restrict__ a_d, float* __restrict__ als,
                           float* __restrict__ ald, int N) {
  int tid = threadIdx.x;
  int n = blockIdx.x * 16 + (tid >> 4);
  int sl = tid & 15;
  if (n >= N) return;
  float4 hv = *(const float4*)(h + (long)n * 64 + sl * 4);
  float4 sv = *(const float4*)(a_s + sl * 4);
  float4 dv = *(const float4*)(a_d + sl * 4);
  float vs = hv.x * sv.x + hv.y * sv.y + hv.z * sv.z + hv.w * sv.w;
  float vd = hv.x * dv.x + hv.y * dv.y + hv.z * dv.z + hv.w * dv.w;
#pragma unroll
  for (int off = 1; off <= 8; off <<= 1) {
    vs += __shfl_xor(vs, off);
    vd += __shfl_xor(vd, off);
  }
  if (sl == 0) { als[n] = vs; ald[n] = vd; }
}

// ---------------- fused single-pass aggregation (online softmax) ----------------

// 4 heads x 32 feats. Block 128 = 4 edge-slots x 32 lanes; each slot gathers a
// full 512B h[src] row per edge (float4/lane). Online softmax per slot, then
// LDS combine across slots. Fused +bias +relu.
__global__ __launch_bounds__(128) void gat_agg128(const float* __restrict__ h,
    const float* __restrict__ als, const float* __restrict__ ald,
    const int* __restrict__ rowptr, const int* __restrict__ esrc,
    const float* __restrict__ bias, float* __restrict__ out) {
  int n = blockIdx.x;
  int tid = threadIdx.x;
  int slot = tid >> 5, sl = tid & 31, hd = sl >> 3;
  int beg = rowptr[n], end = rowptr[n + 1];
  float aldv = ald[(long)n * 4 + hd];
  float m = -1e30f, den = 0.f;
  float4 acc = {0.f, 0.f, 0.f, 0.f};

  int e = beg + slot;
  int s = 0; float alv = 0.f; float4 hv = {0.f, 0.f, 0.f, 0.f};
  if (e < end) {
    s = esrc[e];
    alv = als[(long)s * 4 + hd];
    hv = *(const float4*)(h + (long)s * 128 + sl * 4);
  }
  while (e < end) {
    int en = e + 4;
    int sn = 0; float alvn = 0.f; float4 hvn = {0.f, 0.f, 0.f, 0.f};
    if (en < end) {
      sn = esrc[en];
      alvn = als[(long)sn * 4 + hd];
      hvn = *(const float4*)(h + (long)sn * 128 + sl * 4);
    }
    float el = lrelu(alv + aldv);
    float mn = fmaxf(m, el);
    float c = __expf(m - mn);
    float p = __expf(el - mn);
    den = fmaf(den, c, p);
    acc.x = fmaf(acc.x, c, p * hv.x);
    acc.y = fmaf(acc.y, c, p * hv.y);
    acc.z = fmaf(acc.z, c, p * hv.z);
    acc.w = fmaf(acc.w, c, p * hv.w);
    m = mn;
    e = en; alv = alvn; hv = hvn;
  }

  __shared__ float sacc[4][32][4];
  __shared__ float smx[4][4], sden[4][4];
  *(float4*)&sacc[slot][sl][0] = acc;
  if ((sl & 7) == 0) { smx[slot][hd] = m; sden[slot][hd] = den; }
  __syncthreads();
  if (tid < 32) {
    int hh = tid >> 3;
    float mg = fmaxf(fmaxf(smx[0][hh], smx[1][hh]), fmaxf(smx[2][hh], smx[3][hh]));
    float d = 0.f;
    float4 a = {0.f, 0.f, 0.f, 0.f};
#pragma unroll
    for (int s2 = 0; s2 < 4; ++s2) {
      float c = __expf(smx[s2][hh] - mg);
      d = fmaf(sden[s2][hh], c, d);
      a.x = fmaf(sacc[s2][tid][0], c, a.x);
      a.y = fmaf(sacc[s2][tid][1], c, a.y);
      a.z = fmaf(sacc[s2][tid][2], c, a.z);
      a.w = fmaf(sacc[s2][tid][3], c, a.w);
    }
    float inv = 1.f / d;
    float4 bv = *(const float4*)(bias + tid * 4);
    float4 o;
    o.x = fmaxf(fmaf(a.x, inv, bv.x), 0.f);
    o.y = fmaxf(fmaf(a.y, inv, bv.y), 0.f);
    o.z = fmaxf(fmaf(a.z, inv, bv.z), 0.f);
    o.w = fmaxf(fmaf(a.w, inv, bv.w), 0.f);
    *(float4*)(out + (long)n * 128 + tid * 4) = o;
  }
}

// 1 head x 64 feats. Block 64 = 1 wave = 4 slots x 16 lanes; shuffle combine;
// fused +bias + log_softmax over the 64 classes.
__global__ __launch_bounds__(64) void gat_agg64_lsm(const float* __restrict__ h,
    const float* __restrict__ als, const float* __restrict__ ald,
    const int* __restrict__ rowptr, const int* __restrict__ esrc,
    const float* __restrict__ bias, float* __restrict__ out) {
  int n = blockIdx.x;
  int tid = threadIdx.x;
  int slot = tid >> 4, sl = tid & 15;
  int beg = rowptr[n], end = rowptr[n + 1];
  float aldv = ald[n];
  float m = -1e30f, den = 0.f;
  float4 acc = {0.f, 0.f, 0.f, 0.f};

  int e = beg + slot;
  int s = 0; float alv = 0.f; float4 hv = {0.f, 0.f, 0.f, 0.f};
  if (e < end) {
    s = esrc[e];
    alv = als[s];
    hv = *(const float4*)(h + (long)s * 64 + sl * 4);
  }
  while (e < end) {
    int en = e + 4;
    int sn = 0; float alvn = 0.f; float4 hvn = {0.f, 0.f, 0.f, 0.f};
    if (en < end) {
      sn = esrc[en];
      alvn = als[sn];
      hvn = *(const float4*)(h + (long)sn * 64 + sl * 4);
    }
    float el = lrelu(alv + aldv);
    float mn = fmaxf(m, el);
    float c = __expf(m - mn);
    float p = __expf(el - mn);
    den = fmaf(den, c, p);
    acc.x = fmaf(acc.x, c, p * hv.x);
    acc.y = fmaf(acc.y, c, p * hv.y);
    acc.z = fmaf(acc.z, c, p * hv.z);
    acc.w = fmaf(acc.w, c, p * hv.w);
    m = mn;
    e = en; alv = alvn; hv = hvn;
  }

  // combine across the 4 slots (xor 16/32 preserves sl)
  float mg = m;
  mg = fmaxf(mg, __shfl_xor(mg, 16));
  mg = fmaxf(mg, __shfl_xor(mg, 32));
  float c = __expf(m - mg);
  den *= c; acc.x *= c; acc.y *= c; acc.z *= c; acc.w *= c;
  den += __shfl_xor(den, 16); den += __shfl_xor(den, 32);
  acc.x += __shfl_xor(acc.x, 16); acc.x += __shfl_xor(acc.x, 32);
  acc.y += __shfl_xor(acc.y, 16); acc.y += __shfl_xor(acc.y, 32);
  acc.z += __shfl_xor(acc.z, 16); acc.z += __shfl_xor(acc.z, 32);
  acc.w += __shfl_xor(acc.w, 16); acc.w += __shfl_xor(acc.w, 32);
  float inv = 1.f / den;
  float4 bv = *(const float4*)(bias + sl * 4);
  float v0 = fmaf(acc.x, inv, bv.x);
  float v1 = fmaf(acc.y, inv, bv.y);
  float v2 = fmaf(acc.z, inv, bv.z);
  float v3 = fmaf(acc.w, inv, bv.w);
  // log_softmax over 64 classes
  float lm = fmaxf(fmaxf(v0, v1), fmaxf(v2, v3));
#pragma unroll
  for (int off = 1; off <= 8; off <<= 1) lm = fmaxf(lm, __shfl_xor(lm, off));
  float es = __expf(v0 - lm) + __expf(v1 - lm) + __expf(v2 - lm) + __expf(v3 - lm);
#pragma unroll
  for (int off = 1; off <= 8; off <<= 1) es += __shfl_xor(es, off);
  float lse = lm + __logf(es);
  if (tid < 16) {
    float4 o = {v0 - lse, v1 - lse, v2 - lse, v3 - lse};
    *(float4*)(out + (long)n * 64 + sl * 4) = o;
  }
}

// ---------------- launch ----------------

extern "C" void kernel_launch(void* const* d_in, const int* in_sizes, int n_in,
                              void* d_out, int out_size, void* d_ws, size_t ws_size,
                              hipStream_t stream) {
  const float* x   = (const float*)d_in[0];
  const int*   ei  = (const int*)d_in[1];
  const float* w1  = (const float*)d_in[2];
  const float* as1 = (const float*)d_in[3];
  const float* ad1 = (const float*)d_in[4];
  const float* b1  = (const float*)d_in[5];
  const float* w2  = (const float*)d_in[6];
  const float* as2 = (const float*)d_in[7];
  const float* ad2 = (const float*)d_in[8];
  const float* b2  = (const float*)d_in[9];
  const float* w3  = (const float*)d_in[10];
  const float* as3 = (const float*)d_in[11];
  const float* ad3 = (const float*)d_in[12];
  const float* b3  = (const float*)d_in[13];
  float* out = (float*)d_out;

  const int N = in_sizes[0] / 128;
  const int E = in_sizes[1] / 2;
  const int ET = E + N;

  char* ws = (char*)d_ws;
  size_t off = 0;
  auto alloc = [&](size_t bytes) -> void* {
    void* p = ws + off;
    off += (bytes + 255) & ~(size_t)255;
    return p;
  };
  float* bufA  = (float*)alloc((size_t)N * 128 * 4);
  float* bufB  = (float*)alloc((size_t)N * 128 * 4);
  float* als   = (float*)alloc((size_t)N * 4 * 4);
  float* ald   = (float*)alloc((size_t)N * 4 * 4);
  int* cnt     = (int*)alloc((size_t)N * 4);
  int* rowptr  = (int*)alloc((size_t)(N + 1) * 4);
  int* cursor  = (int*)alloc((size_t)N * 4);
  int* bsum    = (int*)alloc((size_t)1024 * 4);
  int* esrc    = (int*)alloc((size_t)ET * 4);

  const int tpb = 256;
  const int egrid = (ET + tpb - 1) / tpb;
  const int ggrid = (N + 63) / 64;
  const int nb = (N + 1023) / 1024;     // scan blocks

  // CSR build (once per launch; edge_index identical for all 3 layers)
  hipMemsetAsync(cnt, 0, (size_t)N * 4, stream);
  count_kernel<<<egrid, tpb, 0, stream>>>(ei, cnt, E, N);
  scan_blocks<<<nb, 256, 0, stream>>>(cnt, rowptr, bsum, N);
  scan_sums<<<1, 1024, 0, stream>>>(bsum, nb);
  scan_add<<<nb, 256, 0, stream>>>(cnt, rowptr, cursor, bsum, N);
  scatter_kernel<<<egrid, tpb, 0, stream>>>(ei, cursor, esrc, E, N);

  // ---- layer 1: x[N,128] -> bufB[N,128] ----
  gemm_tile<128><<<ggrid, 256, 0, stream>>>(x, w1, bufA, N);
  al_kernel4<<<(N + 7) / 8, 256, 0, stream>>>(bufA, as1, ad1, als, ald, N);
  gat_agg128<<<N, 128, 0, stream>>>(bufA, als, ald, rowptr, esrc, b1, bufB);

  // ---- layer 2: bufB -> bufB (via bufA) ----
  gemm_tile<128><<<ggrid, 256, 0, stream>>>(bufB, w2, bufA, N);
  al_kernel4<<<(N + 7) / 8, 256, 0, stream>>>(bufA, as2, ad2, als, ald, N);
  gat_agg128<<<N, 128, 0, stream>>>(bufA, als, ald, rowptr, esrc, b2, bufB);

  // ---- layer 3: bufB[N,128] -> out[N,64] ----
  gemm_tile<64><<<ggrid, 256, 0, stream>>>(bufB, w3, bufA, N);
  al_kernel1<<<(N + 15) / 16, 256, 0, stream>>>(bufA, as3, ad3, als, ald, N);
  gat_agg64_lsm<<<N, 64, 0, stream>>>(bufA, als, ald, rowptr, esrc, b3, out);
}

// Round 5
// 422.151 us; speedup vs baseline: 2.0542x; 1.0939x over previous
//
#include <hip/hip_runtime.h>
#include <hip/hip_bf16.h>
#include <math.h>

#define SLOPE 0.2f
typedef unsigned int uint_t;
typedef unsigned short ushort_t;

static __device__ __forceinline__ float lrelu(float v) { return v > 0.f ? v : SLOPE * v; }
// bf16 (stored as ushort bits) -> float
static __device__ __forceinline__ float b2f(uint_t lo16) { return __uint_as_float(lo16 << 16); }
// float -> bf16 bits, round-to-nearest-even
static __device__ __forceinline__ ushort_t f2b(float f) {
  uint_t u = __float_as_uint(f);
  u += 0x7fffu + ((u >> 16) & 1u);
  return (ushort_t)(u >> 16);
}

// ---------------- CSR build (dst-sorted edge list, self loops appended) ----------------

__global__ void count_kernel(const int* __restrict__ ei, int* __restrict__ cnt, int E, int N) {
  int i = blockIdx.x * blockDim.x + threadIdx.x;
  int ET = E + N;
  if (i >= ET) return;
  int d = (i < E) ? ei[E + i] : (i - E);
  atomicAdd(&cnt[d], 1);
}

__global__ __launch_bounds__(256) void scan_blocks(const int* __restrict__ cnt,
                                                   int* __restrict__ rowptr,
                                                   int* __restrict__ bsum, int N) {
  int tid = threadIdx.x;
  int base = blockIdx.x * 1024 + tid * 4;
  int4 c = {0, 0, 0, 0};
  if (base + 3 < N) {
    c = *(const int4*)(cnt + base);
  } else {
    if (base + 0 < N) c.x = cnt[base + 0];
    if (base + 1 < N) c.y = cnt[base + 1];
    if (base + 2 < N) c.z = cnt[base + 2];
    if (base + 3 < N) c.w = cnt[base + 3];
  }
  int s = c.x + c.y + c.z + c.w;
  int lane = tid & 63, wid = tid >> 6;
  int pre = s;
#pragma unroll
  for (int off = 1; off < 64; off <<= 1) {
    int t = __shfl_up(pre, off);
    if (lane >= off) pre += t;
  }
  __shared__ int wsum[4];
  if (lane == 63) wsum[wid] = pre;
  __syncthreads();
  int woff = 0;
#pragma unroll
  for (int w = 0; w < 4; ++w) woff += (w < wid) ? wsum[w] : 0;
  int excl = woff + pre - s;
  if (base + 0 < N) rowptr[base + 0] = excl;
  if (base + 1 < N) rowptr[base + 1] = excl + c.x;
  if (base + 2 < N) rowptr[base + 2] = excl + c.x + c.y;
  if (base + 3 < N) rowptr[base + 3] = excl + c.x + c.y + c.z;
  if (tid == 255) bsum[blockIdx.x] = wsum[0] + wsum[1] + wsum[2] + wsum[3];
}

__global__ __launch_bounds__(1024) void scan_sums(int* __restrict__ bsum, int nb) {
  __shared__ int sh[1024];
  int tid = threadIdx.x;
  int v = (tid < nb) ? bsum[tid] : 0;
  sh[tid] = v;
  __syncthreads();
  for (int off = 1; off < 1024; off <<= 1) {
    int add = (tid >= off) ? sh[tid - off] : 0;
    __syncthreads();
    sh[tid] += add;
    __syncthreads();
  }
  if (tid < nb) bsum[tid] = sh[tid] - v;
}

__global__ __launch_bounds__(256) void scan_add(const int* __restrict__ cnt,
                                                int* __restrict__ rowptr,
                                                int* __restrict__ cursor,
                                                const int* __restrict__ bsum, int N) {
  int tid = threadIdx.x;
  int base = blockIdx.x * 1024 + tid * 4;
  if (base >= N) return;
  int off = bsum[blockIdx.x];
  if (base + 3 < N) {
    int4 r = *(const int4*)(rowptr + base);
    r.x += off; r.y += off; r.z += off; r.w += off;
    *(int4*)(rowptr + base) = r;
    *(int4*)(cursor + base) = r;
    if (base + 4 == N) rowptr[N] = r.w + cnt[N - 1];
  } else {
    for (int j = 0; j < 4 && base + j < N; ++j) {
      int r = rowptr[base + j] + off;
      rowptr[base + j] = r;
      cursor[base + j] = r;
      if (base + j == N - 1) rowptr[N] = r + cnt[N - 1];
    }
  }
}

__global__ void scatter_kernel(const int* __restrict__ ei, int* __restrict__ cursor,
                               int* __restrict__ esrc, int E, int N) {
  int i = blockIdx.x * blockDim.x + threadIdx.x;
  int ET = E + N;
  if (i >= ET) return;
  int s, d;
  if (i < E) { s = ei[i]; d = ei[E + i]; } else { s = i - E; d = i - E; }
  int pos = atomicAdd(&cursor[d], 1);
  esrc[pos] = s;
}

// ---------------- GEMM: H[N,OC](bf16) = X[N,128](f32|bf16) @ W[128,OC](f32) ----------------
// 64-row x OC-col tile / 256 threads. X staged transposed into LDS as fp32 (stride 68,
// r-major staging -> conflict-free LDS writes). fp32 math, bf16 RNE output.

template<int OC, bool BF16IN>
__global__ __launch_bounds__(256) void gemm_tile(const void* __restrict__ Xv,
                                                 const float* __restrict__ W,
                                                 ushort_t* __restrict__ H, int N) {
  const int K = 128;
  const int CT = OC / 4;             // 32 (OC=128) / 16 (OC=64)
  const int RPT = 64 / (256 / CT);   // 8 / 4
  __shared__ float xs[K][68];
  int tid = threadIdx.x;
  long row0 = (long)blockIdx.x * 64;
  if (BF16IN) {
    const ushort_t* X = (const ushort_t*)Xv;
#pragma unroll
    for (int i = 0; i < 4; ++i) {
      int flat = i * 256 + tid;      // 64 rows x 16 chunks of 8 bf16
      int r = flat & 63, kc = flat >> 6;
      long row = row0 + r;
      long rr = row < N ? row : (long)(N - 1);
      uint4 v = *(const uint4*)(X + rr * K + kc * 8);
      uint_t vv[4] = {v.x, v.y, v.z, v.w};
#pragma unroll
      for (int j = 0; j < 4; ++j) {
        xs[kc * 8 + j * 2 + 0][r] = __uint_as_float(vv[j] << 16);
        xs[kc * 8 + j * 2 + 1][r] = __uint_as_float(vv[j] & 0xffff0000u);
      }
    }
  } else {
    const float* X = (const float*)Xv;
#pragma unroll
    for (int i = 0; i < 8; ++i) {
      int flat = i * 256 + tid;      // 64 rows x 32 float4 chunks
      int r = flat & 63, kc = flat >> 6;
      long row = row0 + r;
      long rr = row < N ? row : (long)(N - 1);
      float4 xv = *(const float4*)(X + rr * K + kc * 4);
      xs[kc * 4 + 0][r] = xv.x;
      xs[kc * 4 + 1][r] = xv.y;
      xs[kc * 4 + 2][r] = xv.z;
      xs[kc * 4 + 3][r] = xv.w;
    }
  }
  __syncthreads();
  int ct = tid % CT;
  int rg = tid / CT;
  int c0 = ct * 4;
  int r0 = rg * RPT;
  float acc[RPT][4];
#pragma unroll
  for (int i = 0; i < RPT; ++i)
    for (int j = 0; j < 4; ++j) acc[i][j] = 0.f;
#pragma unroll 4
  for (int k = 0; k < K; ++k) {
    float4 wv = *(const float4*)(W + (long)k * OC + c0);
    const float4* xr = (const float4*)(&xs[k][r0]);
#pragma unroll
    for (int i4 = 0; i4 < RPT / 4; ++i4) {
      float4 xv = xr[i4];
      float xa[4] = {xv.x, xv.y, xv.z, xv.w};
#pragma unroll
      for (int j = 0; j < 4; ++j) {
        int i = i4 * 4 + j;
        acc[i][0] = fmaf(xa[j], wv.x, acc[i][0]);
        acc[i][1] = fmaf(xa[j], wv.y, acc[i][1]);
        acc[i][2] = fmaf(xa[j], wv.z, acc[i][2]);
        acc[i][3] = fmaf(xa[j], wv.w, acc[i][3]);
      }
    }
  }
#pragma unroll
  for (int i = 0; i < RPT; ++i) {
    long row = row0 + r0 + i;
    if (row < N) {
      ushort4 o = {f2b(acc[i][0]), f2b(acc[i][1]), f2b(acc[i][2]), f2b(acc[i][3])};
      *(ushort4*)(H + row * OC + c0) = o;
    }
  }
}

// ---------------- attention coefficients per node (bf16 h) ----------------

// 4 heads x 32: block 256 = 16 nodes x 16 lanes (8 feats each).
__global__ void al_kernel4(const ushort_t* __restrict__ h, const float* __restrict__ a_s,
                           const float* __restrict__ a_d, float* __restrict__ als,
                           float* __restrict__ ald, int N) {
  int tid = threadIdx.x;
  int n = blockIdx.x * 16 + (tid >> 4);
  int sl = tid & 15, hd = sl >> 2;
  if (n >= N) return;
  uint4 v = *(const uint4*)(h + (long)n * 128 + sl * 8);
  uint_t vv[4] = {v.x, v.y, v.z, v.w};
  const float* sp = a_s + hd * 32 + (sl & 3) * 8;
  const float* dp = a_d + hd * 32 + (sl & 3) * 8;
  float vs = 0.f, vd = 0.f;
#pragma unroll
  for (int j = 0; j < 4; ++j) {
    float h0 = b2f(vv[j] & 0xffffu) * 0.f + __uint_as_float(vv[j] << 16);
    float h1 = __uint_as_float(vv[j] & 0xffff0000u);
    vs = fmaf(h0, sp[j * 2 + 0], vs); vs = fmaf(h1, sp[j * 2 + 1], vs);
    vd = fmaf(h0, dp[j * 2 + 0], vd); vd = fmaf(h1, dp[j * 2 + 1], vd);
  }
#pragma unroll
  for (int off = 1; off <= 2; off <<= 1) {
    vs += __shfl_xor(vs, off);
    vd += __shfl_xor(vd, off);
  }
  if ((sl & 3) == 0) { als[(long)n * 4 + hd] = vs; ald[(long)n * 4 + hd] = vd; }
}

// single head of 64: block 256 = 32 nodes x 8 lanes (8 feats each)
__global__ void al_kernel1(const ushort_t* __restrict__ h, const float* __restrict__ a_s,
                           const float* __restrict__ a_d, float* __restrict__ als,
                           float* __restrict__ ald, int N) {
  int tid = threadIdx.x;
  int n = blockIdx.x * 32 + (tid >> 3);
  int sl = tid & 7;
  if (n >= N) return;
  uint4 v = *(const uint4*)(h + (long)n * 64 + sl * 8);
  uint_t vv[4] = {v.x, v.y, v.z, v.w};
  const float* sp = a_s + sl * 8;
  const float* dp = a_d + sl * 8;
  float vs = 0.f, vd = 0.f;
#pragma unroll
  for (int j = 0; j < 4; ++j) {
    float h0 = __uint_as_float(vv[j] << 16);
    float h1 = __uint_as_float(vv[j] & 0xffff0000u);
    vs = fmaf(h0, sp[j * 2 + 0], vs); vs = fmaf(h1, sp[j * 2 + 1], vs);
    vd = fmaf(h0, dp[j * 2 + 0], vd); vd = fmaf(h1, dp[j * 2 + 1], vd);
  }
#pragma unroll
  for (int off = 1; off <= 4; off <<= 1) {
    vs += __shfl_xor(vs, off);
    vd += __shfl_xor(vd, off);
  }
  if (sl == 0) { als[n] = vs; ald[n] = vd; }
}

// ---------------- two-phase softmax aggregation (bf16 h gather) ----------------

// 4 heads x 32 feats. Phase 1: per-head max over logits (no gather). Phase 2:
// 8 edge-slots x 16 lanes, 16B bf16 gather per lane, single exp per edge, no
// rescale. Combine slots in LDS. Fused +bias +relu, bf16 out.
__global__ __launch_bounds__(128) void gat_agg128(const ushort_t* __restrict__ h,
    const float* __restrict__ als, const float* __restrict__ ald,
    const int* __restrict__ rowptr, const int* __restrict__ esrc,
    const float* __restrict__ bias, ushort_t* __restrict__ out) {
  int n = blockIdx.x;
  int tid = threadIdx.x;
  int beg = rowptr[n], end = rowptr[n + 1];
  // phase 1: per-head max
  int hd1 = tid & 3;
  float aldv1 = ald[(long)n * 4 + hd1];
  float m = -1e30f;
  for (int e = beg + (tid >> 2); e < end; e += 32)
    m = fmaxf(m, lrelu(als[(long)esrc[e] * 4 + hd1] + aldv1));
#pragma unroll
  for (int off = 4; off <= 32; off <<= 1) m = fmaxf(m, __shfl_xor(m, off));
  __shared__ float sm[2][4];
  if ((tid & 63) < 4) sm[tid >> 6][hd1] = m;
  __syncthreads();
  // phase 2
  int slot = tid >> 4, sl = tid & 15, hd = sl >> 2;
  float mh = fmaxf(sm[0][hd], sm[1][hd]);
  float aldv = ald[(long)n * 4 + hd];
  float den = 0.f;
  float acc[8] = {0.f, 0.f, 0.f, 0.f, 0.f, 0.f, 0.f, 0.f};
  for (int e = beg + slot; e < end; e += 8) {
    int s = esrc[e];
    float p = __expf(lrelu(als[(long)s * 4 + hd] + aldv) - mh);
    den += p;
    uint4 v = *(const uint4*)(h + (long)s * 128 + sl * 8);
    uint_t vv[4] = {v.x, v.y, v.z, v.w};
#pragma unroll
    for (int j = 0; j < 4; ++j) {
      acc[2 * j + 0] = fmaf(p, __uint_as_float(vv[j] << 16), acc[2 * j + 0]);
      acc[2 * j + 1] = fmaf(p, __uint_as_float(vv[j] & 0xffff0000u), acc[2 * j + 1]);
    }
  }
  __shared__ float sacc[8][16][9];
  __shared__ float sden[8][4];
#pragma unroll
  for (int j = 0; j < 8; ++j) sacc[slot][sl][j] = acc[j];
  if ((sl & 3) == 0) sden[slot][hd] = den;
  __syncthreads();
  if (tid < 16) {
    int hh = tid >> 2;
    float d = 0.f;
    float o[8] = {0.f, 0.f, 0.f, 0.f, 0.f, 0.f, 0.f, 0.f};
#pragma unroll
    for (int s2 = 0; s2 < 8; ++s2) {
      d += sden[s2][hh];
#pragma unroll
      for (int j = 0; j < 8; ++j) o[j] += sacc[s2][tid][j];
    }
    float inv = 1.f / d;
    uint_t pk[4];
#pragma unroll
    for (int j = 0; j < 4; ++j) {
      float v0 = fmaxf(fmaf(o[2 * j + 0], inv, bias[tid * 8 + 2 * j + 0]), 0.f);
      float v1 = fmaxf(fmaf(o[2 * j + 1], inv, bias[tid * 8 + 2 * j + 1]), 0.f);
      pk[j] = (uint_t)f2b(v0) | ((uint_t)f2b(v1) << 16);
    }
    uint4 pv = {pk[0], pk[1], pk[2], pk[3]};
    *(uint4*)(out + (long)n * 128 + tid * 8) = pv;
  }
}

// 1 head x 64 feats. Block 64 = 8 slots x 8 lanes. Fused +bias + log_softmax, f32 out.
__global__ __launch_bounds__(64) void gat_agg64_lsm(const ushort_t* __restrict__ h,
    const float* __restrict__ als, const float* __restrict__ ald,
    const int* __restrict__ rowptr, const int* __restrict__ esrc,
    const float* __restrict__ bias, float* __restrict__ out) {
  int n = blockIdx.x;
  int tid = threadIdx.x;
  int beg = rowptr[n], end = rowptr[n + 1];
  float aldv = ald[n];
  float m = -1e30f;
  for (int e = beg + tid; e < end; e += 64)
    m = fmaxf(m, lrelu(als[esrc[e]] + aldv));
#pragma unroll
  for (int off = 1; off <= 32; off <<= 1) m = fmaxf(m, __shfl_xor(m, off));
  int slot = tid >> 3, sl = tid & 7;
  float den = 0.f;
  float acc[8] = {0.f, 0.f, 0.f, 0.f, 0.f, 0.f, 0.f, 0.f};
  for (int e = beg + slot; e < end; e += 8) {
    int s = esrc[e];
    float p = __expf(lrelu(als[s] + aldv) - m);
    den += p;
    uint4 v = *(const uint4*)(h + (long)s * 64 + sl * 8);
    uint_t vv[4] = {v.x, v.y, v.z, v.w};
#pragma unroll
    for (int j = 0; j < 4; ++j) {
      acc[2 * j + 0] = fmaf(p, __uint_as_float(vv[j] << 16), acc[2 * j + 0]);
      acc[2 * j + 1] = fmaf(p, __uint_as_float(vv[j] & 0xffff0000u), acc[2 * j + 1]);
    }
  }
  __shared__ float sacc[8][8][9];
  __shared__ float sden[8];
#pragma unroll
  for (int j = 0; j < 8; ++j) sacc[slot][sl][j] = acc[j];
  if (sl == 0) sden[slot] = den;
  __syncthreads();
  if (tid < 8) {
    float d = 0.f;
    float o[8] = {0.f, 0.f, 0.f, 0.f, 0.f, 0.f, 0.f, 0.f};
#pragma unroll
    for (int s2 = 0; s2 < 8; ++s2) {
      d += sden[s2];
#pragma unroll
      for (int j = 0; j < 8; ++j) o[j] += sacc[s2][tid][j];
    }
    float inv = 1.f / d;
    float v[8];
#pragma unroll
    for (int j = 0; j < 8; ++j) v[j] = fmaf(o[j], inv, bias[tid * 8 + j]);
    float lm = v[0];
#pragma unroll
    for (int j = 1; j < 8; ++j) lm = fmaxf(lm, v[j]);
#pragma unroll
    for (int off = 1; off <= 4; off <<= 1) lm = fmaxf(lm, __shfl_xor(lm, off));
    float es = 0.f;
#pragma unroll
    for (int j = 0; j < 8; ++j) es += __expf(v[j] - lm);
#pragma unroll
    for (int off = 1; off <= 4; off <<= 1) es += __shfl_xor(es, off);
    float lse = lm + __logf(es);
    float4 o0 = {v[0] - lse, v[1] - lse, v[2] - lse, v[3] - lse};
    float4 o1 = {v[4] - lse, v[5] - lse, v[6] - lse, v[7] - lse};
    *(float4*)(out + (long)n * 64 + tid * 8 + 0) = o0;
    *(float4*)(out + (long)n * 64 + tid * 8 + 4) = o1;
  }
}

// ---------------- launch ----------------

extern "C" void kernel_launch(void* const* d_in, const int* in_sizes, int n_in,
                              void* d_out, int out_size, void* d_ws, size_t ws_size,
                              hipStream_t stream) {
  const float* x   = (const float*)d_in[0];
  const int*   ei  = (const int*)d_in[1];
  const float* w1  = (const float*)d_in[2];
  const float* as1 = (const float*)d_in[3];
  const float* ad1 = (const float*)d_in[4];
  const float* b1  = (const float*)d_in[5];
  const float* w2  = (const float*)d_in[6];
  const float* as2 = (const float*)d_in[7];
  const float* ad2 = (const float*)d_in[8];
  const float* b2  = (const float*)d_in[9];
  const float* w3  = (const float*)d_in[10];
  const float* as3 = (const float*)d_in[11];
  const float* ad3 = (const float*)d_in[12];
  const float* b3  = (const float*)d_in[13];
  float* out = (float*)d_out;

  const int N = in_sizes[0] / 128;
  const int E = in_sizes[1] / 2;
  const int ET = E + N;

  char* ws = (char*)d_ws;
  size_t off = 0;
  auto alloc = [&](size_t bytes) -> void* {
    void* p = ws + off;
    off += (bytes + 255) & ~(size_t)255;
    return p;
  };
  ushort_t* bufA = (ushort_t*)alloc((size_t)N * 128 * 2);  // h (bf16)
  ushort_t* bufB = (ushort_t*)alloc((size_t)N * 128 * 2);  // layer outputs (bf16)
  float* als   = (float*)alloc((size_t)N * 4 * 4);
  float* ald   = (float*)alloc((size_t)N * 4 * 4);
  int* cnt     = (int*)alloc((size_t)N * 4);
  int* rowptr  = (int*)alloc((size_t)(N + 1) * 4);
  int* cursor  = (int*)alloc((size_t)N * 4);
  int* bsum    = (int*)alloc((size_t)1024 * 4);
  int* esrc    = (int*)alloc((size_t)ET * 4);

  const int tpb = 256;
  const int egrid = (ET + tpb - 1) / tpb;
  const int ggrid = (N + 63) / 64;
  const int nb = (N + 1023) / 1024;

  // CSR build
  hipMemsetAsync(cnt, 0, (size_t)N * 4, stream);
  count_kernel<<<egrid, tpb, 0, stream>>>(ei, cnt, E, N);
  scan_blocks<<<nb, 256, 0, stream>>>(cnt, rowptr, bsum, N);
  scan_sums<<<1, 1024, 0, stream>>>(bsum, nb);
  scan_add<<<nb, 256, 0, stream>>>(cnt, rowptr, cursor, bsum, N);
  scatter_kernel<<<egrid, tpb, 0, stream>>>(ei, cursor, esrc, E, N);

  // ---- layer 1: x(f32) -> bufA(h, bf16) -> bufB(bf16) ----
  gemm_tile<128, false><<<ggrid, 256, 0, stream>>>(x, w1, bufA, N);
  al_kernel4<<<(N + 15) / 16, 256, 0, stream>>>(bufA, as1, ad1, als, ald, N);
  gat_agg128<<<N, 128, 0, stream>>>(bufA, als, ald, rowptr, esrc, b1, bufB);

  // ---- layer 2 ----
  gemm_tile<128, true><<<ggrid, 256, 0, stream>>>(bufB, w2, bufA, N);
  al_kernel4<<<(N + 15) / 16, 256, 0, stream>>>(bufA, as2, ad2, als, ald, N);
  gat_agg128<<<N, 128, 0, stream>>>(bufA, als, ald, rowptr, esrc, b2, bufB);

  // ---- layer 3 ----
  gemm_tile<64, true><<<ggrid, 256, 0, stream>>>(bufB, w3, bufA, N);
  al_kernel1<<<(N + 31) / 32, 256, 0, stream>>>(bufA, as3, ad3, als, ald, N);
  gat_agg64_lsm<<<N, 64, 0, stream>>>(bufA, als, ald, rowptr, esrc, b3, out);
}

// Round 6
// 411.750 us; speedup vs baseline: 2.1061x; 1.0253x over previous
//
#include <hip/hip_runtime.h>
#include <hip/hip_bf16.h>
#include <math.h>

#define SLOPE 0.2f
typedef unsigned int uint_t;
typedef unsigned short ushort_t;

static __device__ __forceinline__ float lrelu(float v) { return v > 0.f ? v : SLOPE * v; }
// float -> bf16 bits, round-to-nearest-even
static __device__ __forceinline__ ushort_t f2b(float f) {
  uint_t u = __float_as_uint(f);
  u += 0x7fffu + ((u >> 16) & 1u);
  return (ushort_t)(u >> 16);
}

// cnt/cursor are padded: one counter per 64B cache line (idx*16) to kill
// per-line atomic serialization (measured: packed cursor -> 59us scatter;
// 272 atomics/line x ~500cyc cross-XCD transfer matches).
#define PAD 16

// ---------------- GEMM body: H[N,OC](bf16) = X[N,128](f32|bf16) @ W[128,OC](f32) ----------------

template<int OC, bool BF16IN>
__device__ __forceinline__ void gemm_body(const void* __restrict__ Xv,
                                          const float* __restrict__ W,
                                          ushort_t* __restrict__ H, int N, int bid) {
  const int K = 128;
  const int CT = OC / 4;             // 32 (OC=128) / 16 (OC=64)
  const int RPT = 64 / (256 / CT);   // 8 / 4
  __shared__ float xs[K][68];
  int tid = threadIdx.x;
  long row0 = (long)bid * 64;
  if (BF16IN) {
    const ushort_t* X = (const ushort_t*)Xv;
#pragma unroll
    for (int i = 0; i < 4; ++i) {
      int flat = i * 256 + tid;      // 64 rows x 16 chunks of 8 bf16
      int r = flat & 63, kc = flat >> 6;
      long row = row0 + r;
      long rr = row < N ? row : (long)(N - 1);
      uint4 v = *(const uint4*)(X + rr * K + kc * 8);
      uint_t vv[4] = {v.x, v.y, v.z, v.w};
#pragma unroll
      for (int j = 0; j < 4; ++j) {
        xs[kc * 8 + j * 2 + 0][r] = __uint_as_float(vv[j] << 16);
        xs[kc * 8 + j * 2 + 1][r] = __uint_as_float(vv[j] & 0xffff0000u);
      }
    }
  } else {
    const float* X = (const float*)Xv;
#pragma unroll
    for (int i = 0; i < 8; ++i) {
      int flat = i * 256 + tid;      // 64 rows x 32 float4 chunks
      int r = flat & 63, kc = flat >> 6;
      long row = row0 + r;
      long rr = row < N ? row : (long)(N - 1);
      float4 xv = *(const float4*)(X + rr * K + kc * 4);
      xs[kc * 4 + 0][r] = xv.x;
      xs[kc * 4 + 1][r] = xv.y;
      xs[kc * 4 + 2][r] = xv.z;
      xs[kc * 4 + 3][r] = xv.w;
    }
  }
  __syncthreads();
  int ct = tid % CT;
  int rg = tid / CT;
  int c0 = ct * 4;
  int r0 = rg * RPT;
  float acc[RPT][4];
#pragma unroll
  for (int i = 0; i < RPT; ++i)
    for (int j = 0; j < 4; ++j) acc[i][j] = 0.f;
#pragma unroll 4
  for (int k = 0; k < K; ++k) {
    float4 wv = *(const float4*)(W + (long)k * OC + c0);
    const float4* xr = (const float4*)(&xs[k][r0]);
#pragma unroll
    for (int i4 = 0; i4 < RPT / 4; ++i4) {
      float4 xv = xr[i4];
      float xa[4] = {xv.x, xv.y, xv.z, xv.w};
#pragma unroll
      for (int j = 0; j < 4; ++j) {
        int i = i4 * 4 + j;
        acc[i][0] = fmaf(xa[j], wv.x, acc[i][0]);
        acc[i][1] = fmaf(xa[j], wv.y, acc[i][1]);
        acc[i][2] = fmaf(xa[j], wv.z, acc[i][2]);
        acc[i][3] = fmaf(xa[j], wv.w, acc[i][3]);
      }
    }
  }
#pragma unroll
  for (int i = 0; i < RPT; ++i) {
    long row = row0 + r0 + i;
    if (row < N) {
      ushort4 o = {f2b(acc[i][0]), f2b(acc[i][1]), f2b(acc[i][2]), f2b(acc[i][3])};
      *(ushort4*)(H + row * OC + c0) = o;
    }
  }
}

template<int OC, bool BF16IN>
__global__ __launch_bounds__(256) void gemm_tile(const void* __restrict__ Xv,
                                                 const float* __restrict__ W,
                                                 ushort_t* __restrict__ H, int N) {
  gemm_body<OC, BF16IN>(Xv, W, H, N, blockIdx.x);
}

// ---------------- al4 body (4 heads x 32, bf16 h) ----------------

__device__ __forceinline__ void al4_body(const ushort_t* __restrict__ h,
                                         const float* __restrict__ a_s,
                                         const float* __restrict__ a_d,
                                         float* __restrict__ als, float* __restrict__ ald,
                                         int N, int bid) {
  int tid = threadIdx.x;
  int n = bid * 16 + (tid >> 4);
  int sl = tid & 15, hd = sl >> 2;
  if (n >= N) return;
  uint4 v = *(const uint4*)(h + (long)n * 128 + sl * 8);
  uint_t vv[4] = {v.x, v.y, v.z, v.w};
  const float* sp = a_s + hd * 32 + (sl & 3) * 8;
  const float* dp = a_d + hd * 32 + (sl & 3) * 8;
  float vs = 0.f, vd = 0.f;
#pragma unroll
  for (int j = 0; j < 4; ++j) {
    float h0 = __uint_as_float(vv[j] << 16);
    float h1 = __uint_as_float(vv[j] & 0xffff0000u);
    vs = fmaf(h0, sp[j * 2 + 0], vs); vs = fmaf(h1, sp[j * 2 + 1], vs);
    vd = fmaf(h0, dp[j * 2 + 0], vd); vd = fmaf(h1, dp[j * 2 + 1], vd);
  }
#pragma unroll
  for (int off = 1; off <= 2; off <<= 1) {
    vs += __shfl_xor(vs, off);
    vd += __shfl_xor(vd, off);
  }
  if ((sl & 3) == 0) { als[(long)n * 4 + hd] = vs; ald[(long)n * 4 + hd] = vd; }
}

__global__ void al_kernel4(const ushort_t* __restrict__ h, const float* __restrict__ a_s,
                           const float* __restrict__ a_d, float* __restrict__ als,
                           float* __restrict__ ald, int N) {
  al4_body(h, a_s, a_d, als, ald, N, blockIdx.x);
}

// single head of 64: block 256 = 32 nodes x 8 lanes (8 feats each)
__global__ void al_kernel1(const ushort_t* __restrict__ h, const float* __restrict__ a_s,
                           const float* __restrict__ a_d, float* __restrict__ als,
                           float* __restrict__ ald, int N) {
  int tid = threadIdx.x;
  int n = blockIdx.x * 32 + (tid >> 3);
  int sl = tid & 7;
  if (n >= N) return;
  uint4 v = *(const uint4*)(h + (long)n * 64 + sl * 8);
  uint_t vv[4] = {v.x, v.y, v.z, v.w};
  const float* sp = a_s + sl * 8;
  const float* dp = a_d + sl * 8;
  float vs = 0.f, vd = 0.f;
#pragma unroll
  for (int j = 0; j < 4; ++j) {
    float h0 = __uint_as_float(vv[j] << 16);
    float h1 = __uint_as_float(vv[j] & 0xffff0000u);
    vs = fmaf(h0, sp[j * 2 + 0], vs); vs = fmaf(h1, sp[j * 2 + 1], vs);
    vd = fmaf(h0, dp[j * 2 + 0], vd); vd = fmaf(h1, dp[j * 2 + 1], vd);
  }
#pragma unroll
  for (int off = 1; off <= 4; off <<= 1) {
    vs += __shfl_xor(vs, off);
    vd += __shfl_xor(vd, off);
  }
  if (sl == 0) { als[n] = vs; ald[n] = vd; }
}

// ---------------- fused: gemm1 + edge count ----------------

__global__ __launch_bounds__(256) void k_gemm1_count(const float* __restrict__ X,
    const float* __restrict__ W, ushort_t* __restrict__ H, int N,
    const int* __restrict__ ei, int* __restrict__ cnt, int E, int gemmBlocks) {
  int bid = blockIdx.x;
  if (bid < gemmBlocks) {
    gemm_body<128, false>(X, W, H, N, bid);
  } else {
    int i = (bid - gemmBlocks) * 256 + threadIdx.x;
    int ET = E + N;
    if (i >= ET) return;
    int d = (i < E) ? ei[E + i] : (i - E);
    atomicAdd(&cnt[d * PAD], 1);
  }
}

// ---------------- scan (padded cnt -> compact rowptr, padded cursor) ----------------

__global__ __launch_bounds__(256) void scan_blocks(const int* __restrict__ cnt,
                                                   int* __restrict__ rowptr,
                                                   int* __restrict__ bsum, int N) {
  int tid = threadIdx.x;
  int base = blockIdx.x * 1024 + tid * 4;
  int c0 = (base + 0 < N) ? cnt[(base + 0) * PAD] : 0;
  int c1 = (base + 1 < N) ? cnt[(base + 1) * PAD] : 0;
  int c2 = (base + 2 < N) ? cnt[(base + 2) * PAD] : 0;
  int c3 = (base + 3 < N) ? cnt[(base + 3) * PAD] : 0;
  int s = c0 + c1 + c2 + c3;
  int lane = tid & 63, wid = tid >> 6;
  int pre = s;
#pragma unroll
  for (int off = 1; off < 64; off <<= 1) {
    int t = __shfl_up(pre, off);
    if (lane >= off) pre += t;
  }
  __shared__ int wsum[4];
  if (lane == 63) wsum[wid] = pre;
  __syncthreads();
  int woff = 0;
#pragma unroll
  for (int w = 0; w < 4; ++w) woff += (w < wid) ? wsum[w] : 0;
  int excl = woff + pre - s;
  if (base + 0 < N) rowptr[base + 0] = excl;
  if (base + 1 < N) rowptr[base + 1] = excl + c0;
  if (base + 2 < N) rowptr[base + 2] = excl + c0 + c1;
  if (base + 3 < N) rowptr[base + 3] = excl + c0 + c1 + c2;
  if (tid == 255) bsum[blockIdx.x] = wsum[0] + wsum[1] + wsum[2] + wsum[3];
}

__global__ __launch_bounds__(1024) void scan_sums(int* __restrict__ bsum, int nb) {
  __shared__ int sh[1024];
  int tid = threadIdx.x;
  int v = (tid < nb) ? bsum[tid] : 0;
  sh[tid] = v;
  __syncthreads();
  for (int off = 1; off < 1024; off <<= 1) {
    int add = (tid >= off) ? sh[tid - off] : 0;
    __syncthreads();
    sh[tid] += add;
    __syncthreads();
  }
  if (tid < nb) bsum[tid] = sh[tid] - v;
}

__global__ __launch_bounds__(256) void scan_add(const int* __restrict__ cnt,
                                                int* __restrict__ rowptr,
                                                int* __restrict__ cursor,
                                                const int* __restrict__ bsum, int N) {
  int tid = threadIdx.x;
  int base = blockIdx.x * 1024 + tid * 4;
  if (base >= N) return;
  int off = bsum[blockIdx.x];
  if (base + 3 < N) {
    int4 r = *(const int4*)(rowptr + base);
    r.x += off; r.y += off; r.z += off; r.w += off;
    *(int4*)(rowptr + base) = r;
    cursor[(base + 0) * PAD] = r.x;
    cursor[(base + 1) * PAD] = r.y;
    cursor[(base + 2) * PAD] = r.z;
    cursor[(base + 3) * PAD] = r.w;
    if (base + 4 == N) rowptr[N] = r.w + cnt[(N - 1) * PAD];
  } else {
    for (int j = 0; j < 4 && base + j < N; ++j) {
      int r = rowptr[base + j] + off;
      rowptr[base + j] = r;
      cursor[(base + j) * PAD] = r;
      if (base + j == N - 1) rowptr[N] = r + cnt[(N - 1) * PAD];
    }
  }
}

// ---------------- fused: al4(layer1) + scatter ----------------

__global__ __launch_bounds__(256) void k_al4_scatter(const ushort_t* __restrict__ h,
    const float* __restrict__ a_s, const float* __restrict__ a_d,
    float* __restrict__ als, float* __restrict__ ald, int N,
    const int* __restrict__ ei, int* __restrict__ cursor, int* __restrict__ esrc,
    int E, int alBlocks) {
  int bid = blockIdx.x;
  if (bid < alBlocks) {
    al4_body(h, a_s, a_d, als, ald, N, bid);
  } else {
    int i = (bid - alBlocks) * 256 + threadIdx.x;
    int ET = E + N;
    if (i >= ET) return;
    int s, d;
    if (i < E) { s = ei[i]; d = ei[E + i]; } else { s = i - E; d = i - E; }
    int pos = atomicAdd(&cursor[d * PAD], 1);
    esrc[pos] = s;
  }
}

// ---------------- two-phase softmax aggregation (bf16 h gather) ----------------

__global__ __launch_bounds__(128) void gat_agg128(const ushort_t* __restrict__ h,
    const float* __restrict__ als, const float* __restrict__ ald,
    const int* __restrict__ rowptr, const int* __restrict__ esrc,
    const float* __restrict__ bias, ushort_t* __restrict__ out) {
  int n = blockIdx.x;
  int tid = threadIdx.x;
  int beg = rowptr[n], end = rowptr[n + 1];
  // phase 1: per-head max
  int hd1 = tid & 3;
  float aldv1 = ald[(long)n * 4 + hd1];
  float m = -1e30f;
  for (int e = beg + (tid >> 2); e < end; e += 32)
    m = fmaxf(m, lrelu(als[(long)esrc[e] * 4 + hd1] + aldv1));
#pragma unroll
  for (int off = 4; off <= 32; off <<= 1) m = fmaxf(m, __shfl_xor(m, off));
  __shared__ float sm[2][4];
  if ((tid & 63) < 4) sm[tid >> 6][hd1] = m;
  __syncthreads();
  // phase 2
  int slot = tid >> 4, sl = tid & 15, hd = sl >> 2;
  float mh = fmaxf(sm[0][hd], sm[1][hd]);
  float aldv = ald[(long)n * 4 + hd];
  float den = 0.f;
  float acc[8] = {0.f, 0.f, 0.f, 0.f, 0.f, 0.f, 0.f, 0.f};
  for (int e = beg + slot; e < end; e += 8) {
    int s = esrc[e];
    float p = __expf(lrelu(als[(long)s * 4 + hd] + aldv) - mh);
    den += p;
    uint4 v = *(const uint4*)(h + (long)s * 128 + sl * 8);
    uint_t vv[4] = {v.x, v.y, v.z, v.w};
#pragma unroll
    for (int j = 0; j < 4; ++j) {
      acc[2 * j + 0] = fmaf(p, __uint_as_float(vv[j] << 16), acc[2 * j + 0]);
      acc[2 * j + 1] = fmaf(p, __uint_as_float(vv[j] & 0xffff0000u), acc[2 * j + 1]);
    }
  }
  __shared__ float sacc[8][16][9];
  __shared__ float sden[8][4];
#pragma unroll
  for (int j = 0; j < 8; ++j) sacc[slot][sl][j] = acc[j];
  if ((sl & 3) == 0) sden[slot][hd] = den;
  __syncthreads();
  if (tid < 16) {
    int hh = tid >> 2;
    float d = 0.f;
    float o[8] = {0.f, 0.f, 0.f, 0.f, 0.f, 0.f, 0.f, 0.f};
#pragma unroll
    for (int s2 = 0; s2 < 8; ++s2) {
      d += sden[s2][hh];
#pragma unroll
      for (int j = 0; j < 8; ++j) o[j] += sacc[s2][tid][j];
    }
    float inv = 1.f / d;
    uint_t pk[4];
#pragma unroll
    for (int j = 0; j < 4; ++j) {
      float v0 = fmaxf(fmaf(o[2 * j + 0], inv, bias[tid * 8 + 2 * j + 0]), 0.f);
      float v1 = fmaxf(fmaf(o[2 * j + 1], inv, bias[tid * 8 + 2 * j + 1]), 0.f);
      pk[j] = (uint_t)f2b(v0) | ((uint_t)f2b(v1) << 16);
    }
    uint4 pv = {pk[0], pk[1], pk[2], pk[3]};
    *(uint4*)(out + (long)n * 128 + tid * 8) = pv;
  }
}

__global__ __launch_bounds__(64) void gat_agg64_lsm(const ushort_t* __restrict__ h,
    const float* __restrict__ als, const float* __restrict__ ald,
    const int* __restrict__ rowptr, const int* __restrict__ esrc,
    const float* __restrict__ bias, float* __restrict__ out) {
  int n = blockIdx.x;
  int tid = threadIdx.x;
  int beg = rowptr[n], end = rowptr[n + 1];
  float aldv = ald[n];
  float m = -1e30f;
  for (int e = beg + tid; e < end; e += 64)
    m = fmaxf(m, lrelu(als[esrc[e]] + aldv));
#pragma unroll
  for (int off = 1; off <= 32; off <<= 1) m = fmaxf(m, __shfl_xor(m, off));
  int slot = tid >> 3, sl = tid & 7;
  float den = 0.f;
  float acc[8] = {0.f, 0.f, 0.f, 0.f, 0.f, 0.f, 0.f, 0.f};
  for (int e = beg + slot; e < end; e += 8) {
    int s = esrc[e];
    float p = __expf(lrelu(als[s] + aldv) - m);
    den += p;
    uint4 v = *(const uint4*)(h + (long)s * 64 + sl * 8);
    uint_t vv[4] = {v.x, v.y, v.z, v.w};
#pragma unroll
    for (int j = 0; j < 4; ++j) {
      acc[2 * j + 0] = fmaf(p, __uint_as_float(vv[j] << 16), acc[2 * j + 0]);
      acc[2 * j + 1] = fmaf(p, __uint_as_float(vv[j] & 0xffff0000u), acc[2 * j + 1]);
    }
  }
  __shared__ float sacc[8][8][9];
  __shared__ float sden[8];
#pragma unroll
  for (int j = 0; j < 8; ++j) sacc[slot][sl][j] = acc[j];
  if (sl == 0) sden[slot] = den;
  __syncthreads();
  if (tid < 8) {
    float d = 0.f;
    float o[8] = {0.f, 0.f, 0.f, 0.f, 0.f, 0.f, 0.f, 0.f};
#pragma unroll
    for (int s2 = 0; s2 < 8; ++s2) {
      d += sden[s2];
#pragma unroll
      for (int j = 0; j < 8; ++j) o[j] += sacc[s2][tid][j];
    }
    float inv = 1.f / d;
    float v[8];
#pragma unroll
    for (int j = 0; j < 8; ++j) v[j] = fmaf(o[j], inv, bias[tid * 8 + j]);
    float lm = v[0];
#pragma unroll
    for (int j = 1; j < 8; ++j) lm = fmaxf(lm, v[j]);
#pragma unroll
    for (int off = 1; off <= 4; off <<= 1) lm = fmaxf(lm, __shfl_xor(lm, off));
    float es = 0.f;
#pragma unroll
    for (int j = 0; j < 8; ++j) es += __expf(v[j] - lm);
#pragma unroll
    for (int off = 1; off <= 4; off <<= 1) es += __shfl_xor(es, off);
    float lse = lm + __logf(es);
    float4 o0 = {v[0] - lse, v[1] - lse, v[2] - lse, v[3] - lse};
    float4 o1 = {v[4] - lse, v[5] - lse, v[6] - lse, v[7] - lse};
    *(float4*)(out + (long)n * 64 + tid * 8 + 0) = o0;
    *(float4*)(out + (long)n * 64 + tid * 8 + 4) = o1;
  }
}

// ---------------- launch ----------------

extern "C" void kernel_launch(void* const* d_in, const int* in_sizes, int n_in,
                              void* d_out, int out_size, void* d_ws, size_t ws_size,
                              hipStream_t stream) {
  const float* x   = (const float*)d_in[0];
  const int*   ei  = (const int*)d_in[1];
  const float* w1  = (const float*)d_in[2];
  const float* as1 = (const float*)d_in[3];
  const float* ad1 = (const float*)d_in[4];
  const float* b1  = (const float*)d_in[5];
  const float* w2  = (const float*)d_in[6];
  const float* as2 = (const float*)d_in[7];
  const float* ad2 = (const float*)d_in[8];
  const float* b2  = (const float*)d_in[9];
  const float* w3  = (const float*)d_in[10];
  const float* as3 = (const float*)d_in[11];
  const float* ad3 = (const float*)d_in[12];
  const float* b3  = (const float*)d_in[13];
  float* out = (float*)d_out;

  const int N = in_sizes[0] / 128;
  const int E = in_sizes[1] / 2;
  const int ET = E + N;

  char* ws = (char*)d_ws;
  size_t off = 0;
  auto alloc = [&](size_t bytes) -> void* {
    void* p = ws + off;
    off += (bytes + 255) & ~(size_t)255;
    return p;
  };
  ushort_t* bufA = (ushort_t*)alloc((size_t)N * 128 * 2);  // h (bf16)
  ushort_t* bufB = (ushort_t*)alloc((size_t)N * 128 * 2);  // layer outputs (bf16)
  float* als   = (float*)alloc((size_t)N * 4 * 4);
  float* ald   = (float*)alloc((size_t)N * 4 * 4);
  int* cnt     = (int*)alloc((size_t)N * PAD * 4);   // padded: 1 counter / 64B line
  int* rowptr  = (int*)alloc((size_t)(N + 1) * 4);
  int* cursor  = (int*)alloc((size_t)N * PAD * 4);   // padded
  int* bsum    = (int*)alloc((size_t)1024 * 4);
  int* esrc    = (int*)alloc((size_t)ET * 4);

  const int tpb = 256;
  const int egrid = (ET + tpb - 1) / tpb;
  const int ggrid = (N + 63) / 64;
  const int albk = (N + 15) / 16;
  const int nb = (N + 1023) / 1024;

  hipMemsetAsync(cnt, 0, (size_t)N * PAD * 4, stream);
  // fused: gemm layer1 (independent) || edge count
  k_gemm1_count<<<ggrid + egrid, tpb, 0, stream>>>(x, w1, bufA, N, ei, cnt, E, ggrid);
  scan_blocks<<<nb, 256, 0, stream>>>(cnt, rowptr, bsum, N);
  scan_sums<<<1, 1024, 0, stream>>>(bsum, nb);
  scan_add<<<nb, 256, 0, stream>>>(cnt, rowptr, cursor, bsum, N);
  // fused: al coefficients layer1 || CSR scatter
  k_al4_scatter<<<albk + egrid, tpb, 0, stream>>>(bufA, as1, ad1, als, ald, N,
                                                  ei, cursor, esrc, E, albk);
  gat_agg128<<<N, 128, 0, stream>>>(bufA, als, ald, rowptr, esrc, b1, bufB);

  // ---- layer 2 ----
  gemm_tile<128, true><<<ggrid, 256, 0, stream>>>(bufB, w2, bufA, N);
  al_kernel4<<<albk, 256, 0, stream>>>(bufA, as2, ad2, als, ald, N);
  gat_agg128<<<N, 128, 0, stream>>>(bufA, als, ald, rowptr, esrc, b2, bufB);

  // ---- layer 3 ----
  gemm_tile<64, true><<<ggrid, 256, 0, stream>>>(bufB, w3, bufA, N);
  al_kernel1<<<(N + 31) / 32, 256, 0, stream>>>(bufA, as3, ad3, als, ald, N);
  gat_agg64_lsm<<<N, 64, 0, stream>>>(bufA, als, ald, rowptr, esrc, b3, out);
}

// Round 7
// 348.822 us; speedup vs baseline: 2.4860x; 1.1804x over previous
//
#include <hip/hip_runtime.h>
#include <hip/hip_bf16.h>
#include <math.h>

#define SLOPE 0.2f
typedef unsigned int uint_t;
typedef unsigned short ushort_t;

static __device__ __forceinline__ float lrelu(float v) { return v > 0.f ? v : SLOPE * v; }
// float -> bf16 bits, round-to-nearest-even
static __device__ __forceinline__ ushort_t f2b(float f) {
  uint_t u = __float_as_uint(f);
  u += 0x7fffu + ((u >> 16) & 1u);
  return (ushort_t)(u >> 16);
}

// ================= CSR build: atomic-free MSD bucket sort by dst =================
// Global atomics write 64B lines through to HBM (~12 G atomics/s measured r5/r6);
// instead: block histograms + scan + LDS-atomic ranks. Order within a dst segment
// is arbitrary (reference only sums per segment).

// Stage H: per-block histogram of dst>>8. ts[digit * NB + block] = count.
__global__ __launch_bounds__(256) void hist_kernel(const int* __restrict__ ei,
                                                   int* __restrict__ ts,
                                                   int E, int N, int NB, int NBUCK) {
  __shared__ int h[256];
  int tid = threadIdx.x, b = blockIdx.x;
  h[tid] = 0;
  __syncthreads();
  int ET = E + N;
  int base = b * 4096;
#pragma unroll
  for (int j = 0; j < 16; ++j) {
    int i = base + j * 256 + tid;
    if (i < ET) {
      int d = (i < E) ? ei[E + i] : (i - E);
      atomicAdd(&h[d >> 8], 1);
    }
  }
  __syncthreads();
  if (tid < NBUCK) ts[tid * NB + b] = h[tid];
}

// Hierarchical exclusive scan of a[0..L-1], in place. 1024 elems/block.
__global__ __launch_bounds__(256) void scan1(int* __restrict__ a, int* __restrict__ bsum, int L) {
  int tid = threadIdx.x;
  int base = blockIdx.x * 1024 + tid * 4;
  int c0 = (base + 0 < L) ? a[base + 0] : 0;
  int c1 = (base + 1 < L) ? a[base + 1] : 0;
  int c2 = (base + 2 < L) ? a[base + 2] : 0;
  int c3 = (base + 3 < L) ? a[base + 3] : 0;
  int s = c0 + c1 + c2 + c3;
  int lane = tid & 63, wid = tid >> 6;
  int pre = s;
#pragma unroll
  for (int off = 1; off < 64; off <<= 1) {
    int t = __shfl_up(pre, off);
    if (lane >= off) pre += t;
  }
  __shared__ int wsum[4];
  if (lane == 63) wsum[wid] = pre;
  __syncthreads();
  int woff = 0;
#pragma unroll
  for (int w = 0; w < 4; ++w) woff += (w < wid) ? wsum[w] : 0;
  int excl = woff + pre - s;
  if (base + 0 < L) a[base + 0] = excl;
  if (base + 1 < L) a[base + 1] = excl + c0;
  if (base + 2 < L) a[base + 2] = excl + c0 + c1;
  if (base + 3 < L) a[base + 3] = excl + c0 + c1 + c2;
  if (tid == 255) bsum[blockIdx.x] = wsum[0] + wsum[1] + wsum[2] + wsum[3];
}

__global__ __launch_bounds__(1024) void scan2(int* __restrict__ bsum, int nb) {
  __shared__ int sh[1024];
  int tid = threadIdx.x;
  int v = (tid < nb) ? bsum[tid] : 0;
  sh[tid] = v;
  __syncthreads();
  for (int off = 1; off < 1024; off <<= 1) {
    int add = (tid >= off) ? sh[tid - off] : 0;
    __syncthreads();
    sh[tid] += add;
    __syncthreads();
  }
  if (tid < nb) bsum[tid] = sh[tid] - v;
}

__global__ __launch_bounds__(256) void scan3(int* __restrict__ a, const int* __restrict__ bsum, int L) {
  int tid = threadIdx.x;
  int base = blockIdx.x * 1024 + tid * 4;
  if (base >= L) return;
  int off = bsum[blockIdx.x];
#pragma unroll
  for (int j = 0; j < 4; ++j)
    if (base + j < L) a[base + j] += off;
}

// Stage R: partition edges into buckets. pos from LDS-atomic rank seeded by ts.
__global__ __launch_bounds__(256) void part_kernel(const int* __restrict__ ei,
                                                   const int* __restrict__ ts,
                                                   uint_t* __restrict__ tmp,
                                                   int E, int N, int NB, int NBUCK) {
  __shared__ int bin[256];
  int tid = threadIdx.x, b = blockIdx.x;
  if (tid < NBUCK) bin[tid] = ts[tid * NB + b];
  __syncthreads();
  int ET = E + N;
  int base = b * 4096;
#pragma unroll
  for (int j = 0; j < 16; ++j) {
    int i = base + j * 256 + tid;
    if (i < ET) {
      int s, d;
      if (i < E) { s = ei[i]; d = ei[E + i]; } else { s = i - E; d = i - E; }
      int pos = atomicAdd(&bin[d >> 8], 1);
      tmp[pos] = ((uint_t)d << 16) | (uint_t)s;
    }
  }
}

// Stage L: per-bucket counting sort by dst&255; emits esrc + rowptr (incl rowptr[N]).
__global__ __launch_bounds__(256) void bucket_kernel(const uint_t* __restrict__ tmp,
                                                     const int* __restrict__ ts,
                                                     int* __restrict__ rowptr,
                                                     int* __restrict__ esrc,
                                                     int N, int NB, int NBUCK, int ET) {
  __shared__ int h[256], pref[256], rank[256];
  __shared__ int wsum[4];
  int tid = threadIdx.x, d = blockIdx.x;
  int start = ts[d * NB];
  int end = (d == NBUCK - 1) ? ET : ts[(d + 1) * NB];
  h[tid] = 0; rank[tid] = 0;
  __syncthreads();
  for (int i = start + tid; i < end; i += 256)
    atomicAdd(&h[(tmp[i] >> 16) & 255], 1);
  __syncthreads();
  int v = h[tid];
  int lane = tid & 63, wid = tid >> 6;
  int inc = v;
#pragma unroll
  for (int off = 1; off < 64; off <<= 1) {
    int t = __shfl_up(inc, off);
    if (lane >= off) inc += t;
  }
  if (lane == 63) wsum[wid] = inc;
  __syncthreads();
  int woff = 0;
#pragma unroll
  for (int w = 0; w < 4; ++w) woff += (w < wid) ? wsum[w] : 0;
  pref[tid] = woff + inc - v;
  __syncthreads();
  int idx = d * 256 + tid;
  if (idx <= N) rowptr[idx] = start + pref[tid];
  for (int i = start + tid; i < end; i += 256) {
    uint_t v2 = tmp[i];
    int low = (v2 >> 16) & 255;
    int r = atomicAdd(&rank[low], 1);
    esrc[start + pref[low] + r] = (int)(v2 & 0xffffu);
  }
}

// ================= GEMM: H[N,OC](bf16) = X[N,128](f32|bf16) @ W[128,OC](f32) =================

template<int OC, bool BF16IN>
__global__ __launch_bounds__(256) void gemm_tile(const void* __restrict__ Xv,
                                                 const float* __restrict__ W,
                                                 ushort_t* __restrict__ H, int N) {
  const int K = 128;
  const int CT = OC / 4;             // 32 (OC=128) / 16 (OC=64)
  const int RPT = 64 / (256 / CT);   // 8 / 4
  __shared__ float xs[K][68];
  int tid = threadIdx.x;
  long row0 = (long)blockIdx.x * 64;
  if (BF16IN) {
    const ushort_t* X = (const ushort_t*)Xv;
#pragma unroll
    for (int i = 0; i < 4; ++i) {
      int flat = i * 256 + tid;
      int r = flat & 63, kc = flat >> 6;
      long row = row0 + r;
      long rr = row < N ? row : (long)(N - 1);
      uint4 v = *(const uint4*)(X + rr * K + kc * 8);
      uint_t vv[4] = {v.x, v.y, v.z, v.w};
#pragma unroll
      for (int j = 0; j < 4; ++j) {
        xs[kc * 8 + j * 2 + 0][r] = __uint_as_float(vv[j] << 16);
        xs[kc * 8 + j * 2 + 1][r] = __uint_as_float(vv[j] & 0xffff0000u);
      }
    }
  } else {
    const float* X = (const float*)Xv;
#pragma unroll
    for (int i = 0; i < 8; ++i) {
      int flat = i * 256 + tid;
      int r = flat & 63, kc = flat >> 6;
      long row = row0 + r;
      long rr = row < N ? row : (long)(N - 1);
      float4 xv = *(const float4*)(X + rr * K + kc * 4);
      xs[kc * 4 + 0][r] = xv.x;
      xs[kc * 4 + 1][r] = xv.y;
      xs[kc * 4 + 2][r] = xv.z;
      xs[kc * 4 + 3][r] = xv.w;
    }
  }
  __syncthreads();
  int ct = tid % CT;
  int rg = tid / CT;
  int c0 = ct * 4;
  int r0 = rg * RPT;
  float acc[RPT][4];
#pragma unroll
  for (int i = 0; i < RPT; ++i)
    for (int j = 0; j < 4; ++j) acc[i][j] = 0.f;
#pragma unroll 4
  for (int k = 0; k < K; ++k) {
    float4 wv = *(const float4*)(W + (long)k * OC + c0);
    const float4* xr = (const float4*)(&xs[k][r0]);
#pragma unroll
    for (int i4 = 0; i4 < RPT / 4; ++i4) {
      float4 xv = xr[i4];
      float xa[4] = {xv.x, xv.y, xv.z, xv.w};
#pragma unroll
      for (int j = 0; j < 4; ++j) {
        int i = i4 * 4 + j;
        acc[i][0] = fmaf(xa[j], wv.x, acc[i][0]);
        acc[i][1] = fmaf(xa[j], wv.y, acc[i][1]);
        acc[i][2] = fmaf(xa[j], wv.z, acc[i][2]);
        acc[i][3] = fmaf(xa[j], wv.w, acc[i][3]);
      }
    }
  }
#pragma unroll
  for (int i = 0; i < RPT; ++i) {
    long row = row0 + r0 + i;
    if (row < N) {
      ushort4 o = {f2b(acc[i][0]), f2b(acc[i][1]), f2b(acc[i][2]), f2b(acc[i][3])};
      *(ushort4*)(H + row * OC + c0) = o;
    }
  }
}

// ================= attention coefficients per node (bf16 h) =================

__global__ void al_kernel4(const ushort_t* __restrict__ h, const float* __restrict__ a_s,
                           const float* __restrict__ a_d, float* __restrict__ als,
                           float* __restrict__ ald, int N) {
  int tid = threadIdx.x;
  int n = blockIdx.x * 16 + (tid >> 4);
  int sl = tid & 15, hd = sl >> 2;
  if (n >= N) return;
  uint4 v = *(const uint4*)(h + (long)n * 128 + sl * 8);
  uint_t vv[4] = {v.x, v.y, v.z, v.w};
  const float* sp = a_s + hd * 32 + (sl & 3) * 8;
  const float* dp = a_d + hd * 32 + (sl & 3) * 8;
  float vs = 0.f, vd = 0.f;
#pragma unroll
  for (int j = 0; j < 4; ++j) {
    float h0 = __uint_as_float(vv[j] << 16);
    float h1 = __uint_as_float(vv[j] & 0xffff0000u);
    vs = fmaf(h0, sp[j * 2 + 0], vs); vs = fmaf(h1, sp[j * 2 + 1], vs);
    vd = fmaf(h0, dp[j * 2 + 0], vd); vd = fmaf(h1, dp[j * 2 + 1], vd);
  }
#pragma unroll
  for (int off = 1; off <= 2; off <<= 1) {
    vs += __shfl_xor(vs, off);
    vd += __shfl_xor(vd, off);
  }
  if ((sl & 3) == 0) { als[(long)n * 4 + hd] = vs; ald[(long)n * 4 + hd] = vd; }
}

__global__ void al_kernel1(const ushort_t* __restrict__ h, const float* __restrict__ a_s,
                           const float* __restrict__ a_d, float* __restrict__ als,
                           float* __restrict__ ald, int N) {
  int tid = threadIdx.x;
  int n = blockIdx.x * 32 + (tid >> 3);
  int sl = tid & 7;
  if (n >= N) return;
  uint4 v = *(const uint4*)(h + (long)n * 64 + sl * 8);
  uint_t vv[4] = {v.x, v.y, v.z, v.w};
  const float* sp = a_s + sl * 8;
  const float* dp = a_d + sl * 8;
  float vs = 0.f, vd = 0.f;
#pragma unroll
  for (int j = 0; j < 4; ++j) {
    float h0 = __uint_as_float(vv[j] << 16);
    float h1 = __uint_as_float(vv[j] & 0xffff0000u);
    vs = fmaf(h0, sp[j * 2 + 0], vs); vs = fmaf(h1, sp[j * 2 + 1], vs);
    vd = fmaf(h0, dp[j * 2 + 0], vd); vd = fmaf(h1, dp[j * 2 + 1], vd);
  }
#pragma unroll
  for (int off = 1; off <= 4; off <<= 1) {
    vs += __shfl_xor(vs, off);
    vd += __shfl_xor(vd, off);
  }
  if (sl == 0) { als[n] = vs; ald[n] = vd; }
}

// ================= two-phase softmax aggregation, 4-edge batched gathers =================

__global__ __launch_bounds__(128) void gat_agg128(const ushort_t* __restrict__ h,
    const float* __restrict__ als, const float* __restrict__ ald,
    const int* __restrict__ rowptr, const int* __restrict__ esrc,
    const float* __restrict__ bias, ushort_t* __restrict__ out) {
  int n = blockIdx.x;
  int tid = threadIdx.x;
  int beg = rowptr[n], end = rowptr[n + 1];
  // phase 1: per-head max over logits
  int hd1 = tid & 3;
  float aldv1 = ald[(long)n * 4 + hd1];
  float m = -1e30f;
  for (int e = beg + (tid >> 2); e < end; e += 32)
    m = fmaxf(m, lrelu(als[(long)esrc[e] * 4 + hd1] + aldv1));
#pragma unroll
  for (int off = 4; off <= 32; off <<= 1) m = fmaxf(m, __shfl_xor(m, off));
  __shared__ float sm[2][4];
  if ((tid & 63) < 4) sm[tid >> 6][hd1] = m;
  __syncthreads();
  // phase 2: 8 slots x 16 lanes, 4 edges batched per round
  int slot = tid >> 4, sl = tid & 15, hd = sl >> 2;
  float mh = fmaxf(sm[0][hd], sm[1][hd]);
  float aldv = ald[(long)n * 4 + hd];
  float den = 0.f;
  float acc[8] = {0.f, 0.f, 0.f, 0.f, 0.f, 0.f, 0.f, 0.f};
  for (int base = beg + slot; base < end; base += 32) {
    int ss[4];
#pragma unroll
    for (int b = 0; b < 4; ++b) {
      int e = base + b * 8;
      ss[b] = (e < end) ? esrc[e] : -1;
    }
    float pv[4]; uint4 hv[4];
#pragma unroll
    for (int b = 0; b < 4; ++b) {
      if (ss[b] >= 0) {
        pv[b] = als[(long)ss[b] * 4 + hd];
        hv[b] = *(const uint4*)(h + (long)ss[b] * 128 + sl * 8);
      } else {
        pv[b] = -1e30f;
        hv[b] = make_uint4(0u, 0u, 0u, 0u);
      }
    }
#pragma unroll
    for (int b = 0; b < 4; ++b) {
      float p = __expf(lrelu(pv[b] + aldv) - mh);
      den += p;
      uint_t vv[4] = {hv[b].x, hv[b].y, hv[b].z, hv[b].w};
#pragma unroll
      for (int j = 0; j < 4; ++j) {
        acc[2 * j + 0] = fmaf(p, __uint_as_float(vv[j] << 16), acc[2 * j + 0]);
        acc[2 * j + 1] = fmaf(p, __uint_as_float(vv[j] & 0xffff0000u), acc[2 * j + 1]);
      }
    }
  }
  __shared__ float sacc[8][16][9];
  __shared__ float sden[8][4];
#pragma unroll
  for (int j = 0; j < 8; ++j) sacc[slot][sl][j] = acc[j];
  if ((sl & 3) == 0) sden[slot][hd] = den;
  __syncthreads();
  if (tid < 16) {
    int hh = tid >> 2;
    float d = 0.f;
    float o[8] = {0.f, 0.f, 0.f, 0.f, 0.f, 0.f, 0.f, 0.f};
#pragma unroll
    for (int s2 = 0; s2 < 8; ++s2) {
      d += sden[s2][hh];
#pragma unroll
      for (int j = 0; j < 8; ++j) o[j] += sacc[s2][tid][j];
    }
    float inv = 1.f / d;
    uint_t pk[4];
#pragma unroll
    for (int j = 0; j < 4; ++j) {
      float v0 = fmaxf(fmaf(o[2 * j + 0], inv, bias[tid * 8 + 2 * j + 0]), 0.f);
      float v1 = fmaxf(fmaf(o[2 * j + 1], inv, bias[tid * 8 + 2 * j + 1]), 0.f);
      pk[j] = (uint_t)f2b(v0) | ((uint_t)f2b(v1) << 16);
    }
    uint4 pv2 = {pk[0], pk[1], pk[2], pk[3]};
    *(uint4*)(out + (long)n * 128 + tid * 8) = pv2;
  }
}

__global__ __launch_bounds__(64) void gat_agg64_lsm(const ushort_t* __restrict__ h,
    const float* __restrict__ als, const float* __restrict__ ald,
    const int* __restrict__ rowptr, const int* __restrict__ esrc,
    const float* __restrict__ bias, float* __restrict__ out) {
  int n = blockIdx.x;
  int tid = threadIdx.x;
  int beg = rowptr[n], end = rowptr[n + 1];
  float aldv = ald[n];
  float m = -1e30f;
  for (int e = beg + tid; e < end; e += 64)
    m = fmaxf(m, lrelu(als[esrc[e]] + aldv));
#pragma unroll
  for (int off = 1; off <= 32; off <<= 1) m = fmaxf(m, __shfl_xor(m, off));
  int slot = tid >> 3, sl = tid & 7;
  float den = 0.f;
  float acc[8] = {0.f, 0.f, 0.f, 0.f, 0.f, 0.f, 0.f, 0.f};
  for (int base = beg + slot; base < end; base += 32) {
    int ss[4];
#pragma unroll
    for (int b = 0; b < 4; ++b) {
      int e = base + b * 8;
      ss[b] = (e < end) ? esrc[e] : -1;
    }
    float pv[4]; uint4 hv[4];
#pragma unroll
    for (int b = 0; b < 4; ++b) {
      if (ss[b] >= 0) {
        pv[b] = als[ss[b]];
        hv[b] = *(const uint4*)(h + (long)ss[b] * 64 + sl * 8);
      } else {
        pv[b] = -1e30f;
        hv[b] = make_uint4(0u, 0u, 0u, 0u);
      }
    }
#pragma unroll
    for (int b = 0; b < 4; ++b) {
      float p = __expf(lrelu(pv[b] + aldv) - m);
      den += p;
      uint_t vv[4] = {hv[b].x, hv[b].y, hv[b].z, hv[b].w};
#pragma unroll
      for (int j = 0; j < 4; ++j) {
        acc[2 * j + 0] = fmaf(p, __uint_as_float(vv[j] << 16), acc[2 * j + 0]);
        acc[2 * j + 1] = fmaf(p, __uint_as_float(vv[j] & 0xffff0000u), acc[2 * j + 1]);
      }
    }
  }
  __shared__ float sacc[8][8][9];
  __shared__ float sden[8];
#pragma unroll
  for (int j = 0; j < 8; ++j) sacc[slot][sl][j] = acc[j];
  if (sl == 0) sden[slot] = den;
  __syncthreads();
  if (tid < 8) {
    float d = 0.f;
    float o[8] = {0.f, 0.f, 0.f, 0.f, 0.f, 0.f, 0.f, 0.f};
#pragma unroll
    for (int s2 = 0; s2 < 8; ++s2) {
      d += sden[s2];
#pragma unroll
      for (int j = 0; j < 8; ++j) o[j] += sacc[s2][tid][j];
    }
    float inv = 1.f / d;
    float v[8];
#pragma unroll
    for (int j = 0; j < 8; ++j) v[j] = fmaf(o[j], inv, bias[tid * 8 + j]);
    float lm = v[0];
#pragma unroll
    for (int j = 1; j < 8; ++j) lm = fmaxf(lm, v[j]);
#pragma unroll
    for (int off = 1; off <= 4; off <<= 1) lm = fmaxf(lm, __shfl_xor(lm, off));
    float es = 0.f;
#pragma unroll
    for (int j = 0; j < 8; ++j) es += __expf(v[j] - lm);
#pragma unroll
    for (int off = 1; off <= 4; off <<= 1) es += __shfl_xor(es, off);
    float lse = lm + __logf(es);
    float4 o0 = {v[0] - lse, v[1] - lse, v[2] - lse, v[3] - lse};
    float4 o1 = {v[4] - lse, v[5] - lse, v[6] - lse, v[7] - lse};
    *(float4*)(out + (long)n * 64 + tid * 8 + 0) = o0;
    *(float4*)(out + (long)n * 64 + tid * 8 + 4) = o1;
  }
}

// ================= launch =================

extern "C" void kernel_launch(void* const* d_in, const int* in_sizes, int n_in,
                              void* d_out, int out_size, void* d_ws, size_t ws_size,
                              hipStream_t stream) {
  const float* x   = (const float*)d_in[0];
  const int*   ei  = (const int*)d_in[1];
  const float* w1  = (const float*)d_in[2];
  const float* as1 = (const float*)d_in[3];
  const float* ad1 = (const float*)d_in[4];
  const float* b1  = (const float*)d_in[5];
  const float* w2  = (const float*)d_in[6];
  const float* as2 = (const float*)d_in[7];
  const float* ad2 = (const float*)d_in[8];
  const float* b2  = (const float*)d_in[9];
  const float* w3  = (const float*)d_in[10];
  const float* as3 = (const float*)d_in[11];
  const float* ad3 = (const float*)d_in[12];
  const float* b3  = (const float*)d_in[13];
  float* out = (float*)d_out;

  const int N = in_sizes[0] / 128;
  const int E = in_sizes[1] / 2;
  const int ET = E + N;

  const int NB = (ET + 4095) / 4096;      // partition blocks
  const int NBUCK = (N + 255) >> 8;       // buckets (dst>>8)
  const int SL = NBUCK * NB;              // scan length
  const int nsb = (SL + 1023) / 1024;     // scan1/3 blocks

  char* ws = (char*)d_ws;
  size_t off = 0;
  auto alloc = [&](size_t bytes) -> void* {
    void* p = ws + off;
    off += (bytes + 255) & ~(size_t)255;
    return p;
  };
  ushort_t* bufA = (ushort_t*)alloc((size_t)N * 128 * 2);
  ushort_t* bufB = (ushort_t*)alloc((size_t)N * 128 * 2);
  float* als   = (float*)alloc((size_t)N * 4 * 4);
  float* ald   = (float*)alloc((size_t)N * 4 * 4);
  int* ts      = (int*)alloc((size_t)SL * 4);
  int* bsum    = (int*)alloc((size_t)1024 * 4);
  uint_t* tmp  = (uint_t*)alloc((size_t)ET * 4);
  int* rowptr  = (int*)alloc((size_t)(N + 1) * 4);
  int* esrc    = (int*)alloc((size_t)ET * 4);

  const int ggrid = (N + 63) / 64;
  const int albk = (N + 15) / 16;

  // CSR build (atomic-free bucket sort), once per launch
  hist_kernel<<<NB, 256, 0, stream>>>(ei, ts, E, N, NB, NBUCK);
  scan1<<<nsb, 256, 0, stream>>>(ts, bsum, SL);
  scan2<<<1, 1024, 0, stream>>>(bsum, nsb);
  scan3<<<nsb, 256, 0, stream>>>(ts, bsum, SL);
  part_kernel<<<NB, 256, 0, stream>>>(ei, ts, tmp, E, N, NB, NBUCK);
  bucket_kernel<<<NBUCK, 256, 0, stream>>>(tmp, ts, rowptr, esrc, N, NB, NBUCK, ET);

  // ---- layer 1: x(f32) -> bufA(h, bf16) -> bufB(bf16) ----
  gemm_tile<128, false><<<ggrid, 256, 0, stream>>>(x, w1, bufA, N);
  al_kernel4<<<albk, 256, 0, stream>>>(bufA, as1, ad1, als, ald, N);
  gat_agg128<<<N, 128, 0, stream>>>(bufA, als, ald, rowptr, esrc, b1, bufB);

  // ---- layer 2 ----
  gemm_tile<128, true><<<ggrid, 256, 0, stream>>>(bufB, w2, bufA, N);
  al_kernel4<<<albk, 256, 0, stream>>>(bufA, as2, ad2, als, ald, N);
  gat_agg128<<<N, 128, 0, stream>>>(bufA, als, ald, rowptr, esrc, b2, bufB);

  // ---- layer 3 ----
  gemm_tile<64, true><<<ggrid, 256, 0, stream>>>(bufB, w3, bufA, N);
  al_kernel1<<<(N + 31) / 32, 256, 0, stream>>>(bufA, as3, ad3, als, ald, N);
  gat_agg64_lsm<<<N, 64, 0, stream>>>(bufA, als, ald, rowptr, esrc, b3, out);
}

// Round 8
// 325.032 us; speedup vs baseline: 2.6680x; 1.0732x over previous
//
#include <hip/hip_runtime.h>
#include <hip/hip_bf16.h>
#include <math.h>

#define SLOPE 0.2f
typedef unsigned int uint_t;
typedef unsigned short ushort_t;

static __device__ __forceinline__ float lrelu(float v) { return v > 0.f ? v : SLOPE * v; }
// float -> bf16 bits, round-to-nearest-even
static __device__ __forceinline__ ushort_t f2b(float f) {
  uint_t u = __float_as_uint(f);
  u += 0x7fffu + ((u >> 16) & 1u);
  return (ushort_t)(u >> 16);
}

// ================= CSR build: atomic-free MSD bucket sort by dst =================
// Global atomics write 64B lines through to HBM (~12 G atomics/s measured r5/r6);
// instead: block histograms + scan + LDS-atomic ranks. Order within a dst segment
// is arbitrary (reference only sums per segment).

__global__ __launch_bounds__(256) void hist_kernel(const int* __restrict__ ei,
                                                   int* __restrict__ ts,
                                                   int E, int N, int NB, int NBUCK) {
  __shared__ int h[256];
  int tid = threadIdx.x, b = blockIdx.x;
  h[tid] = 0;
  __syncthreads();
  int ET = E + N;
  int base = b * 4096;
#pragma unroll
  for (int j = 0; j < 16; ++j) {
    int i = base + j * 256 + tid;
    if (i < ET) {
      int d = (i < E) ? ei[E + i] : (i - E);
      atomicAdd(&h[d >> 8], 1);
    }
  }
  __syncthreads();
  if (tid < NBUCK) ts[tid * NB + b] = h[tid];
}

__global__ __launch_bounds__(256) void scan1(int* __restrict__ a, int* __restrict__ bsum, int L) {
  int tid = threadIdx.x;
  int base = blockIdx.x * 1024 + tid * 4;
  int c0 = (base + 0 < L) ? a[base + 0] : 0;
  int c1 = (base + 1 < L) ? a[base + 1] : 0;
  int c2 = (base + 2 < L) ? a[base + 2] : 0;
  int c3 = (base + 3 < L) ? a[base + 3] : 0;
  int s = c0 + c1 + c2 + c3;
  int lane = tid & 63, wid = tid >> 6;
  int pre = s;
#pragma unroll
  for (int off = 1; off < 64; off <<= 1) {
    int t = __shfl_up(pre, off);
    if (lane >= off) pre += t;
  }
  __shared__ int wsum[4];
  if (lane == 63) wsum[wid] = pre;
  __syncthreads();
  int woff = 0;
#pragma unroll
  for (int w = 0; w < 4; ++w) woff += (w < wid) ? wsum[w] : 0;
  int excl = woff + pre - s;
  if (base + 0 < L) a[base + 0] = excl;
  if (base + 1 < L) a[base + 1] = excl + c0;
  if (base + 2 < L) a[base + 2] = excl + c0 + c1;
  if (base + 3 < L) a[base + 3] = excl + c0 + c1 + c2;
  if (tid == 255) bsum[blockIdx.x] = wsum[0] + wsum[1] + wsum[2] + wsum[3];
}

__global__ __launch_bounds__(1024) void scan2(int* __restrict__ bsum, int nb) {
  __shared__ int sh[1024];
  int tid = threadIdx.x;
  int v = (tid < nb) ? bsum[tid] : 0;
  sh[tid] = v;
  __syncthreads();
  for (int off = 1; off < 1024; off <<= 1) {
    int add = (tid >= off) ? sh[tid - off] : 0;
    __syncthreads();
    sh[tid] += add;
    __syncthreads();
  }
  if (tid < nb) bsum[tid] = sh[tid] - v;
}

__global__ __launch_bounds__(256) void scan3(int* __restrict__ a, const int* __restrict__ bsum, int L) {
  int tid = threadIdx.x;
  int base = blockIdx.x * 1024 + tid * 4;
  if (base >= L) return;
  int off = bsum[blockIdx.x];
#pragma unroll
  for (int j = 0; j < 4; ++j)
    if (base + j < L) a[base + j] += off;
}

__global__ __launch_bounds__(256) void part_kernel(const int* __restrict__ ei,
                                                   const int* __restrict__ ts,
                                                   uint_t* __restrict__ tmp,
                                                   int E, int N, int NB, int NBUCK) {
  __shared__ int bin[256];
  int tid = threadIdx.x, b = blockIdx.x;
  if (tid < NBUCK) bin[tid] = ts[tid * NB + b];
  __syncthreads();
  int ET = E + N;
  int base = b * 4096;
#pragma unroll
  for (int j = 0; j < 16; ++j) {
    int i = base + j * 256 + tid;
    if (i < ET) {
      int s, d;
      if (i < E) { s = ei[i]; d = ei[E + i]; } else { s = i - E; d = i - E; }
      int pos = atomicAdd(&bin[d >> 8], 1);
      tmp[pos] = ((uint_t)d << 16) | (uint_t)s;
    }
  }
}

__global__ __launch_bounds__(256) void bucket_kernel(const uint_t* __restrict__ tmp,
                                                     const int* __restrict__ ts,
                                                     int* __restrict__ rowptr,
                                                     int* __restrict__ esrc,
                                                     int N, int NB, int NBUCK, int ET) {
  __shared__ int h[256], pref[256], rank[256];
  __shared__ int wsum[4];
  int tid = threadIdx.x, d = blockIdx.x;
  int start = ts[d * NB];
  int end = (d == NBUCK - 1) ? ET : ts[(d + 1) * NB];
  h[tid] = 0; rank[tid] = 0;
  __syncthreads();
  for (int i = start + tid; i < end; i += 256)
    atomicAdd(&h[(tmp[i] >> 16) & 255], 1);
  __syncthreads();
  int v = h[tid];
  int lane = tid & 63, wid = tid >> 6;
  int inc = v;
#pragma unroll
  for (int off = 1; off < 64; off <<= 1) {
    int t = __shfl_up(inc, off);
    if (lane >= off) inc += t;
  }
  if (lane == 63) wsum[wid] = inc;
  __syncthreads();
  int woff = 0;
#pragma unroll
  for (int w = 0; w < 4; ++w) woff += (w < wid) ? wsum[w] : 0;
  pref[tid] = woff + inc - v;
  __syncthreads();
  int idx = d * 256 + tid;
  if (idx <= N) rowptr[idx] = start + pref[tid];
  for (int i = start + tid; i < end; i += 256) {
    uint_t v2 = tmp[i];
    int low = (v2 >> 16) & 255;
    int r = atomicAdd(&rank[low], 1);
    esrc[start + pref[low] + r] = (int)(v2 & 0xffffu);
  }
}

// ================= GEMM: H[N,OC](bf16) = X[N,128](f32|bf16) @ W[128,OC](f32) =================

template<int OC, bool BF16IN>
__global__ __launch_bounds__(256) void gemm_tile(const void* __restrict__ Xv,
                                                 const float* __restrict__ W,
                                                 ushort_t* __restrict__ H, int N) {
  const int K = 128;
  const int CT = OC / 4;             // 32 (OC=128) / 16 (OC=64)
  const int RPT = 64 / (256 / CT);   // 8 / 4
  __shared__ float xs[K][68];
  int tid = threadIdx.x;
  long row0 = (long)blockIdx.x * 64;
  if (BF16IN) {
    const ushort_t* X = (const ushort_t*)Xv;
#pragma unroll
    for (int i = 0; i < 4; ++i) {
      int flat = i * 256 + tid;
      int r = flat & 63, kc = flat >> 6;
      long row = row0 + r;
      long rr = row < N ? row : (long)(N - 1);
      uint4 v = *(const uint4*)(X + rr * K + kc * 8);
      uint_t vv[4] = {v.x, v.y, v.z, v.w};
#pragma unroll
      for (int j = 0; j < 4; ++j) {
        xs[kc * 8 + j * 2 + 0][r] = __uint_as_float(vv[j] << 16);
        xs[kc * 8 + j * 2 + 1][r] = __uint_as_float(vv[j] & 0xffff0000u);
      }
    }
  } else {
    const float* X = (const float*)Xv;
#pragma unroll
    for (int i = 0; i < 8; ++i) {
      int flat = i * 256 + tid;
      int r = flat & 63, kc = flat >> 6;
      long row = row0 + r;
      long rr = row < N ? row : (long)(N - 1);
      float4 xv = *(const float4*)(X + rr * K + kc * 4);
      xs[kc * 4 + 0][r] = xv.x;
      xs[kc * 4 + 1][r] = xv.y;
      xs[kc * 4 + 2][r] = xv.z;
      xs[kc * 4 + 3][r] = xv.w;
    }
  }
  __syncthreads();
  int ct = tid % CT;
  int rg = tid / CT;
  int c0 = ct * 4;
  int r0 = rg * RPT;
  float acc[RPT][4];
#pragma unroll
  for (int i = 0; i < RPT; ++i)
    for (int j = 0; j < 4; ++j) acc[i][j] = 0.f;
#pragma unroll 4
  for (int k = 0; k < K; ++k) {
    float4 wv = *(const float4*)(W + (long)k * OC + c0);
    const float4* xr = (const float4*)(&xs[k][r0]);
#pragma unroll
    for (int i4 = 0; i4 < RPT / 4; ++i4) {
      float4 xv = xr[i4];
      float xa[4] = {xv.x, xv.y, xv.z, xv.w};
#pragma unroll
      for (int j = 0; j < 4; ++j) {
        int i = i4 * 4 + j;
        acc[i][0] = fmaf(xa[j], wv.x, acc[i][0]);
        acc[i][1] = fmaf(xa[j], wv.y, acc[i][1]);
        acc[i][2] = fmaf(xa[j], wv.z, acc[i][2]);
        acc[i][3] = fmaf(xa[j], wv.w, acc[i][3]);
      }
    }
  }
#pragma unroll
  for (int i = 0; i < RPT; ++i) {
    long row = row0 + r0 + i;
    if (row < N) {
      ushort4 o = {f2b(acc[i][0]), f2b(acc[i][1]), f2b(acc[i][2]), f2b(acc[i][3])};
      *(ushort4*)(H + row * OC + c0) = o;
    }
  }
}

// ================= attention coefficients per node (bf16 h) =================

__global__ void al_kernel4(const ushort_t* __restrict__ h, const float* __restrict__ a_s,
                           const float* __restrict__ a_d, float* __restrict__ als,
                           float* __restrict__ ald, int N) {
  int tid = threadIdx.x;
  int n = blockIdx.x * 16 + (tid >> 4);
  int sl = tid & 15, hd = sl >> 2;
  if (n >= N) return;
  uint4 v = *(const uint4*)(h + (long)n * 128 + sl * 8);
  uint_t vv[4] = {v.x, v.y, v.z, v.w};
  const float* sp = a_s + hd * 32 + (sl & 3) * 8;
  const float* dp = a_d + hd * 32 + (sl & 3) * 8;
  float vs = 0.f, vd = 0.f;
#pragma unroll
  for (int j = 0; j < 4; ++j) {
    float h0 = __uint_as_float(vv[j] << 16);
    float h1 = __uint_as_float(vv[j] & 0xffff0000u);
    vs = fmaf(h0, sp[j * 2 + 0], vs); vs = fmaf(h1, sp[j * 2 + 1], vs);
    vd = fmaf(h0, dp[j * 2 + 0], vd); vd = fmaf(h1, dp[j * 2 + 1], vd);
  }
#pragma unroll
  for (int off = 1; off <= 2; off <<= 1) {
    vs += __shfl_xor(vs, off);
    vd += __shfl_xor(vd, off);
  }
  if ((sl & 3) == 0) { als[(long)n * 4 + hd] = vs; ald[(long)n * 4 + hd] = vd; }
}

__global__ void al_kernel1(const ushort_t* __restrict__ h, const float* __restrict__ a_s,
                           const float* __restrict__ a_d, float* __restrict__ als,
                           float* __restrict__ ald, int N) {
  int tid = threadIdx.x;
  int n = blockIdx.x * 32 + (tid >> 3);
  int sl = tid & 7;
  if (n >= N) return;
  uint4 v = *(const uint4*)(h + (long)n * 64 + sl * 8);
  uint_t vv[4] = {v.x, v.y, v.z, v.w};
  const float* sp = a_s + sl * 8;
  const float* dp = a_d + sl * 8;
  float vs = 0.f, vd = 0.f;
#pragma unroll
  for (int j = 0; j < 4; ++j) {
    float h0 = __uint_as_float(vv[j] << 16);
    float h1 = __uint_as_float(vv[j] & 0xffff0000u);
    vs = fmaf(h0, sp[j * 2 + 0], vs); vs = fmaf(h1, sp[j * 2 + 1], vs);
    vd = fmaf(h0, dp[j * 2 + 0], vd); vd = fmaf(h1, dp[j * 2 + 1], vd);
  }
#pragma unroll
  for (int off = 1; off <= 4; off <<= 1) {
    vs += __shfl_xor(vs, off);
    vd += __shfl_xor(vd, off);
  }
  if (sl == 0) { als[n] = vs; ald[n] = vd; }
}

// ================= softmax aggregation, no max-pass (m=0; logits bounded), =================
// ================= half-wave per node, shuffle-only combine                 =================

// 4 heads x 32 feats. 32 lanes (2 slots x 16) per node; 8 nodes per 256-block.
// p = exp(lrelu(als+ald)) directly (softmax shift-invariant; |logit| <~6).
__global__ __launch_bounds__(256) void gat_agg128(const ushort_t* __restrict__ h,
    const float* __restrict__ als, const float* __restrict__ ald,
    const int* __restrict__ rowptr, const int* __restrict__ esrc,
    const float* __restrict__ bias, ushort_t* __restrict__ out, int N) {
  int tid = threadIdx.x;
  int n = blockIdx.x * 8 + (tid >> 5);
  int l = tid & 31;
  int slot = l >> 4, sl = l & 15, hd = sl >> 2;
  if (n >= N) return;
  int beg = rowptr[n], end = rowptr[n + 1];
  float aldv = ald[(long)n * 4 + hd];
  float den = 0.f;
  float acc[8] = {0.f, 0.f, 0.f, 0.f, 0.f, 0.f, 0.f, 0.f};
  for (int e = beg + slot; e < end; e += 2) {
    int s = esrc[e];
    float p = __expf(lrelu(als[(long)s * 4 + hd] + aldv));
    den += p;
    uint4 v = *(const uint4*)(h + (long)s * 128 + sl * 8);
    uint_t vv[4] = {v.x, v.y, v.z, v.w};
#pragma unroll
    for (int j = 0; j < 4; ++j) {
      acc[2 * j + 0] = fmaf(p, __uint_as_float(vv[j] << 16), acc[2 * j + 0]);
      acc[2 * j + 1] = fmaf(p, __uint_as_float(vv[j] & 0xffff0000u), acc[2 * j + 1]);
    }
  }
  // combine the 2 slots (xor 16 stays within the 32-lane half-wave)
  den += __shfl_xor(den, 16);
#pragma unroll
  for (int j = 0; j < 8; ++j) acc[j] += __shfl_xor(acc[j], 16);
  if (slot == 0) {
    float inv = 1.f / den;
    float4 bv0 = *(const float4*)(bias + sl * 8);
    float4 bv1 = *(const float4*)(bias + sl * 8 + 4);
    float bb[8] = {bv0.x, bv0.y, bv0.z, bv0.w, bv1.x, bv1.y, bv1.z, bv1.w};
    uint_t pk[4];
#pragma unroll
    for (int j = 0; j < 4; ++j) {
      float v0 = fmaxf(fmaf(acc[2 * j + 0], inv, bb[2 * j + 0]), 0.f);
      float v1 = fmaxf(fmaf(acc[2 * j + 1], inv, bb[2 * j + 1]), 0.f);
      pk[j] = (uint_t)f2b(v0) | ((uint_t)f2b(v1) << 16);
    }
    uint4 pv = {pk[0], pk[1], pk[2], pk[3]};
    *(uint4*)(out + (long)n * 128 + sl * 8) = pv;
  }
}

// 1 head x 64 feats. 32 lanes (4 slots x 8) per node; 8 nodes per 256-block.
// Fused +bias + log_softmax over 64 classes, f32 out.
__global__ __launch_bounds__(256) void gat_agg64_lsm(const ushort_t* __restrict__ h,
    const float* __restrict__ als, const float* __restrict__ ald,
    const int* __restrict__ rowptr, const int* __restrict__ esrc,
    const float* __restrict__ bias, float* __restrict__ out, int N) {
  int tid = threadIdx.x;
  int n = blockIdx.x * 8 + (tid >> 5);
  int l = tid & 31;
  int slot = l >> 3, sl = l & 7;
  if (n >= N) return;
  int beg = rowptr[n], end = rowptr[n + 1];
  float aldv = ald[n];
  float den = 0.f;
  float acc[8] = {0.f, 0.f, 0.f, 0.f, 0.f, 0.f, 0.f, 0.f};
  for (int e = beg + slot; e < end; e += 4) {
    int s = esrc[e];
    float p = __expf(lrelu(als[s] + aldv));
    den += p;
    uint4 v = *(const uint4*)(h + (long)s * 64 + sl * 8);
    uint_t vv[4] = {v.x, v.y, v.z, v.w};
#pragma unroll
    for (int j = 0; j < 4; ++j) {
      acc[2 * j + 0] = fmaf(p, __uint_as_float(vv[j] << 16), acc[2 * j + 0]);
      acc[2 * j + 1] = fmaf(p, __uint_as_float(vv[j] & 0xffff0000u), acc[2 * j + 1]);
    }
  }
  // combine 4 slots: xor 8, 16 (stay within 32-lane half-wave)
  den += __shfl_xor(den, 8); den += __shfl_xor(den, 16);
#pragma unroll
  for (int j = 0; j < 8; ++j) {
    acc[j] += __shfl_xor(acc[j], 8);
    acc[j] += __shfl_xor(acc[j], 16);
  }
  if (slot == 0) {
    float inv = 1.f / den;
    float v[8];
#pragma unroll
    for (int j = 0; j < 8; ++j) v[j] = fmaf(acc[j], inv, bias[sl * 8 + j]);
    float lm = v[0];
#pragma unroll
    for (int j = 1; j < 8; ++j) lm = fmaxf(lm, v[j]);
#pragma unroll
    for (int off = 1; off <= 4; off <<= 1) lm = fmaxf(lm, __shfl_xor(lm, off));
    float es = 0.f;
#pragma unroll
    for (int j = 0; j < 8; ++j) es += __expf(v[j] - lm);
#pragma unroll
    for (int off = 1; off <= 4; off <<= 1) es += __shfl_xor(es, off);
    float lse = lm + __logf(es);
    float4 o0 = {v[0] - lse, v[1] - lse, v[2] - lse, v[3] - lse};
    float4 o1 = {v[4] - lse, v[5] - lse, v[6] - lse, v[7] - lse};
    *(float4*)(out + (long)n * 64 + sl * 8 + 0) = o0;
    *(float4*)(out + (long)n * 64 + sl * 8 + 4) = o1;
  }
}

// ================= launch =================

extern "C" void kernel_launch(void* const* d_in, const int* in_sizes, int n_in,
                              void* d_out, int out_size, void* d_ws, size_t ws_size,
                              hipStream_t stream) {
  const float* x   = (const float*)d_in[0];
  const int*   ei  = (const int*)d_in[1];
  const float* w1  = (const float*)d_in[2];
  const float* as1 = (const float*)d_in[3];
  const float* ad1 = (const float*)d_in[4];
  const float* b1  = (const float*)d_in[5];
  const float* w2  = (const float*)d_in[6];
  const float* as2 = (const float*)d_in[7];
  const float* ad2 = (const float*)d_in[8];
  const float* b2  = (const float*)d_in[9];
  const float* w3  = (const float*)d_in[10];
  const float* as3 = (const float*)d_in[11];
  const float* ad3 = (const float*)d_in[12];
  const float* b3  = (const float*)d_in[13];
  float* out = (float*)d_out;

  const int N = in_sizes[0] / 128;
  const int E = in_sizes[1] / 2;
  const int ET = E + N;

  const int NB = (ET + 4095) / 4096;      // partition blocks
  const int NBUCK = (N + 255) >> 8;       // buckets (dst>>8)
  const int SL = NBUCK * NB;              // scan length
  const int nsb = (SL + 1023) / 1024;     // scan1/3 blocks

  char* ws = (char*)d_ws;
  size_t off = 0;
  auto alloc = [&](size_t bytes) -> void* {
    void* p = ws + off;
    off += (bytes + 255) & ~(size_t)255;
    return p;
  };
  ushort_t* bufA = (ushort_t*)alloc((size_t)N * 128 * 2);
  ushort_t* bufB = (ushort_t*)alloc((size_t)N * 128 * 2);
  float* als   = (float*)alloc((size_t)N * 4 * 4);
  float* ald   = (float*)alloc((size_t)N * 4 * 4);
  int* ts      = (int*)alloc((size_t)SL * 4);
  int* bsum    = (int*)alloc((size_t)1024 * 4);
  uint_t* tmp  = (uint_t*)alloc((size_t)ET * 4);
  int* rowptr  = (int*)alloc((size_t)(N + 1) * 4);
  int* esrc    = (int*)alloc((size_t)ET * 4);

  const int ggrid = (N + 63) / 64;
  const int albk = (N + 15) / 16;
  const int aggrid = (N + 7) / 8;

  // CSR build (atomic-free bucket sort), once per launch
  hist_kernel<<<NB, 256, 0, stream>>>(ei, ts, E, N, NB, NBUCK);
  scan1<<<nsb, 256, 0, stream>>>(ts, bsum, SL);
  scan2<<<1, 1024, 0, stream>>>(bsum, nsb);
  scan3<<<nsb, 256, 0, stream>>>(ts, bsum, SL);
  part_kernel<<<NB, 256, 0, stream>>>(ei, ts, tmp, E, N, NB, NBUCK);
  bucket_kernel<<<NBUCK, 256, 0, stream>>>(tmp, ts, rowptr, esrc, N, NB, NBUCK, ET);

  // ---- layer 1: x(f32) -> bufA(h, bf16) -> bufB(bf16) ----
  gemm_tile<128, false><<<ggrid, 256, 0, stream>>>(x, w1, bufA, N);
  al_kernel4<<<albk, 256, 0, stream>>>(bufA, as1, ad1, als, ald, N);
  gat_agg128<<<aggrid, 256, 0, stream>>>(bufA, als, ald, rowptr, esrc, b1, bufB, N);

  // ---- layer 2 ----
  gemm_tile<128, true><<<ggrid, 256, 0, stream>>>(bufB, w2, bufA, N);
  al_kernel4<<<albk, 256, 0, stream>>>(bufA, as2, ad2, als, ald, N);
  gat_agg128<<<aggrid, 256, 0, stream>>>(bufA, als, ald, rowptr, esrc, b2, bufB, N);

  // ---- layer 3 ----
  gemm_tile<64, true><<<ggrid, 256, 0, stream>>>(bufB, w3, bufA, N);
  al_kernel1<<<(N + 31) / 32, 256, 0, stream>>>(bufA, as3, ad3, als, ald, N);
  gat_agg64_lsm<<<aggrid, 256, 0, stream>>>(bufA, als, ald, rowptr, esrc, b3, out, N);
}

// Round 9
// 315.661 us; speedup vs baseline: 2.7472x; 1.0297x over previous
//
#include <hip/hip_runtime.h>
#include <hip/hip_bf16.h>
#include <math.h>

#define SLOPE 0.2f
typedef unsigned int uint_t;
typedef unsigned short ushort_t;

static __device__ __forceinline__ float lrelu(float v) { return v > 0.f ? v : SLOPE * v; }
// float -> bf16 bits, round-to-nearest-even
static __device__ __forceinline__ ushort_t f2b(float f) {
  uint_t u = __float_as_uint(f);
  u += 0x7fffu + ((u >> 16) & 1u);
  return (ushort_t)(u >> 16);
}
// packed bf16x2 (as uint) -> float2; on gfx950 should lower to v_cvt_pk_f32_bf16
static __device__ __forceinline__ float2 b2x2(uint_t u) {
  union { uint_t u; __hip_bfloat162 b; } cv;
  cv.u = u;
  return __bfloat1622float2(cv.b);
}

// ================= CSR build: atomic-free MSD bucket sort by dst =================

__device__ __forceinline__ void hist_body(const int* __restrict__ ei, int* __restrict__ ts,
                                          int E, int N, int NB, int NBUCK, int b) {
  __shared__ int h[256];
  int tid = threadIdx.x;
  h[tid] = 0;
  __syncthreads();
  int ET = E + N;
  int base = b * 4096;
#pragma unroll
  for (int j = 0; j < 16; ++j) {
    int i = base + j * 256 + tid;
    if (i < ET) {
      int d = (i < E) ? ei[E + i] : (i - E);
      atomicAdd(&h[d >> 8], 1);
    }
  }
  __syncthreads();
  if (tid < NBUCK) ts[tid * NB + b] = h[tid];
}

__global__ __launch_bounds__(256) void scan1(int* __restrict__ a, int* __restrict__ bsum, int L) {
  int tid = threadIdx.x;
  int base = blockIdx.x * 1024 + tid * 4;
  int c0 = (base + 0 < L) ? a[base + 0] : 0;
  int c1 = (base + 1 < L) ? a[base + 1] : 0;
  int c2 = (base + 2 < L) ? a[base + 2] : 0;
  int c3 = (base + 3 < L) ? a[base + 3] : 0;
  int s = c0 + c1 + c2 + c3;
  int lane = tid & 63, wid = tid >> 6;
  int pre = s;
#pragma unroll
  for (int off = 1; off < 64; off <<= 1) {
    int t = __shfl_up(pre, off);
    if (lane >= off) pre += t;
  }
  __shared__ int wsum[4];
  if (lane == 63) wsum[wid] = pre;
  __syncthreads();
  int woff = 0;
#pragma unroll
  for (int w = 0; w < 4; ++w) woff += (w < wid) ? wsum[w] : 0;
  int excl = woff + pre - s;
  if (base + 0 < L) a[base + 0] = excl;
  if (base + 1 < L) a[base + 1] = excl + c0;
  if (base + 2 < L) a[base + 2] = excl + c0 + c1;
  if (base + 3 < L) a[base + 3] = excl + c0 + c1 + c2;
  if (tid == 255) bsum[blockIdx.x] = wsum[0] + wsum[1] + wsum[2] + wsum[3];
}

__global__ __launch_bounds__(1024) void scan2(int* __restrict__ bsum, int nb) {
  __shared__ int sh[1024];
  int tid = threadIdx.x;
  int v = (tid < nb) ? bsum[tid] : 0;
  sh[tid] = v;
  __syncthreads();
  for (int off = 1; off < 1024; off <<= 1) {
    int add = (tid >= off) ? sh[tid - off] : 0;
    __syncthreads();
    sh[tid] += add;
    __syncthreads();
  }
  if (tid < nb) bsum[tid] = sh[tid] - v;
}

__device__ __forceinline__ void scan3_body(int* __restrict__ a, const int* __restrict__ bsum,
                                           int L, int b) {
  int tid = threadIdx.x;
  int base = b * 1024 + tid * 4;
  if (base >= L) return;
  int off = bsum[b];
#pragma unroll
  for (int j = 0; j < 4; ++j)
    if (base + j < L) a[base + j] += off;
}

__global__ __launch_bounds__(256) void part_kernel(const int* __restrict__ ei,
                                                   const int* __restrict__ ts,
                                                   uint_t* __restrict__ tmp,
                                                   int E, int N, int NB, int NBUCK) {
  __shared__ int bin[256];
  int tid = threadIdx.x, b = blockIdx.x;
  if (tid < NBUCK) bin[tid] = ts[tid * NB + b];
  __syncthreads();
  int ET = E + N;
  int base = b * 4096;
#pragma unroll
  for (int j = 0; j < 16; ++j) {
    int i = base + j * 256 + tid;
    if (i < ET) {
      int s, d;
      if (i < E) { s = ei[i]; d = ei[E + i]; } else { s = i - E; d = i - E; }
      int pos = atomicAdd(&bin[d >> 8], 1);
      tmp[pos] = ((uint_t)d << 16) | (uint_t)s;
    }
  }
}

__global__ __launch_bounds__(256) void bucket_kernel(const uint_t* __restrict__ tmp,
                                                     const int* __restrict__ ts,
                                                     int* __restrict__ rowptr,
                                                     int* __restrict__ esrc,
                                                     int N, int NB, int NBUCK, int ET) {
  __shared__ int h[256], pref[256], rank[256];
  __shared__ int wsum[4];
  int tid = threadIdx.x, d = blockIdx.x;
  int start = ts[d * NB];
  int end = (d == NBUCK - 1) ? ET : ts[(d + 1) * NB];
  h[tid] = 0; rank[tid] = 0;
  __syncthreads();
  for (int i = start + tid; i < end; i += 256)
    atomicAdd(&h[(tmp[i] >> 16) & 255], 1);
  __syncthreads();
  int v = h[tid];
  int lane = tid & 63, wid = tid >> 6;
  int inc = v;
#pragma unroll
  for (int off = 1; off < 64; off <<= 1) {
    int t = __shfl_up(inc, off);
    if (lane >= off) inc += t;
  }
  if (lane == 63) wsum[wid] = inc;
  __syncthreads();
  int woff = 0;
#pragma unroll
  for (int w = 0; w < 4; ++w) woff += (w < wid) ? wsum[w] : 0;
  pref[tid] = woff + inc - v;
  __syncthreads();
  int idx = d * 256 + tid;
  if (idx <= N) rowptr[idx] = start + pref[tid];
  for (int i = start + tid; i < end; i += 256) {
    uint_t v2 = tmp[i];
    int low = (v2 >> 16) & 255;
    int r = atomicAdd(&rank[low], 1);
    esrc[start + pref[low] + r] = (int)(v2 & 0xffffu);
  }
}

// ================= GEMM: H[N,OC](bf16) = X[N,128](f32|bf16) @ W[128,OC](f32) =================

template<int OC, bool BF16IN>
__device__ __forceinline__ void gemm_body(const void* __restrict__ Xv,
                                          const float* __restrict__ W,
                                          ushort_t* __restrict__ H, int N, int bid) {
  const int K = 128;
  const int CT = OC / 4;             // 32 (OC=128) / 16 (OC=64)
  const int RPT = 64 / (256 / CT);   // 8 / 4
  __shared__ float xs[K][68];
  int tid = threadIdx.x;
  long row0 = (long)bid * 64;
  if (BF16IN) {
    const ushort_t* X = (const ushort_t*)Xv;
#pragma unroll
    for (int i = 0; i < 4; ++i) {
      int flat = i * 256 + tid;
      int r = flat & 63, kc = flat >> 6;
      long row = row0 + r;
      long rr = row < N ? row : (long)(N - 1);
      uint4 v = *(const uint4*)(X + rr * K + kc * 8);
      uint_t vv[4] = {v.x, v.y, v.z, v.w};
#pragma unroll
      for (int j = 0; j < 4; ++j) {
        float2 f = b2x2(vv[j]);
        xs[kc * 8 + j * 2 + 0][r] = f.x;
        xs[kc * 8 + j * 2 + 1][r] = f.y;
      }
    }
  } else {
    const float* X = (const float*)Xv;
#pragma unroll
    for (int i = 0; i < 8; ++i) {
      int flat = i * 256 + tid;
      int r = flat & 63, kc = flat >> 6;
      long row = row0 + r;
      long rr = row < N ? row : (long)(N - 1);
      float4 xv = *(const float4*)(X + rr * K + kc * 4);
      xs[kc * 4 + 0][r] = xv.x;
      xs[kc * 4 + 1][r] = xv.y;
      xs[kc * 4 + 2][r] = xv.z;
      xs[kc * 4 + 3][r] = xv.w;
    }
  }
  __syncthreads();
  int ct = tid % CT;
  int rg = tid / CT;
  int c0 = ct * 4;
  int r0 = rg * RPT;
  float acc[RPT][4];
#pragma unroll
  for (int i = 0; i < RPT; ++i)
    for (int j = 0; j < 4; ++j) acc[i][j] = 0.f;
#pragma unroll 4
  for (int k = 0; k < K; ++k) {
    float4 wv = *(const float4*)(W + (long)k * OC + c0);
    const float4* xr = (const float4*)(&xs[k][r0]);
#pragma unroll
    for (int i4 = 0; i4 < RPT / 4; ++i4) {
      float4 xv = xr[i4];
      float xa[4] = {xv.x, xv.y, xv.z, xv.w};
#pragma unroll
      for (int j = 0; j < 4; ++j) {
        int i = i4 * 4 + j;
        acc[i][0] = fmaf(xa[j], wv.x, acc[i][0]);
        acc[i][1] = fmaf(xa[j], wv.y, acc[i][1]);
        acc[i][2] = fmaf(xa[j], wv.z, acc[i][2]);
        acc[i][3] = fmaf(xa[j], wv.w, acc[i][3]);
      }
    }
  }
#pragma unroll
  for (int i = 0; i < RPT; ++i) {
    long row = row0 + r0 + i;
    if (row < N) {
      ushort4 o = {f2b(acc[i][0]), f2b(acc[i][1]), f2b(acc[i][2]), f2b(acc[i][3])};
      *(ushort4*)(H + row * OC + c0) = o;
    }
  }
}

template<int OC, bool BF16IN>
__global__ __launch_bounds__(256) void gemm_tile(const void* __restrict__ Xv,
                                                 const float* __restrict__ W,
                                                 ushort_t* __restrict__ H, int N) {
  gemm_body<OC, BF16IN>(Xv, W, H, N, blockIdx.x);
}

// fused: gemm layer1 (f32 in) || edge histogram
__global__ __launch_bounds__(256) void k_gemm1_hist(const float* __restrict__ X,
    const float* __restrict__ W, ushort_t* __restrict__ H, int N,
    const int* __restrict__ ei, int* __restrict__ ts, int E, int NB, int NBUCK,
    int gemmBlocks) {
  int bid = blockIdx.x;
  if (bid < gemmBlocks) gemm_body<128, false>(X, W, H, N, bid);
  else hist_body(ei, ts, E, N, NB, NBUCK, bid - gemmBlocks);
}

// ================= attention coefficients per node (bf16 h) =================

__device__ __forceinline__ void al4_body(const ushort_t* __restrict__ h,
                                         const float* __restrict__ a_s,
                                         const float* __restrict__ a_d,
                                         float* __restrict__ als, float* __restrict__ ald,
                                         int N, int bid) {
  int tid = threadIdx.x;
  int n = bid * 16 + (tid >> 4);
  int sl = tid & 15, hd = sl >> 2;
  if (n >= N) return;
  uint4 v = *(const uint4*)(h + (long)n * 128 + sl * 8);
  uint_t vv[4] = {v.x, v.y, v.z, v.w};
  const float* sp = a_s + hd * 32 + (sl & 3) * 8;
  const float* dp = a_d + hd * 32 + (sl & 3) * 8;
  float vs = 0.f, vd = 0.f;
#pragma unroll
  for (int j = 0; j < 4; ++j) {
    float2 f = b2x2(vv[j]);
    vs = fmaf(f.x, sp[j * 2 + 0], vs); vs = fmaf(f.y, sp[j * 2 + 1], vs);
    vd = fmaf(f.x, dp[j * 2 + 0], vd); vd = fmaf(f.y, dp[j * 2 + 1], vd);
  }
#pragma unroll
  for (int off = 1; off <= 2; off <<= 1) {
    vs += __shfl_xor(vs, off);
    vd += __shfl_xor(vd, off);
  }
  if ((sl & 3) == 0) { als[(long)n * 4 + hd] = vs; ald[(long)n * 4 + hd] = vd; }
}

__global__ void al_kernel4(const ushort_t* __restrict__ h, const float* __restrict__ a_s,
                           const float* __restrict__ a_d, float* __restrict__ als,
                           float* __restrict__ ald, int N) {
  al4_body(h, a_s, a_d, als, ald, N, blockIdx.x);
}

// fused: scan3 || al4 layer1
__global__ __launch_bounds__(256) void k_scan3_al4(int* __restrict__ a,
    const int* __restrict__ bsum, int L, int scanBlocks,
    const ushort_t* __restrict__ h, const float* __restrict__ a_s,
    const float* __restrict__ a_d, float* __restrict__ als, float* __restrict__ ald, int N) {
  int bid = blockIdx.x;
  if (bid < scanBlocks) scan3_body(a, bsum, L, bid);
  else al4_body(h, a_s, a_d, als, ald, N, bid - scanBlocks);
}

__global__ void al_kernel1(const ushort_t* __restrict__ h, const float* __restrict__ a_s,
                           const float* __restrict__ a_d, float* __restrict__ als,
                           float* __restrict__ ald, int N) {
  int tid = threadIdx.x;
  int n = blockIdx.x * 32 + (tid >> 3);
  int sl = tid & 7;
  if (n >= N) return;
  uint4 v = *(const uint4*)(h + (long)n * 64 + sl * 8);
  uint_t vv[4] = {v.x, v.y, v.z, v.w};
  const float* sp = a_s + sl * 8;
  const float* dp = a_d + sl * 8;
  float vs = 0.f, vd = 0.f;
#pragma unroll
  for (int j = 0; j < 4; ++j) {
    float2 f = b2x2(vv[j]);
    vs = fmaf(f.x, sp[j * 2 + 0], vs); vs = fmaf(f.y, sp[j * 2 + 1], vs);
    vd = fmaf(f.x, dp[j * 2 + 0], vd); vd = fmaf(f.y, dp[j * 2 + 1], vd);
  }
#pragma unroll
  for (int off = 1; off <= 4; off <<= 1) {
    vs += __shfl_xor(vs, off);
    vd += __shfl_xor(vd, off);
  }
  if (sl == 0) { als[n] = vs; ald[n] = vd; }
}

// ================= softmax aggregation (m=0; logits bounded), half-wave/node =================

__global__ __launch_bounds__(256) void gat_agg128(const ushort_t* __restrict__ h,
    const float* __restrict__ als, const float* __restrict__ ald,
    const int* __restrict__ rowptr, const int* __restrict__ esrc,
    const float* __restrict__ bias, ushort_t* __restrict__ out, int N) {
  int tid = threadIdx.x;
  int n = blockIdx.x * 8 + (tid >> 5);
  int l = tid & 31;
  int slot = l >> 4, sl = l & 15, hd = sl >> 2;
  if (n >= N) return;
  int beg = rowptr[n], end = rowptr[n + 1];
  float aldv = ald[(long)n * 4 + hd];
  float den = 0.f;
  float acc[8] = {0.f, 0.f, 0.f, 0.f, 0.f, 0.f, 0.f, 0.f};
  for (int e = beg + slot; e < end; e += 2) {
    int s = esrc[e];
    float p = __expf(lrelu(als[(long)s * 4 + hd] + aldv));
    den += p;
    uint4 v = *(const uint4*)(h + (long)s * 128 + sl * 8);
    uint_t vv[4] = {v.x, v.y, v.z, v.w};
#pragma unroll
    for (int j = 0; j < 4; ++j) {
      float2 f = b2x2(vv[j]);
      acc[2 * j + 0] = fmaf(p, f.x, acc[2 * j + 0]);
      acc[2 * j + 1] = fmaf(p, f.y, acc[2 * j + 1]);
    }
  }
  den += __shfl_xor(den, 16);
#pragma unroll
  for (int j = 0; j < 8; ++j) acc[j] += __shfl_xor(acc[j], 16);
  if (slot == 0) {
    float inv = 1.f / den;
    float4 bv0 = *(const float4*)(bias + sl * 8);
    float4 bv1 = *(const float4*)(bias + sl * 8 + 4);
    float bb[8] = {bv0.x, bv0.y, bv0.z, bv0.w, bv1.x, bv1.y, bv1.z, bv1.w};
    uint_t pk[4];
#pragma unroll
    for (int j = 0; j < 4; ++j) {
      float v0 = fmaxf(fmaf(acc[2 * j + 0], inv, bb[2 * j + 0]), 0.f);
      float v1 = fmaxf(fmaf(acc[2 * j + 1], inv, bb[2 * j + 1]), 0.f);
      pk[j] = (uint_t)f2b(v0) | ((uint_t)f2b(v1) << 16);
    }
    uint4 pv = {pk[0], pk[1], pk[2], pk[3]};
    *(uint4*)(out + (long)n * 128 + sl * 8) = pv;
  }
}

__global__ __launch_bounds__(256) void gat_agg64_lsm(const ushort_t* __restrict__ h,
    const float* __restrict__ als, const float* __restrict__ ald,
    const int* __restrict__ rowptr, const int* __restrict__ esrc,
    const float* __restrict__ bias, float* __restrict__ out, int N) {
  int tid = threadIdx.x;
  int n = blockIdx.x * 8 + (tid >> 5);
  int l = tid & 31;
  int slot = l >> 3, sl = l & 7;
  if (n >= N) return;
  int beg = rowptr[n], end = rowptr[n + 1];
  float aldv = ald[n];
  float den = 0.f;
  float acc[8] = {0.f, 0.f, 0.f, 0.f, 0.f, 0.f, 0.f, 0.f};
  for (int e = beg + slot; e < end; e += 4) {
    int s = esrc[e];
    float p = __expf(lrelu(als[s] + aldv));
    den += p;
    uint4 v = *(const uint4*)(h + (long)s * 64 + sl * 8);
    uint_t vv[4] = {v.x, v.y, v.z, v.w};
#pragma unroll
    for (int j = 0; j < 4; ++j) {
      float2 f = b2x2(vv[j]);
      acc[2 * j + 0] = fmaf(p, f.x, acc[2 * j + 0]);
      acc[2 * j + 1] = fmaf(p, f.y, acc[2 * j + 1]);
    }
  }
  den += __shfl_xor(den, 8); den += __shfl_xor(den, 16);
#pragma unroll
  for (int j = 0; j < 8; ++j) {
    acc[j] += __shfl_xor(acc[j], 8);
    acc[j] += __shfl_xor(acc[j], 16);
  }
  if (slot == 0) {
    float inv = 1.f / den;
    float v[8];
#pragma unroll
    for (int j = 0; j < 8; ++j) v[j] = fmaf(acc[j], inv, bias[sl * 8 + j]);
    float lm = v[0];
#pragma unroll
    for (int j = 1; j < 8; ++j) lm = fmaxf(lm, v[j]);
#pragma unroll
    for (int off = 1; off <= 4; off <<= 1) lm = fmaxf(lm, __shfl_xor(lm, off));
    float es = 0.f;
#pragma unroll
    for (int j = 0; j < 8; ++j) es += __expf(v[j] - lm);
#pragma unroll
    for (int off = 1; off <= 4; off <<= 1) es += __shfl_xor(es, off);
    float lse = lm + __logf(es);
    float4 o0 = {v[0] - lse, v[1] - lse, v[2] - lse, v[3] - lse};
    float4 o1 = {v[4] - lse, v[5] - lse, v[6] - lse, v[7] - lse};
    *(float4*)(out + (long)n * 64 + sl * 8 + 0) = o0;
    *(float4*)(out + (long)n * 64 + sl * 8 + 4) = o1;
  }
}

// ================= launch =================

extern "C" void kernel_launch(void* const* d_in, const int* in_sizes, int n_in,
                              void* d_out, int out_size, void* d_ws, size_t ws_size,
                              hipStream_t stream) {
  const float* x   = (const float*)d_in[0];
  const int*   ei  = (const int*)d_in[1];
  const float* w1  = (const float*)d_in[2];
  const float* as1 = (const float*)d_in[3];
  const float* ad1 = (const float*)d_in[4];
  const float* b1  = (const float*)d_in[5];
  const float* w2  = (const float*)d_in[6];
  const float* as2 = (const float*)d_in[7];
  const float* ad2 = (const float*)d_in[8];
  const float* b2  = (const float*)d_in[9];
  const float* w3  = (const float*)d_in[10];
  const float* as3 = (const float*)d_in[11];
  const float* ad3 = (const float*)d_in[12];
  const float* b3  = (const float*)d_in[13];
  float* out = (float*)d_out;

  const int N = in_sizes[0] / 128;
  const int E = in_sizes[1] / 2;
  const int ET = E + N;

  const int NB = (ET + 4095) / 4096;      // hist/part blocks
  const int NBUCK = (N + 255) >> 8;       // buckets (dst>>8)
  const int SL = NBUCK * NB;              // scan length
  const int nsb = (SL + 1023) / 1024;     // scan blocks

  char* ws = (char*)d_ws;
  size_t off = 0;
  auto alloc = [&](size_t bytes) -> void* {
    void* p = ws + off;
    off += (bytes + 255) & ~(size_t)255;
    return p;
  };
  ushort_t* bufA = (ushort_t*)alloc((size_t)N * 128 * 2);
  ushort_t* bufB = (ushort_t*)alloc((size_t)N * 128 * 2);
  float* als   = (float*)alloc((size_t)N * 4 * 4);
  float* ald   = (float*)alloc((size_t)N * 4 * 4);
  int* ts      = (int*)alloc((size_t)SL * 4);
  int* bsum    = (int*)alloc((size_t)1024 * 4);
  uint_t* tmp  = (uint_t*)alloc((size_t)ET * 4);
  int* rowptr  = (int*)alloc((size_t)(N + 1) * 4);
  int* esrc    = (int*)alloc((size_t)ET * 4);

  const int ggrid = (N + 63) / 64;
  const int albk = (N + 15) / 16;
  const int aggrid = (N + 7) / 8;

  // fused: gemm layer1 || histogram (independent)
  k_gemm1_hist<<<ggrid + NB, 256, 0, stream>>>(x, w1, bufA, N, ei, ts, E, NB, NBUCK, ggrid);
  scan1<<<nsb, 256, 0, stream>>>(ts, bsum, SL);
  scan2<<<1, 1024, 0, stream>>>(bsum, nsb);
  // fused: scan3 || al4 layer1 (al4 needs gemm1 only)
  k_scan3_al4<<<nsb + albk, 256, 0, stream>>>(ts, bsum, SL, nsb,
                                              bufA, as1, ad1, als, ald, N);
  part_kernel<<<NB, 256, 0, stream>>>(ei, ts, tmp, E, N, NB, NBUCK);
  bucket_kernel<<<NBUCK, 256, 0, stream>>>(tmp, ts, rowptr, esrc, N, NB, NBUCK, ET);

  // ---- layer 1 aggregation ----
  gat_agg128<<<aggrid, 256, 0, stream>>>(bufA, als, ald, rowptr, esrc, b1, bufB, N);

  // ---- layer 2 ----
  gemm_tile<128, true><<<ggrid, 256, 0, stream>>>(bufB, w2, bufA, N);
  al_kernel4<<<albk, 256, 0, stream>>>(bufA, as2, ad2, als, ald, N);
  gat_agg128<<<aggrid, 256, 0, stream>>>(bufA, als, ald, rowptr, esrc, b2, bufB, N);

  // ---- layer 3 ----
  gemm_tile<64, true><<<ggrid, 256, 0, stream>>>(bufB, w3, bufA, N);
  al_kernel1<<<(N + 31) / 32, 256, 0, stream>>>(bufA, as3, ad3, als, ald, N);
  gat_agg64_lsm<<<aggrid, 256, 0, stream>>>(bufA, als, ald, rowptr, esrc, b3, out, N);
}

// Round 10
// 308.450 us; speedup vs baseline: 2.8114x; 1.0234x over previous
//
#include <hip/hip_runtime.h>
#include <hip/hip_bf16.h>
#include <math.h>

#define SLOPE 0.2f
typedef unsigned int uint_t;
typedef unsigned short ushort_t;

static __device__ __forceinline__ float lrelu(float v) { return v > 0.f ? v : SLOPE * v; }
// float -> bf16 bits, round-to-nearest-even
static __device__ __forceinline__ ushort_t f2b(float f) {
  uint_t u = __float_as_uint(f);
  u += 0x7fffu + ((u >> 16) & 1u);
  return (ushort_t)(u >> 16);
}
// packed bf16x2 (as uint) -> float2 (v_cvt_pk_f32_bf16 path)
static __device__ __forceinline__ float2 b2x2(uint_t u) {
  union { uint_t u; __hip_bfloat162 b; } cv;
  cv.u = u;
  return __bfloat1622float2(cv.b);
}

// ================= CSR build: atomic-free MSD bucket sort by dst =================

__device__ __forceinline__ void hist_body(const int* __restrict__ ei, int* __restrict__ ts,
                                          int E, int N, int NB, int NBUCK, int b) {
  __shared__ int h[256];
  int tid = threadIdx.x;
  h[tid] = 0;
  __syncthreads();
  int ET = E + N;
  int base = b * 4096;
#pragma unroll
  for (int j = 0; j < 16; ++j) {
    int i = base + j * 256 + tid;
    if (i < ET) {
      int d = (i < E) ? ei[E + i] : (i - E);
      atomicAdd(&h[d >> 8], 1);
    }
  }
  __syncthreads();
  if (tid < NBUCK) ts[tid * NB + b] = h[tid];
}

__global__ __launch_bounds__(256) void scan1(int* __restrict__ a, int* __restrict__ bsum, int L) {
  int tid = threadIdx.x;
  int base = blockIdx.x * 1024 + tid * 4;
  int c0 = (base + 0 < L) ? a[base + 0] : 0;
  int c1 = (base + 1 < L) ? a[base + 1] : 0;
  int c2 = (base + 2 < L) ? a[base + 2] : 0;
  int c3 = (base + 3 < L) ? a[base + 3] : 0;
  int s = c0 + c1 + c2 + c3;
  int lane = tid & 63, wid = tid >> 6;
  int pre = s;
#pragma unroll
  for (int off = 1; off < 64; off <<= 1) {
    int t = __shfl_up(pre, off);
    if (lane >= off) pre += t;
  }
  __shared__ int wsum[4];
  if (lane == 63) wsum[wid] = pre;
  __syncthreads();
  int woff = 0;
#pragma unroll
  for (int w = 0; w < 4; ++w) woff += (w < wid) ? wsum[w] : 0;
  int excl = woff + pre - s;
  if (base + 0 < L) a[base + 0] = excl;
  if (base + 1 < L) a[base + 1] = excl + c0;
  if (base + 2 < L) a[base + 2] = excl + c0 + c1;
  if (base + 3 < L) a[base + 3] = excl + c0 + c1 + c2;
  if (tid == 255) bsum[blockIdx.x] = wsum[0] + wsum[1] + wsum[2] + wsum[3];
}

__global__ __launch_bounds__(1024) void scan2(int* __restrict__ bsum, int nb) {
  __shared__ int sh[1024];
  int tid = threadIdx.x;
  int v = (tid < nb) ? bsum[tid] : 0;
  sh[tid] = v;
  __syncthreads();
  for (int off = 1; off < 1024; off <<= 1) {
    int add = (tid >= off) ? sh[tid - off] : 0;
    __syncthreads();
    sh[tid] += add;
    __syncthreads();
  }
  if (tid < nb) bsum[tid] = sh[tid] - v;
}

// part/bucket apply the scan2 block offsets on the fly: scanned ts[i] = ts[i] + bsum[i>>10]

__global__ __launch_bounds__(256) void part_kernel(const int* __restrict__ ei,
                                                   const int* __restrict__ ts,
                                                   const int* __restrict__ bsum,
                                                   uint_t* __restrict__ tmp,
                                                   int E, int N, int NB, int NBUCK) {
  __shared__ int bin[256];
  int tid = threadIdx.x, b = blockIdx.x;
  if (tid < NBUCK) {
    int idx = tid * NB + b;
    bin[tid] = ts[idx] + bsum[idx >> 10];
  }
  __syncthreads();
  int ET = E + N;
  int base = b * 4096;
#pragma unroll
  for (int j = 0; j < 16; ++j) {
    int i = base + j * 256 + tid;
    if (i < ET) {
      int s, d;
      if (i < E) { s = ei[i]; d = ei[E + i]; } else { s = i - E; d = i - E; }
      int pos = atomicAdd(&bin[d >> 8], 1);
      tmp[pos] = ((uint_t)d << 16) | (uint_t)s;
    }
  }
}

__global__ __launch_bounds__(256) void bucket_kernel(const uint_t* __restrict__ tmp,
                                                     const int* __restrict__ ts,
                                                     const int* __restrict__ bsum,
                                                     int* __restrict__ rowptr,
                                                     int* __restrict__ esrc,
                                                     int N, int NB, int NBUCK, int ET) {
  __shared__ int h[256], pref[256], rank[256];
  __shared__ int wsum[4];
  int tid = threadIdx.x, d = blockIdx.x;
  int i0 = d * NB;
  int start = ts[i0] + bsum[i0 >> 10];
  int end = ET;
  if (d != NBUCK - 1) {
    int i1 = (d + 1) * NB;
    end = ts[i1] + bsum[i1 >> 10];
  }
  h[tid] = 0; rank[tid] = 0;
  __syncthreads();
  for (int i = start + tid; i < end; i += 256)
    atomicAdd(&h[(tmp[i] >> 16) & 255], 1);
  __syncthreads();
  int v = h[tid];
  int lane = tid & 63, wid = tid >> 6;
  int inc = v;
#pragma unroll
  for (int off = 1; off < 64; off <<= 1) {
    int t = __shfl_up(inc, off);
    if (lane >= off) inc += t;
  }
  if (lane == 63) wsum[wid] = inc;
  __syncthreads();
  int woff = 0;
#pragma unroll
  for (int w = 0; w < 4; ++w) woff += (w < wid) ? wsum[w] : 0;
  pref[tid] = woff + inc - v;
  __syncthreads();
  int idx = d * 256 + tid;
  if (idx <= N) rowptr[idx] = start + pref[tid];
  for (int i = start + tid; i < end; i += 256) {
    uint_t v2 = tmp[i];
    int low = (v2 >> 16) & 255;
    int r = atomicAdd(&rank[low], 1);
    esrc[start + pref[low] + r] = (int)(v2 & 0xffffu);
  }
}

// ========== GEMM + fused al projections: H(bf16) = X @ W; als/ald from fp32 acc ==========
// a_s/a_d are laid out [head][feat] = flat col index, so fragment ptr is a_s + c0.

template<int OC, bool BF16IN>
__device__ __forceinline__ void gemm_body(const void* __restrict__ Xv,
                                          const float* __restrict__ W,
                                          ushort_t* __restrict__ H,
                                          const float* __restrict__ a_s,
                                          const float* __restrict__ a_d,
                                          float* __restrict__ als,
                                          float* __restrict__ ald,
                                          int N, int bid) {
  const int K = 128;
  const int CT = OC / 4;             // 32 (OC=128) / 16 (OC=64)
  const int RPT = 64 / (256 / CT);   // 8 / 4
  __shared__ float xs[K][68];
  int tid = threadIdx.x;
  long row0 = (long)bid * 64;
  if (BF16IN) {
    const ushort_t* X = (const ushort_t*)Xv;
#pragma unroll
    for (int i = 0; i < 4; ++i) {
      int flat = i * 256 + tid;
      int r = flat & 63, kc = flat >> 6;
      long row = row0 + r;
      long rr = row < N ? row : (long)(N - 1);
      uint4 v = *(const uint4*)(X + rr * K + kc * 8);
      uint_t vv[4] = {v.x, v.y, v.z, v.w};
#pragma unroll
      for (int j = 0; j < 4; ++j) {
        float2 f = b2x2(vv[j]);
        xs[kc * 8 + j * 2 + 0][r] = f.x;
        xs[kc * 8 + j * 2 + 1][r] = f.y;
      }
    }
  } else {
    const float* X = (const float*)Xv;
#pragma unroll
    for (int i = 0; i < 8; ++i) {
      int flat = i * 256 + tid;
      int r = flat & 63, kc = flat >> 6;
      long row = row0 + r;
      long rr = row < N ? row : (long)(N - 1);
      float4 xv = *(const float4*)(X + rr * K + kc * 4);
      xs[kc * 4 + 0][r] = xv.x;
      xs[kc * 4 + 1][r] = xv.y;
      xs[kc * 4 + 2][r] = xv.z;
      xs[kc * 4 + 3][r] = xv.w;
    }
  }
  __syncthreads();
  int ct = tid % CT;
  int rg = tid / CT;
  int c0 = ct * 4;
  int r0 = rg * RPT;
  float acc[RPT][4];
#pragma unroll
  for (int i = 0; i < RPT; ++i)
    for (int j = 0; j < 4; ++j) acc[i][j] = 0.f;
#pragma unroll 4
  for (int k = 0; k < K; ++k) {
    float4 wv = *(const float4*)(W + (long)k * OC + c0);
    const float4* xr = (const float4*)(&xs[k][r0]);
#pragma unroll
    for (int i4 = 0; i4 < RPT / 4; ++i4) {
      float4 xv = xr[i4];
      float xa[4] = {xv.x, xv.y, xv.z, xv.w};
#pragma unroll
      for (int j = 0; j < 4; ++j) {
        int i = i4 * 4 + j;
        acc[i][0] = fmaf(xa[j], wv.x, acc[i][0]);
        acc[i][1] = fmaf(xa[j], wv.y, acc[i][1]);
        acc[i][2] = fmaf(xa[j], wv.z, acc[i][2]);
        acc[i][3] = fmaf(xa[j], wv.w, acc[i][3]);
      }
    }
  }
  // store bf16 H
#pragma unroll
  for (int i = 0; i < RPT; ++i) {
    long row = row0 + r0 + i;
    if (row < N) {
      ushort4 o = {f2b(acc[i][0]), f2b(acc[i][1]), f2b(acc[i][2]), f2b(acc[i][3])};
      *(ushort4*)(H + row * OC + c0) = o;
    }
  }
  // fused al: per-head dot of acc row with a_s/a_d, shuffle-reduced across the
  // head's col-threads (8 lanes for OC=128, 16 for OC=64).
  float4 sv = *(const float4*)(a_s + c0);
  float4 dv = *(const float4*)(a_d + c0);
  const int RED = (OC == 128) ? 4 : 8;      // max xor offset
  const int GM  = (OC == 128) ? 7 : 15;     // group mask
#pragma unroll
  for (int i = 0; i < RPT; ++i) {
    float ps = acc[i][0] * sv.x + acc[i][1] * sv.y + acc[i][2] * sv.z + acc[i][3] * sv.w;
    float pd = acc[i][0] * dv.x + acc[i][1] * dv.y + acc[i][2] * dv.z + acc[i][3] * dv.w;
#pragma unroll
    for (int off = 1; off <= RED; off <<= 1) {
      ps += __shfl_xor(ps, off);
      pd += __shfl_xor(pd, off);
    }
    long row = row0 + r0 + i;
    if ((ct & GM) == 0 && row < N) {
      if (OC == 128) {
        int head = c0 >> 5;
        als[row * 4 + head] = ps;
        ald[row * 4 + head] = pd;
      } else {
        als[row] = ps;
        ald[row] = pd;
      }
    }
  }
}

template<int OC, bool BF16IN>
__global__ __launch_bounds__(256) void gemm_tile(const void* __restrict__ Xv,
                                                 const float* __restrict__ W,
                                                 ushort_t* __restrict__ H,
                                                 const float* __restrict__ a_s,
                                                 const float* __restrict__ a_d,
                                                 float* __restrict__ als,
                                                 float* __restrict__ ald, int N) {
  gemm_body<OC, BF16IN>(Xv, W, H, a_s, a_d, als, ald, N, blockIdx.x);
}

// fused: gemm layer1 (f32 in, +al epilogue) || edge histogram
__global__ __launch_bounds__(256) void k_gemm1_hist(const float* __restrict__ X,
    const float* __restrict__ W, ushort_t* __restrict__ H,
    const float* __restrict__ a_s, const float* __restrict__ a_d,
    float* __restrict__ als, float* __restrict__ ald, int N,
    const int* __restrict__ ei, int* __restrict__ ts, int E, int NB, int NBUCK,
    int gemmBlocks) {
  int bid = blockIdx.x;
  if (bid < gemmBlocks) gemm_body<128, false>(X, W, H, a_s, a_d, als, ald, N, bid);
  else hist_body(ei, ts, E, N, NB, NBUCK, bid - gemmBlocks);
}

// ================= softmax aggregation (m=0; logits bounded), half-wave/node =================

__global__ __launch_bounds__(256) void gat_agg128(const ushort_t* __restrict__ h,
    const float* __restrict__ als, const float* __restrict__ ald,
    const int* __restrict__ rowptr, const int* __restrict__ esrc,
    const float* __restrict__ bias, ushort_t* __restrict__ out, int N) {
  int tid = threadIdx.x;
  int n = blockIdx.x * 8 + (tid >> 5);
  int l = tid & 31;
  int slot = l >> 4, sl = l & 15, hd = sl >> 2;
  if (n >= N) return;
  int beg = rowptr[n], end = rowptr[n + 1];
  float aldv = ald[(long)n * 4 + hd];
  float den = 0.f;
  float acc[8] = {0.f, 0.f, 0.f, 0.f, 0.f, 0.f, 0.f, 0.f};
  for (int e = beg + slot; e < end; e += 2) {
    int s = esrc[e];
    float p = __expf(lrelu(als[(long)s * 4 + hd] + aldv));
    den += p;
    uint4 v = *(const uint4*)(h + (long)s * 128 + sl * 8);
    uint_t vv[4] = {v.x, v.y, v.z, v.w};
#pragma unroll
    for (int j = 0; j < 4; ++j) {
      float2 f = b2x2(vv[j]);
      acc[2 * j + 0] = fmaf(p, f.x, acc[2 * j + 0]);
      acc[2 * j + 1] = fmaf(p, f.y, acc[2 * j + 1]);
    }
  }
  den += __shfl_xor(den, 16);
#pragma unroll
  for (int j = 0; j < 8; ++j) acc[j] += __shfl_xor(acc[j], 16);
  if (slot == 0) {
    float inv = 1.f / den;
    float4 bv0 = *(const float4*)(bias + sl * 8);
    float4 bv1 = *(const float4*)(bias + sl * 8 + 4);
    float bb[8] = {bv0.x, bv0.y, bv0.z, bv0.w, bv1.x, bv1.y, bv1.z, bv1.w};
    uint_t pk[4];
#pragma unroll
    for (int j = 0; j < 4; ++j) {
      float v0 = fmaxf(fmaf(acc[2 * j + 0], inv, bb[2 * j + 0]), 0.f);
      float v1 = fmaxf(fmaf(acc[2 * j + 1], inv, bb[2 * j + 1]), 0.f);
      pk[j] = (uint_t)f2b(v0) | ((uint_t)f2b(v1) << 16);
    }
    uint4 pv = {pk[0], pk[1], pk[2], pk[3]};
    *(uint4*)(out + (long)n * 128 + sl * 8) = pv;
  }
}

__global__ __launch_bounds__(256) void gat_agg64_lsm(const ushort_t* __restrict__ h,
    const float* __restrict__ als, const float* __restrict__ ald,
    const int* __restrict__ rowptr, const int* __restrict__ esrc,
    const float* __restrict__ bias, float* __restrict__ out, int N) {
  int tid = threadIdx.x;
  int n = blockIdx.x * 8 + (tid >> 5);
  int l = tid & 31;
  int slot = l >> 3, sl = l & 7;
  if (n >= N) return;
  int beg = rowptr[n], end = rowptr[n + 1];
  float aldv = ald[n];
  float den = 0.f;
  float acc[8] = {0.f, 0.f, 0.f, 0.f, 0.f, 0.f, 0.f, 0.f};
  for (int e = beg + slot; e < end; e += 4) {
    int s = esrc[e];
    float p = __expf(lrelu(als[s] + aldv));
    den += p;
    uint4 v = *(const uint4*)(h + (long)s * 64 + sl * 8);
    uint_t vv[4] = {v.x, v.y, v.z, v.w};
#pragma unroll
    for (int j = 0; j < 4; ++j) {
      float2 f = b2x2(vv[j]);
      acc[2 * j + 0] = fmaf(p, f.x, acc[2 * j + 0]);
      acc[2 * j + 1] = fmaf(p, f.y, acc[2 * j + 1]);
    }
  }
  den += __shfl_xor(den, 8); den += __shfl_xor(den, 16);
#pragma unroll
  for (int j = 0; j < 8; ++j) {
    acc[j] += __shfl_xor(acc[j], 8);
    acc[j] += __shfl_xor(acc[j], 16);
  }
  if (slot == 0) {
    float inv = 1.f / den;
    float v[8];
#pragma unroll
    for (int j = 0; j < 8; ++j) v[j] = fmaf(acc[j], inv, bias[sl * 8 + j]);
    float lm = v[0];
#pragma unroll
    for (int j = 1; j < 8; ++j) lm = fmaxf(lm, v[j]);
#pragma unroll
    for (int off = 1; off <= 4; off <<= 1) lm = fmaxf(lm, __shfl_xor(lm, off));
    float es = 0.f;
#pragma unroll
    for (int j = 0; j < 8; ++j) es += __expf(v[j] - lm);
#pragma unroll
    for (int off = 1; off <= 4; off <<= 1) es += __shfl_xor(es, off);
    float lse = lm + __logf(es);
    float4 o0 = {v[0] - lse, v[1] - lse, v[2] - lse, v[3] - lse};
    float4 o1 = {v[4] - lse, v[5] - lse, v[6] - lse, v[7] - lse};
    *(float4*)(out + (long)n * 64 + sl * 8 + 0) = o0;
    *(float4*)(out + (long)n * 64 + sl * 8 + 4) = o1;
  }
}

// ================= launch =================

extern "C" void kernel_launch(void* const* d_in, const int* in_sizes, int n_in,
                              void* d_out, int out_size, void* d_ws, size_t ws_size,
                              hipStream_t stream) {
  const float* x   = (const float*)d_in[0];
  const int*   ei  = (const int*)d_in[1];
  const float* w1  = (const float*)d_in[2];
  const float* as1 = (const float*)d_in[3];
  const float* ad1 = (const float*)d_in[4];
  const float* b1  = (const float*)d_in[5];
  const float* w2  = (const float*)d_in[6];
  const float* as2 = (const float*)d_in[7];
  const float* ad2 = (const float*)d_in[8];
  const float* b2  = (const float*)d_in[9];
  const float* w3  = (const float*)d_in[10];
  const float* as3 = (const float*)d_in[11];
  const float* ad3 = (const float*)d_in[12];
  const float* b3  = (const float*)d_in[13];
  float* out = (float*)d_out;

  const int N = in_sizes[0] / 128;
  const int E = in_sizes[1] / 2;
  const int ET = E + N;

  const int NB = (ET + 4095) / 4096;      // hist/part blocks
  const int NBUCK = (N + 255) >> 8;       // buckets (dst>>8)
  const int SL = NBUCK * NB;              // scan length
  const int nsb = (SL + 1023) / 1024;     // scan blocks

  char* ws = (char*)d_ws;
  size_t off = 0;
  auto alloc = [&](size_t bytes) -> void* {
    void* p = ws + off;
    off += (bytes + 255) & ~(size_t)255;
    return p;
  };
  ushort_t* bufA = (ushort_t*)alloc((size_t)N * 128 * 2);
  ushort_t* bufB = (ushort_t*)alloc((size_t)N * 128 * 2);
  float* als   = (float*)alloc((size_t)N * 4 * 4);
  float* ald   = (float*)alloc((size_t)N * 4 * 4);
  int* ts      = (int*)alloc((size_t)SL * 4);
  int* bsum    = (int*)alloc((size_t)1024 * 4);
  uint_t* tmp  = (uint_t*)alloc((size_t)ET * 4);
  int* rowptr  = (int*)alloc((size_t)(N + 1) * 4);
  int* esrc    = (int*)alloc((size_t)ET * 4);

  const int ggrid = (N + 63) / 64;
  const int aggrid = (N + 7) / 8;

  // 1. fused: gemm layer1 + al epilogue || histogram (independent)
  k_gemm1_hist<<<ggrid + NB, 256, 0, stream>>>(x, w1, bufA, as1, ad1, als, ald, N,
                                               ei, ts, E, NB, NBUCK, ggrid);
  // 2-3. scan of ts
  scan1<<<nsb, 256, 0, stream>>>(ts, bsum, SL);
  scan2<<<1, 1024, 0, stream>>>(bsum, nsb);
  // 4-5. partition + per-bucket counting sort (apply bsum offsets on the fly)
  part_kernel<<<NB, 256, 0, stream>>>(ei, ts, bsum, tmp, E, N, NB, NBUCK);
  bucket_kernel<<<NBUCK, 256, 0, stream>>>(tmp, ts, bsum, rowptr, esrc, N, NB, NBUCK, ET);

  // 6. layer 1 aggregation
  gat_agg128<<<aggrid, 256, 0, stream>>>(bufA, als, ald, rowptr, esrc, b1, bufB, N);

  // 7-8. layer 2
  gemm_tile<128, true><<<ggrid, 256, 0, stream>>>(bufB, w2, bufA, as2, ad2, als, ald, N);
  gat_agg128<<<aggrid, 256, 0, stream>>>(bufA, als, ald, rowptr, esrc, b2, bufB, N);

  // 9-10. layer 3
  gemm_tile<64, true><<<ggrid, 256, 0, stream>>>(bufB, w3, bufA, as3, ad3, als, ald, N);
  gat_agg64_lsm<<<aggrid, 256, 0, stream>>>(bufA, als, ald, rowptr, esrc, b3, out, N);
}

// Round 11
// 298.487 us; speedup vs baseline: 2.9053x; 1.0334x over previous
//
#include <hip/hip_runtime.h>
#include <hip/hip_bf16.h>
#include <math.h>

#define SLOPE 0.2f
typedef unsigned int uint_t;
typedef unsigned short ushort_t;

static __device__ __forceinline__ float lrelu(float v) { return v > 0.f ? v : SLOPE * v; }
// float -> bf16 bits, round-to-nearest-even
static __device__ __forceinline__ ushort_t f2b(float f) {
  uint_t u = __float_as_uint(f);
  u += 0x7fffu + ((u >> 16) & 1u);
  return (ushort_t)(u >> 16);
}
// packed bf16x2 (as uint) -> float2 (v_cvt_pk_f32_bf16 path)
static __device__ __forceinline__ float2 b2x2(uint_t u) {
  union { uint_t u; __hip_bfloat162 b; } cv;
  cv.u = u;
  return __bfloat1622float2(cv.b);
}

// ================= CSR build: atomic-free MSD bucket sort by dst =================

__device__ __forceinline__ void hist_body(const int* __restrict__ ei, int* __restrict__ ts,
                                          int E, int N, int NB, int NBUCK, int b) {
  __shared__ int h[256];
  int tid = threadIdx.x;
  h[tid] = 0;
  __syncthreads();
  int ET = E + N;
  int base = b * 4096;
#pragma unroll
  for (int j = 0; j < 16; ++j) {
    int i = base + j * 256 + tid;
    if (i < ET) {
      int d = (i < E) ? ei[E + i] : (i - E);
      atomicAdd(&h[d >> 8], 1);
    }
  }
  __syncthreads();
  if (tid < NBUCK) ts[tid * NB + b] = h[tid];
}

__global__ __launch_bounds__(256) void scan1(int* __restrict__ a, int* __restrict__ bsum, int L) {
  int tid = threadIdx.x;
  int base = blockIdx.x * 1024 + tid * 4;
  int c0 = (base + 0 < L) ? a[base + 0] : 0;
  int c1 = (base + 1 < L) ? a[base + 1] : 0;
  int c2 = (base + 2 < L) ? a[base + 2] : 0;
  int c3 = (base + 3 < L) ? a[base + 3] : 0;
  int s = c0 + c1 + c2 + c3;
  int lane = tid & 63, wid = tid >> 6;
  int pre = s;
#pragma unroll
  for (int off = 1; off < 64; off <<= 1) {
    int t = __shfl_up(pre, off);
    if (lane >= off) pre += t;
  }
  __shared__ int wsum[4];
  if (lane == 63) wsum[wid] = pre;
  __syncthreads();
  int woff = 0;
#pragma unroll
  for (int w = 0; w < 4; ++w) woff += (w < wid) ? wsum[w] : 0;
  int excl = woff + pre - s;
  if (base + 0 < L) a[base + 0] = excl;
  if (base + 1 < L) a[base + 1] = excl + c0;
  if (base + 2 < L) a[base + 2] = excl + c0 + c1;
  if (base + 3 < L) a[base + 3] = excl + c0 + c1 + c2;
  if (tid == 255) bsum[blockIdx.x] = wsum[0] + wsum[1] + wsum[2] + wsum[3];
}

__global__ __launch_bounds__(1024) void scan2(int* __restrict__ bsum, int nb) {
  __shared__ int sh[1024];
  int tid = threadIdx.x;
  int v = (tid < nb) ? bsum[tid] : 0;
  sh[tid] = v;
  __syncthreads();
  for (int off = 1; off < 1024; off <<= 1) {
    int add = (tid >= off) ? sh[tid - off] : 0;
    __syncthreads();
    sh[tid] += add;
    __syncthreads();
  }
  if (tid < nb) bsum[tid] = sh[tid] - v;
}

// part/bucket apply the scan2 block offsets on the fly: scanned ts[i] = ts[i] + bsum[i>>10]

__global__ __launch_bounds__(256) void part_kernel(const int* __restrict__ ei,
                                                   const int* __restrict__ ts,
                                                   const int* __restrict__ bsum,
                                                   uint_t* __restrict__ tmp,
                                                   int E, int N, int NB, int NBUCK) {
  __shared__ int bin[256];
  int tid = threadIdx.x, b = blockIdx.x;
  if (tid < NBUCK) {
    int idx = tid * NB + b;
    bin[tid] = ts[idx] + bsum[idx >> 10];
  }
  __syncthreads();
  int ET = E + N;
  int base = b * 4096;
#pragma unroll
  for (int j = 0; j < 16; ++j) {
    int i = base + j * 256 + tid;
    if (i < ET) {
      int s, d;
      if (i < E) { s = ei[i]; d = ei[E + i]; } else { s = i - E; d = i - E; }
      int pos = atomicAdd(&bin[d >> 8], 1);
      tmp[pos] = ((uint_t)d << 16) | (uint_t)s;
    }
  }
}

__global__ __launch_bounds__(256) void bucket_kernel(const uint_t* __restrict__ tmp,
                                                     const int* __restrict__ ts,
                                                     const int* __restrict__ bsum,
                                                     int* __restrict__ rowptr,
                                                     int* __restrict__ esrc,
                                                     int N, int NB, int NBUCK, int ET) {
  __shared__ int h[256], pref[256], rank[256];
  __shared__ int wsum[4];
  int tid = threadIdx.x, d = blockIdx.x;
  int i0 = d * NB;
  int start = ts[i0] + bsum[i0 >> 10];
  int end = ET;
  if (d != NBUCK - 1) {
    int i1 = (d + 1) * NB;
    end = ts[i1] + bsum[i1 >> 10];
  }
  h[tid] = 0; rank[tid] = 0;
  __syncthreads();
  for (int i = start + tid; i < end; i += 256)
    atomicAdd(&h[(tmp[i] >> 16) & 255], 1);
  __syncthreads();
  int v = h[tid];
  int lane = tid & 63, wid = tid >> 6;
  int inc = v;
#pragma unroll
  for (int off = 1; off < 64; off <<= 1) {
    int t = __shfl_up(inc, off);
    if (lane >= off) inc += t;
  }
  if (lane == 63) wsum[wid] = inc;
  __syncthreads();
  int woff = 0;
#pragma unroll
  for (int w = 0; w < 4; ++w) woff += (w < wid) ? wsum[w] : 0;
  pref[tid] = woff + inc - v;
  __syncthreads();
  int idx = d * 256 + tid;
  if (idx <= N) rowptr[idx] = start + pref[tid];
  for (int i = start + tid; i < end; i += 256) {
    uint_t v2 = tmp[i];
    int low = (v2 >> 16) & 255;
    int r = atomicAdd(&rank[low], 1);
    esrc[start + pref[low] + r] = (int)(v2 & 0xffffu);
  }
}

// ========== GEMM + fused al projections: H(bf16) = X @ W; als/ald from fp32 acc ==========

template<int OC, bool BF16IN>
__device__ __forceinline__ void gemm_body(const void* __restrict__ Xv,
                                          const float* __restrict__ W,
                                          ushort_t* __restrict__ H,
                                          const float* __restrict__ a_s,
                                          const float* __restrict__ a_d,
                                          float* __restrict__ als,
                                          float* __restrict__ ald,
                                          int N, int bid) {
  const int K = 128;
  const int CT = OC / 4;             // 32 (OC=128) / 16 (OC=64)
  const int RPT = 64 / (256 / CT);   // 8 / 4
  __shared__ float xs[K][68];
  int tid = threadIdx.x;
  long row0 = (long)bid * 64;
  if (BF16IN) {
    const ushort_t* X = (const ushort_t*)Xv;
#pragma unroll
    for (int i = 0; i < 4; ++i) {
      int flat = i * 256 + tid;
      int r = flat & 63, kc = flat >> 6;
      long row = row0 + r;
      long rr = row < N ? row : (long)(N - 1);
      uint4 v = *(const uint4*)(X + rr * K + kc * 8);
      uint_t vv[4] = {v.x, v.y, v.z, v.w};
#pragma unroll
      for (int j = 0; j < 4; ++j) {
        float2 f = b2x2(vv[j]);
        xs[kc * 8 + j * 2 + 0][r] = f.x;
        xs[kc * 8 + j * 2 + 1][r] = f.y;
      }
    }
  } else {
    const float* X = (const float*)Xv;
#pragma unroll
    for (int i = 0; i < 8; ++i) {
      int flat = i * 256 + tid;
      int r = flat & 63, kc = flat >> 6;
      long row = row0 + r;
      long rr = row < N ? row : (long)(N - 1);
      float4 xv = *(const float4*)(X + rr * K + kc * 4);
      xs[kc * 4 + 0][r] = xv.x;
      xs[kc * 4 + 1][r] = xv.y;
      xs[kc * 4 + 2][r] = xv.z;
      xs[kc * 4 + 3][r] = xv.w;
    }
  }
  __syncthreads();
  int ct = tid % CT;
  int rg = tid / CT;
  int c0 = ct * 4;
  int r0 = rg * RPT;
  float acc[RPT][4];
#pragma unroll
  for (int i = 0; i < RPT; ++i)
    for (int j = 0; j < 4; ++j) acc[i][j] = 0.f;
#pragma unroll 4
  for (int k = 0; k < K; ++k) {
    float4 wv = *(const float4*)(W + (long)k * OC + c0);
    const float4* xr = (const float4*)(&xs[k][r0]);
#pragma unroll
    for (int i4 = 0; i4 < RPT / 4; ++i4) {
      float4 xv = xr[i4];
      float xa[4] = {xv.x, xv.y, xv.z, xv.w};
#pragma unroll
      for (int j = 0; j < 4; ++j) {
        int i = i4 * 4 + j;
        acc[i][0] = fmaf(xa[j], wv.x, acc[i][0]);
        acc[i][1] = fmaf(xa[j], wv.y, acc[i][1]);
        acc[i][2] = fmaf(xa[j], wv.z, acc[i][2]);
        acc[i][3] = fmaf(xa[j], wv.w, acc[i][3]);
      }
    }
  }
#pragma unroll
  for (int i = 0; i < RPT; ++i) {
    long row = row0 + r0 + i;
    if (row < N) {
      ushort4 o = {f2b(acc[i][0]), f2b(acc[i][1]), f2b(acc[i][2]), f2b(acc[i][3])};
      *(ushort4*)(H + row * OC + c0) = o;
    }
  }
  // fused al epilogue
  float4 sv = *(const float4*)(a_s + c0);
  float4 dv = *(const float4*)(a_d + c0);
  const int RED = (OC == 128) ? 4 : 8;
  const int GM  = (OC == 128) ? 7 : 15;
#pragma unroll
  for (int i = 0; i < RPT; ++i) {
    float ps = acc[i][0] * sv.x + acc[i][1] * sv.y + acc[i][2] * sv.z + acc[i][3] * sv.w;
    float pd = acc[i][0] * dv.x + acc[i][1] * dv.y + acc[i][2] * dv.z + acc[i][3] * dv.w;
#pragma unroll
    for (int off = 1; off <= RED; off <<= 1) {
      ps += __shfl_xor(ps, off);
      pd += __shfl_xor(pd, off);
    }
    long row = row0 + r0 + i;
    if ((ct & GM) == 0 && row < N) {
      if (OC == 128) {
        int head = c0 >> 5;
        als[row * 4 + head] = ps;
        ald[row * 4 + head] = pd;
      } else {
        als[row] = ps;
        ald[row] = pd;
      }
    }
  }
}

template<int OC, bool BF16IN>
__global__ __launch_bounds__(256) void gemm_tile(const void* __restrict__ Xv,
                                                 const float* __restrict__ W,
                                                 ushort_t* __restrict__ H,
                                                 const float* __restrict__ a_s,
                                                 const float* __restrict__ a_d,
                                                 float* __restrict__ als,
                                                 float* __restrict__ ald, int N) {
  gemm_body<OC, BF16IN>(Xv, W, H, a_s, a_d, als, ald, N, blockIdx.x);
}

__global__ __launch_bounds__(256) void k_gemm1_hist(const float* __restrict__ X,
    const float* __restrict__ W, ushort_t* __restrict__ H,
    const float* __restrict__ a_s, const float* __restrict__ a_d,
    float* __restrict__ als, float* __restrict__ ald, int N,
    const int* __restrict__ ei, int* __restrict__ ts, int E, int NB, int NBUCK,
    int gemmBlocks) {
  int bid = blockIdx.x;
  if (bid < gemmBlocks) gemm_body<128, false>(X, W, H, a_s, a_d, als, ald, N, bid);
  else hist_body(ei, ts, E, N, NB, NBUCK, bid - gemmBlocks);
}

// ===== softmax aggregation (m=0), half-wave/node, 16 feats/lane (VALU-lean) =====

// 4 heads x 32 feats. Node = 32 lanes: 4 slots x 8 lanes; lane covers feats
// [sl*16, sl*16+16), head = sl>>1. 8 nodes / 256-block.
__global__ __launch_bounds__(256) void gat_agg128(const ushort_t* __restrict__ h,
    const float* __restrict__ als, const float* __restrict__ ald,
    const int* __restrict__ rowptr, const int* __restrict__ esrc,
    const float* __restrict__ bias, ushort_t* __restrict__ out, int N) {
  int tid = threadIdx.x;
  int n = blockIdx.x * 8 + (tid >> 5);
  int l = tid & 31;
  int slot = l >> 3, sl = l & 7, hd = sl >> 1;
  if (n >= N) return;
  int beg = rowptr[n], end = rowptr[n + 1];
  float aldv = ald[(long)n * 4 + hd];
  float den = 0.f;
  float acc[16];
#pragma unroll
  for (int j = 0; j < 16; ++j) acc[j] = 0.f;
  for (int e = beg + slot; e < end; e += 4) {
    int s = esrc[e];
    float p = __expf(lrelu(als[(long)s * 4 + hd] + aldv));
    den += p;
    const ushort_t* hp = h + (long)s * 128 + sl * 16;
    uint4 v0 = *(const uint4*)(hp);
    uint4 v1 = *(const uint4*)(hp + 8);
    uint_t vv[8] = {v0.x, v0.y, v0.z, v0.w, v1.x, v1.y, v1.z, v1.w};
#pragma unroll
    for (int j = 0; j < 8; ++j) {
      float2 f = b2x2(vv[j]);
      acc[2 * j + 0] = fmaf(p, f.x, acc[2 * j + 0]);
      acc[2 * j + 1] = fmaf(p, f.y, acc[2 * j + 1]);
    }
  }
  // combine 4 slots: xor 8, 16 (stays within 32-lane node half)
  den += __shfl_xor(den, 8); den += __shfl_xor(den, 16);
#pragma unroll
  for (int j = 0; j < 16; ++j) {
    acc[j] += __shfl_xor(acc[j], 8);
    acc[j] += __shfl_xor(acc[j], 16);
  }
  if (slot == 0) {
    float inv = 1.f / den;
    uint_t pk[8];
#pragma unroll
    for (int j = 0; j < 8; ++j) {
      float v0 = fmaxf(fmaf(acc[2 * j + 0], inv, bias[sl * 16 + 2 * j + 0]), 0.f);
      float v1 = fmaxf(fmaf(acc[2 * j + 1], inv, bias[sl * 16 + 2 * j + 1]), 0.f);
      pk[j] = (uint_t)f2b(v0) | ((uint_t)f2b(v1) << 16);
    }
    uint4 o0 = {pk[0], pk[1], pk[2], pk[3]};
    uint4 o1 = {pk[4], pk[5], pk[6], pk[7]};
    *(uint4*)(out + (long)n * 128 + sl * 16 + 0) = o0;
    *(uint4*)(out + (long)n * 128 + sl * 16 + 8) = o1;
  }
}

// 1 head x 64 feats. Node = 32 lanes: 8 slots x 4 lanes; lane covers feats
// [sl*16, sl*16+16). Fused +bias + log_softmax, f32 out.
__global__ __launch_bounds__(256) void gat_agg64_lsm(const ushort_t* __restrict__ h,
    const float* __restrict__ als, const float* __restrict__ ald,
    const int* __restrict__ rowptr, const int* __restrict__ esrc,
    const float* __restrict__ bias, float* __restrict__ out, int N) {
  int tid = threadIdx.x;
  int n = blockIdx.x * 8 + (tid >> 5);
  int l = tid & 31;
  int slot = l >> 2, sl = l & 3;
  if (n >= N) return;
  int beg = rowptr[n], end = rowptr[n + 1];
  float aldv = ald[n];
  float den = 0.f;
  float acc[16];
#pragma unroll
  for (int j = 0; j < 16; ++j) acc[j] = 0.f;
  for (int e = beg + slot; e < end; e += 8) {
    int s = esrc[e];
    float p = __expf(lrelu(als[s] + aldv));
    den += p;
    const ushort_t* hp = h + (long)s * 64 + sl * 16;
    uint4 v0 = *(const uint4*)(hp);
    uint4 v1 = *(const uint4*)(hp + 8);
    uint_t vv[8] = {v0.x, v0.y, v0.z, v0.w, v1.x, v1.y, v1.z, v1.w};
#pragma unroll
    for (int j = 0; j < 8; ++j) {
      float2 f = b2x2(vv[j]);
      acc[2 * j + 0] = fmaf(p, f.x, acc[2 * j + 0]);
      acc[2 * j + 1] = fmaf(p, f.y, acc[2 * j + 1]);
    }
  }
  // combine 8 slots: xor 4, 8, 16
  den += __shfl_xor(den, 4); den += __shfl_xor(den, 8); den += __shfl_xor(den, 16);
#pragma unroll
  for (int j = 0; j < 16; ++j) {
    acc[j] += __shfl_xor(acc[j], 4);
    acc[j] += __shfl_xor(acc[j], 8);
    acc[j] += __shfl_xor(acc[j], 16);
  }
  if (slot == 0) {
    float inv = 1.f / den;
    float v[16];
#pragma unroll
    for (int j = 0; j < 16; ++j) v[j] = fmaf(acc[j], inv, bias[sl * 16 + j]);
    float lm = v[0];
#pragma unroll
    for (int j = 1; j < 16; ++j) lm = fmaxf(lm, v[j]);
    lm = fmaxf(lm, __shfl_xor(lm, 1));
    lm = fmaxf(lm, __shfl_xor(lm, 2));
    float es = 0.f;
#pragma unroll
    for (int j = 0; j < 16; ++j) es += __expf(v[j] - lm);
    es += __shfl_xor(es, 1);
    es += __shfl_xor(es, 2);
    float lse = lm + __logf(es);
    float* op = out + (long)n * 64 + sl * 16;
#pragma unroll
    for (int q = 0; q < 4; ++q) {
      float4 o = {v[4 * q + 0] - lse, v[4 * q + 1] - lse, v[4 * q + 2] - lse, v[4 * q + 3] - lse};
      *(float4*)(op + 4 * q) = o;
    }
  }
}

// ================= launch =================

extern "C" void kernel_launch(void* const* d_in, const int* in_sizes, int n_in,
                              void* d_out, int out_size, void* d_ws, size_t ws_size,
                              hipStream_t stream) {
  const float* x   = (const float*)d_in[0];
  const int*   ei  = (const int*)d_in[1];
  const float* w1  = (const float*)d_in[2];
  const float* as1 = (const float*)d_in[3];
  const float* ad1 = (const float*)d_in[4];
  const float* b1  = (const float*)d_in[5];
  const float* w2  = (const float*)d_in[6];
  const float* as2 = (const float*)d_in[7];
  const float* ad2 = (const float*)d_in[8];
  const float* b2  = (const float*)d_in[9];
  const float* w3  = (const float*)d_in[10];
  const float* as3 = (const float*)d_in[11];
  const float* ad3 = (const float*)d_in[12];
  const float* b3  = (const float*)d_in[13];
  float* out = (float*)d_out;

  const int N = in_sizes[0] / 128;
  const int E = in_sizes[1] / 2;
  const int ET = E + N;

  const int NB = (ET + 4095) / 4096;      // hist/part blocks
  const int NBUCK = (N + 255) >> 8;       // buckets (dst>>8)
  const int SL = NBUCK * NB;              // scan length
  const int nsb = (SL + 1023) / 1024;     // scan blocks

  char* ws = (char*)d_ws;
  size_t off = 0;
  auto alloc = [&](size_t bytes) -> void* {
    void* p = ws + off;
    off += (bytes + 255) & ~(size_t)255;
    return p;
  };
  ushort_t* bufA = (ushort_t*)alloc((size_t)N * 128 * 2);
  ushort_t* bufB = (ushort_t*)alloc((size_t)N * 128 * 2);
  float* als   = (float*)alloc((size_t)N * 4 * 4);
  float* ald   = (float*)alloc((size_t)N * 4 * 4);
  int* ts      = (int*)alloc((size_t)SL * 4);
  int* bsum    = (int*)alloc((size_t)1024 * 4);
  uint_t* tmp  = (uint_t*)alloc((size_t)ET * 4);
  int* rowptr  = (int*)alloc((size_t)(N + 1) * 4);
  int* esrc    = (int*)alloc((size_t)ET * 4);

  const int ggrid = (N + 63) / 64;
  const int aggrid = (N + 7) / 8;

  // 1. fused: gemm layer1 + al epilogue || histogram (independent)
  k_gemm1_hist<<<ggrid + NB, 256, 0, stream>>>(x, w1, bufA, as1, ad1, als, ald, N,
                                               ei, ts, E, NB, NBUCK, ggrid);
  // 2-3. scan of ts
  scan1<<<nsb, 256, 0, stream>>>(ts, bsum, SL);
  scan2<<<1, 1024, 0, stream>>>(bsum, nsb);
  // 4-5. partition + per-bucket counting sort
  part_kernel<<<NB, 256, 0, stream>>>(ei, ts, bsum, tmp, E, N, NB, NBUCK);
  bucket_kernel<<<NBUCK, 256, 0, stream>>>(tmp, ts, bsum, rowptr, esrc, N, NB, NBUCK, ET);

  // 6. layer 1 aggregation
  gat_agg128<<<aggrid, 256, 0, stream>>>(bufA, als, ald, rowptr, esrc, b1, bufB, N);

  // 7-8. layer 2
  gemm_tile<128, true><<<ggrid, 256, 0, stream>>>(bufB, w2, bufA, as2, ad2, als, ald, N);
  gat_agg128<<<aggrid, 256, 0, stream>>>(bufA, als, ald, rowptr, esrc, b2, bufB, N);

  // 9-10. layer 3
  gemm_tile<64, true><<<ggrid, 256, 0, stream>>>(bufB, w3, bufA, as3, ad3, als, ald, N);
  gat_agg64_lsm<<<aggrid, 256, 0, stream>>>(bufA, als, ald, rowptr, esrc, b3, out, N);
}

// Round 12
// 286.358 us; speedup vs baseline: 3.0283x; 1.0424x over previous
//
#include <hip/hip_runtime.h>
#include <hip/hip_bf16.h>
#include <math.h>

#define SLOPE 0.2f
typedef unsigned int uint_t;
typedef unsigned short ushort_t;
typedef __attribute__((ext_vector_type(8))) short short8;   // 8 bf16 (4 VGPRs)
typedef __attribute__((ext_vector_type(4))) float f32x4;    // MFMA accumulator

static __device__ __forceinline__ float lrelu(float v) { return v > 0.f ? v : SLOPE * v; }
static __device__ __forceinline__ ushort_t f2b(float f) {
  uint_t u = __float_as_uint(f);
  u += 0x7fffu + ((u >> 16) & 1u);
  return (ushort_t)(u >> 16);
}
static __device__ __forceinline__ float2 b2x2(uint_t u) {
  union { uint_t u; __hip_bfloat162 b; } cv;
  cv.u = u;
  return __bfloat1622float2(cv.b);
}

// ================= CSR build: atomic-free MSD bucket sort by dst =================

__device__ __forceinline__ void hist_body(const int* __restrict__ ei, int* __restrict__ ts,
                                          int E, int N, int NB, int NBUCK, int b) {
  __shared__ int h[256];
  int tid = threadIdx.x;
  h[tid] = 0;
  __syncthreads();
  int ET = E + N;
  int base = b * 4096;
#pragma unroll
  for (int j = 0; j < 16; ++j) {
    int i = base + j * 256 + tid;
    if (i < ET) {
      int d = (i < E) ? ei[E + i] : (i - E);
      atomicAdd(&h[d >> 8], 1);
    }
  }
  __syncthreads();
  if (tid < NBUCK) ts[tid * NB + b] = h[tid];
}

__global__ __launch_bounds__(256) void scan1(int* __restrict__ a, int* __restrict__ bsum, int L) {
  int tid = threadIdx.x;
  int base = blockIdx.x * 1024 + tid * 4;
  int c0 = (base + 0 < L) ? a[base + 0] : 0;
  int c1 = (base + 1 < L) ? a[base + 1] : 0;
  int c2 = (base + 2 < L) ? a[base + 2] : 0;
  int c3 = (base + 3 < L) ? a[base + 3] : 0;
  int s = c0 + c1 + c2 + c3;
  int lane = tid & 63, wid = tid >> 6;
  int pre = s;
#pragma unroll
  for (int off = 1; off < 64; off <<= 1) {
    int t = __shfl_up(pre, off);
    if (lane >= off) pre += t;
  }
  __shared__ int wsum[4];
  if (lane == 63) wsum[wid] = pre;
  __syncthreads();
  int woff = 0;
#pragma unroll
  for (int w = 0; w < 4; ++w) woff += (w < wid) ? wsum[w] : 0;
  int excl = woff + pre - s;
  if (base + 0 < L) a[base + 0] = excl;
  if (base + 1 < L) a[base + 1] = excl + c0;
  if (base + 2 < L) a[base + 2] = excl + c0 + c1;
  if (base + 3 < L) a[base + 3] = excl + c0 + c1 + c2;
  if (tid == 255) bsum[blockIdx.x] = wsum[0] + wsum[1] + wsum[2] + wsum[3];
}

__global__ __launch_bounds__(1024) void scan2(int* __restrict__ bsum, int nb) {
  __shared__ int sh[1024];
  int tid = threadIdx.x;
  int v = (tid < nb) ? bsum[tid] : 0;
  sh[tid] = v;
  __syncthreads();
  for (int off = 1; off < 1024; off <<= 1) {
    int add = (tid >= off) ? sh[tid - off] : 0;
    __syncthreads();
    sh[tid] += add;
    __syncthreads();
  }
  if (tid < nb) bsum[tid] = sh[tid] - v;
}

__global__ __launch_bounds__(256) void part_kernel(const int* __restrict__ ei,
                                                   const int* __restrict__ ts,
                                                   const int* __restrict__ bsum,
                                                   uint_t* __restrict__ tmp,
                                                   int E, int N, int NB, int NBUCK) {
  __shared__ int bin[256];
  int tid = threadIdx.x, b = blockIdx.x;
  if (tid < NBUCK) {
    int idx = tid * NB + b;
    bin[tid] = ts[idx] + bsum[idx >> 10];
  }
  __syncthreads();
  int ET = E + N;
  int base = b * 4096;
#pragma unroll
  for (int j = 0; j < 16; ++j) {
    int i = base + j * 256 + tid;
    if (i < ET) {
      int s, d;
      if (i < E) { s = ei[i]; d = ei[E + i]; } else { s = i - E; d = i - E; }
      int pos = atomicAdd(&bin[d >> 8], 1);
      tmp[pos] = ((uint_t)d << 16) | (uint_t)s;
    }
  }
}

__global__ __launch_bounds__(256) void bucket_kernel(const uint_t* __restrict__ tmp,
                                                     const int* __restrict__ ts,
                                                     const int* __restrict__ bsum,
                                                     int* __restrict__ rowptr,
                                                     int* __restrict__ esrc,
                                                     int N, int NB, int NBUCK, int ET) {
  __shared__ int h[256], pref[256], rank[256];
  __shared__ int wsum[4];
  int tid = threadIdx.x, d = blockIdx.x;
  int i0 = d * NB;
  int start = ts[i0] + bsum[i0 >> 10];
  int end = ET;
  if (d != NBUCK - 1) {
    int i1 = (d + 1) * NB;
    end = ts[i1] + bsum[i1 >> 10];
  }
  h[tid] = 0; rank[tid] = 0;
  __syncthreads();
  for (int i = start + tid; i < end; i += 256)
    atomicAdd(&h[(tmp[i] >> 16) & 255], 1);
  __syncthreads();
  int v = h[tid];
  int lane = tid & 63, wid = tid >> 6;
  int inc = v;
#pragma unroll
  for (int off = 1; off < 64; off <<= 1) {
    int t = __shfl_up(inc, off);
    if (lane >= off) inc += t;
  }
  if (lane == 63) wsum[wid] = inc;
  __syncthreads();
  int woff = 0;
#pragma unroll
  for (int w = 0; w < 4; ++w) woff += (w < wid) ? wsum[w] : 0;
  pref[tid] = woff + inc - v;
  __syncthreads();
  int idx = d * 256 + tid;
  if (idx <= N) rowptr[idx] = start + pref[tid];
  for (int i = start + tid; i < end; i += 256) {
    uint_t v2 = tmp[i];
    int low = (v2 >> 16) & 255;
    int r = atomicAdd(&rank[low], 1);
    esrc[start + pref[low] + r] = (int)(v2 & 0xffffu);
  }
}

// ========== layer-1 GEMM (fp32 X, vector ALU) + fused al epilogue ==========

__device__ __forceinline__ void gemm1_body(const float* __restrict__ X,
                                           const float* __restrict__ W,
                                           ushort_t* __restrict__ H,
                                           const float* __restrict__ a_s,
                                           const float* __restrict__ a_d,
                                           float* __restrict__ als,
                                           float* __restrict__ ald,
                                           int N, int bid) {
  const int K = 128;
  const int OC = 128;
  const int CT = 32;
  const int RPT = 8;
  __shared__ float xs[K][68];
  int tid = threadIdx.x;
  long row0 = (long)bid * 64;
#pragma unroll
  for (int i = 0; i < 8; ++i) {
    int flat = i * 256 + tid;
    int r = flat & 63, kc = flat >> 6;
    long row = row0 + r;
    long rr = row < N ? row : (long)(N - 1);
    float4 xv = *(const float4*)(X + rr * K + kc * 4);
    xs[kc * 4 + 0][r] = xv.x;
    xs[kc * 4 + 1][r] = xv.y;
    xs[kc * 4 + 2][r] = xv.z;
    xs[kc * 4 + 3][r] = xv.w;
  }
  __syncthreads();
  int ct = tid % CT;
  int rg = tid / CT;
  int c0 = ct * 4;
  int r0 = rg * RPT;
  float acc[RPT][4];
#pragma unroll
  for (int i = 0; i < RPT; ++i)
    for (int j = 0; j < 4; ++j) acc[i][j] = 0.f;
#pragma unroll 4
  for (int k = 0; k < K; ++k) {
    float4 wv = *(const float4*)(W + (long)k * OC + c0);
    const float4* xr = (const float4*)(&xs[k][r0]);
#pragma unroll
    for (int i4 = 0; i4 < RPT / 4; ++i4) {
      float4 xv = xr[i4];
      float xa[4] = {xv.x, xv.y, xv.z, xv.w};
#pragma unroll
      for (int j = 0; j < 4; ++j) {
        int i = i4 * 4 + j;
        acc[i][0] = fmaf(xa[j], wv.x, acc[i][0]);
        acc[i][1] = fmaf(xa[j], wv.y, acc[i][1]);
        acc[i][2] = fmaf(xa[j], wv.z, acc[i][2]);
        acc[i][3] = fmaf(xa[j], wv.w, acc[i][3]);
      }
    }
  }
#pragma unroll
  for (int i = 0; i < RPT; ++i) {
    long row = row0 + r0 + i;
    if (row < N) {
      ushort4 o = {f2b(acc[i][0]), f2b(acc[i][1]), f2b(acc[i][2]), f2b(acc[i][3])};
      *(ushort4*)(H + row * OC + c0) = o;
    }
  }
  float4 sv = *(const float4*)(a_s + c0);
  float4 dv = *(const float4*)(a_d + c0);
#pragma unroll
  for (int i = 0; i < RPT; ++i) {
    float ps = acc[i][0] * sv.x + acc[i][1] * sv.y + acc[i][2] * sv.z + acc[i][3] * sv.w;
    float pd = acc[i][0] * dv.x + acc[i][1] * dv.y + acc[i][2] * dv.z + acc[i][3] * dv.w;
#pragma unroll
    for (int off = 1; off <= 4; off <<= 1) {
      ps += __shfl_xor(ps, off);
      pd += __shfl_xor(pd, off);
    }
    long row = row0 + r0 + i;
    if ((ct & 7) == 0 && row < N) {
      int head = c0 >> 5;
      als[row * 4 + head] = ps;
      ald[row * 4 + head] = pd;
    }
  }
}

// WT prep: WT[c][k] (bf16) from W[k][c] (f32). 3 blocks x 8192 elems cover w2+w3.
__device__ __forceinline__ void wprep_body(const float* __restrict__ w2,
                                           const float* __restrict__ w3,
                                           ushort_t* __restrict__ wt2,
                                           ushort_t* __restrict__ wt3, int b) {
  int tid = threadIdx.x;
#pragma unroll
  for (int j = 0; j < 32; ++j) {
    int idx = b * 8192 + j * 256 + tid;
    if (idx < 16384) {                 // w2: 128x128
      int c = idx & 127, k = idx >> 7;
      wt2[c * 128 + k] = f2b(w2[idx]);
    } else if (idx < 24576) {          // w3: 128x64
      int i2 = idx - 16384;
      int c = i2 & 63, k = i2 >> 6;
      wt3[c * 128 + k] = f2b(w3[i2]);
    }
  }
}

// fused: gemm layer1 || histogram || WT prep (all independent)
__global__ __launch_bounds__(256) void k_gemm1_hist(const float* __restrict__ X,
    const float* __restrict__ W, ushort_t* __restrict__ H,
    const float* __restrict__ a_s, const float* __restrict__ a_d,
    float* __restrict__ als, float* __restrict__ ald, int N,
    const int* __restrict__ ei, int* __restrict__ ts, int E, int NB, int NBUCK,
    const float* __restrict__ w2, const float* __restrict__ w3,
    ushort_t* __restrict__ wt2, ushort_t* __restrict__ wt3,
    int gemmBlocks) {
  int bid = blockIdx.x;
  if (bid < gemmBlocks) gemm1_body(X, W, H, a_s, a_d, als, ald, N, bid);
  else if (bid < gemmBlocks + NB) hist_body(ei, ts, E, N, NB, NBUCK, bid - gemmBlocks);
  else wprep_body(w2, w3, wt2, wt3, bid - gemmBlocks - NB);
}

// ========== layer-2/3 GEMM: MFMA bf16, fused al epilogue ==========
// H[N,OC] = X[N,128](bf16) @ W(bf16, pre-transposed WT[OC][128]).
// Block 256 = 4 waves, 64 rows; wave = 16 rows x OC cols.
// A-operand = WT tile (A[m=lane&15][k=q*8+j]); B-operand = X rows from LDS
// (B[k=q*8+j][n=lane&15]); C/D: row(m)=q*4+reg, col(n)=lane&15 [m89].
// => lane holds 4 consecutive out-features (m = t*16+q*4+reg) of X-row n.

template<int OC>
__global__ __launch_bounds__(256) void mfma_gemm(const ushort_t* __restrict__ X,
    const ushort_t* __restrict__ WT, ushort_t* __restrict__ H,
    const float* __restrict__ a_s, const float* __restrict__ a_d,
    float* __restrict__ als, float* __restrict__ ald, int N) {
  const int K = 128;
  const int P = 136;                  // LDS stride (bf16 elems); 2-way conflict only
  const int MT = OC / 16;             // m-tiles: 8 (OC=128) / 4 (OC=64)
  __shared__ ushort_t xs[64 * P];
  int tid = threadIdx.x;
  long row0 = (long)blockIdx.x * 64;
  // stage X tile (64 x 128 bf16), uint4 = 8 elems
#pragma unroll
  for (int i = 0; i < 4; ++i) {
    int flat = i * 256 + tid;
    int r = flat & 63, kc = flat >> 6;
    long row = row0 + r;
    long rr = row < N ? row : (long)(N - 1);
    uint4 v = *(const uint4*)(X + rr * K + kc * 8);
    *(uint4*)(xs + r * P + kc * 8) = v;
  }
  __syncthreads();
  int wave = tid >> 6, lane = tid & 63;
  int n = lane & 15, q = lane >> 4;
  int wrow = wave * 16 + n;
  f32x4 acc[MT];
#pragma unroll
  for (int t = 0; t < MT; ++t) acc[t] = (f32x4){0.f, 0.f, 0.f, 0.f};
#pragma unroll
  for (int kk = 0; kk < 4; ++kk) {
    short8 bfrag = *(const short8*)(xs + wrow * P + kk * 32 + q * 8);
#pragma unroll
    for (int t = 0; t < MT; ++t) {
      short8 afrag = *(const short8*)(WT + (t * 16 + n) * K + kk * 32 + q * 8);
      acc[t] = __builtin_amdgcn_mfma_f32_16x16x32_bf16(afrag, bfrag, acc[t], 0, 0, 0);
    }
  }
  long grow = row0 + wrow;
  bool valid = grow < N;
  float ps[4] = {0.f, 0.f, 0.f, 0.f};
  float pd[4] = {0.f, 0.f, 0.f, 0.f};
#pragma unroll
  for (int t = 0; t < MT; ++t) {
    int fb = t * 16 + q * 4;          // first of 4 consecutive features
    if (valid) {
      uint_t lo = (uint_t)f2b(acc[t][0]) | ((uint_t)f2b(acc[t][1]) << 16);
      uint_t hi = (uint_t)f2b(acc[t][2]) | ((uint_t)f2b(acc[t][3]) << 16);
      uint2 pk = {lo, hi};
      *(uint2*)(H + grow * OC + fb) = pk;
    }
    float4 sv = *(const float4*)(a_s + fb);
    float4 dv = *(const float4*)(a_d + fb);
    int hidx = (OC == 128) ? (t >> 1) : 0;
    ps[hidx] += acc[t][0] * sv.x + acc[t][1] * sv.y + acc[t][2] * sv.z + acc[t][3] * sv.w;
    pd[hidx] += acc[t][0] * dv.x + acc[t][1] * dv.y + acc[t][2] * dv.z + acc[t][3] * dv.w;
  }
  const int NH = (OC == 128) ? 4 : 1;
#pragma unroll
  for (int h = 0; h < NH; ++h) {
    ps[h] += __shfl_xor(ps[h], 16); ps[h] += __shfl_xor(ps[h], 32);
    pd[h] += __shfl_xor(pd[h], 16); pd[h] += __shfl_xor(pd[h], 32);
  }
  if (q == 0 && valid) {
    if (OC == 128) {
      float4 s4 = {ps[0], ps[1], ps[2], ps[3]};
      float4 d4 = {pd[0], pd[1], pd[2], pd[3]};
      *(float4*)(als + grow * 4) = s4;
      *(float4*)(ald + grow * 4) = d4;
    } else {
      als[grow] = ps[0];
      ald[grow] = pd[0];
    }
  }
}

// ===== softmax aggregation (m=0), half-wave/node, 16 feats/lane =====

__global__ __launch_bounds__(256) void gat_agg128(const ushort_t* __restrict__ h,
    const float* __restrict__ als, const float* __restrict__ ald,
    const int* __restrict__ rowptr, const int* __restrict__ esrc,
    const float* __restrict__ bias, ushort_t* __restrict__ out, int N) {
  int tid = threadIdx.x;
  int n = blockIdx.x * 8 + (tid >> 5);
  int l = tid & 31;
  int slot = l >> 3, sl = l & 7, hd = sl >> 1;
  if (n >= N) return;
  int beg = rowptr[n], end = rowptr[n + 1];
  float aldv = ald[(long)n * 4 + hd];
  float den = 0.f;
  float acc[16];
#pragma unroll
  for (int j = 0; j < 16; ++j) acc[j] = 0.f;
  for (int e = beg + slot; e < end; e += 4) {
    int s = esrc[e];
    float p = __expf(lrelu(als[(long)s * 4 + hd] + aldv));
    den += p;
    const ushort_t* hp = h + (long)s * 128 + sl * 16;
    uint4 v0 = *(const uint4*)(hp);
    uint4 v1 = *(const uint4*)(hp + 8);
    uint_t vv[8] = {v0.x, v0.y, v0.z, v0.w, v1.x, v1.y, v1.z, v1.w};
#pragma unroll
    for (int j = 0; j < 8; ++j) {
      float2 f = b2x2(vv[j]);
      acc[2 * j + 0] = fmaf(p, f.x, acc[2 * j + 0]);
      acc[2 * j + 1] = fmaf(p, f.y, acc[2 * j + 1]);
    }
  }
  den += __shfl_xor(den, 8); den += __shfl_xor(den, 16);
#pragma unroll
  for (int j = 0; j < 16; ++j) {
    acc[j] += __shfl_xor(acc[j], 8);
    acc[j] += __shfl_xor(acc[j], 16);
  }
  if (slot == 0) {
    float inv = 1.f / den;
    uint_t pk[8];
#pragma unroll
    for (int j = 0; j < 8; ++j) {
      float v0 = fmaxf(fmaf(acc[2 * j + 0], inv, bias[sl * 16 + 2 * j + 0]), 0.f);
      float v1 = fmaxf(fmaf(acc[2 * j + 1], inv, bias[sl * 16 + 2 * j + 1]), 0.f);
      pk[j] = (uint_t)f2b(v0) | ((uint_t)f2b(v1) << 16);
    }
    uint4 o0 = {pk[0], pk[1], pk[2], pk[3]};
    uint4 o1 = {pk[4], pk[5], pk[6], pk[7]};
    *(uint4*)(out + (long)n * 128 + sl * 16 + 0) = o0;
    *(uint4*)(out + (long)n * 128 + sl * 16 + 8) = o1;
  }
}

__global__ __launch_bounds__(256) void gat_agg64_lsm(const ushort_t* __restrict__ h,
    const float* __restrict__ als, const float* __restrict__ ald,
    const int* __restrict__ rowptr, const int* __restrict__ esrc,
    const float* __restrict__ bias, float* __restrict__ out, int N) {
  int tid = threadIdx.x;
  int n = blockIdx.x * 8 + (tid >> 5);
  int l = tid & 31;
  int slot = l >> 2, sl = l & 3;
  if (n >= N) return;
  int beg = rowptr[n], end = rowptr[n + 1];
  float aldv = ald[n];
  float den = 0.f;
  float acc[16];
#pragma unroll
  for (int j = 0; j < 16; ++j) acc[j] = 0.f;
  for (int e = beg + slot; e < end; e += 8) {
    int s = esrc[e];
    float p = __expf(lrelu(als[s] + aldv));
    den += p;
    const ushort_t* hp = h + (long)s * 64 + sl * 16;
    uint4 v0 = *(const uint4*)(hp);
    uint4 v1 = *(const uint4*)(hp + 8);
    uint_t vv[8] = {v0.x, v0.y, v0.z, v0.w, v1.x, v1.y, v1.z, v1.w};
#pragma unroll
    for (int j = 0; j < 8; ++j) {
      float2 f = b2x2(vv[j]);
      acc[2 * j + 0] = fmaf(p, f.x, acc[2 * j + 0]);
      acc[2 * j + 1] = fmaf(p, f.y, acc[2 * j + 1]);
    }
  }
  den += __shfl_xor(den, 4); den += __shfl_xor(den, 8); den += __shfl_xor(den, 16);
#pragma unroll
  for (int j = 0; j < 16; ++j) {
    acc[j] += __shfl_xor(acc[j], 4);
    acc[j] += __shfl_xor(acc[j], 8);
    acc[j] += __shfl_xor(acc[j], 16);
  }
  if (slot == 0) {
    float inv = 1.f / den;
    float v[16];
#pragma unroll
    for (int j = 0; j < 16; ++j) v[j] = fmaf(acc[j], inv, bias[sl * 16 + j]);
    float lm = v[0];
#pragma unroll
    for (int j = 1; j < 16; ++j) lm = fmaxf(lm, v[j]);
    lm = fmaxf(lm, __shfl_xor(lm, 1));
    lm = fmaxf(lm, __shfl_xor(lm, 2));
    float es = 0.f;
#pragma unroll
    for (int j = 0; j < 16; ++j) es += __expf(v[j] - lm);
    es += __shfl_xor(es, 1);
    es += __shfl_xor(es, 2);
    float lse = lm + __logf(es);
    float* op = out + (long)n * 64 + sl * 16;
#pragma unroll
    for (int qq = 0; qq < 4; ++qq) {
      float4 o = {v[4 * qq + 0] - lse, v[4 * qq + 1] - lse, v[4 * qq + 2] - lse, v[4 * qq + 3] - lse};
      *(float4*)(op + 4 * qq) = o;
    }
  }
}

// ================= launch =================

extern "C" void kernel_launch(void* const* d_in, const int* in_sizes, int n_in,
                              void* d_out, int out_size, void* d_ws, size_t ws_size,
                              hipStream_t stream) {
  const float* x   = (const float*)d_in[0];
  const int*   ei  = (const int*)d_in[1];
  const float* w1  = (const float*)d_in[2];
  const float* as1 = (const float*)d_in[3];
  const float* ad1 = (const float*)d_in[4];
  const float* b1  = (const float*)d_in[5];
  const float* w2  = (const float*)d_in[6];
  const float* as2 = (const float*)d_in[7];
  const float* ad2 = (const float*)d_in[8];
  const float* b2  = (const float*)d_in[9];
  const float* w3  = (const float*)d_in[10];
  const float* as3 = (const float*)d_in[11];
  const float* ad3 = (const float*)d_in[12];
  const float* b3  = (const float*)d_in[13];
  float* out = (float*)d_out;

  const int N = in_sizes[0] / 128;
  const int E = in_sizes[1] / 2;
  const int ET = E + N;

  const int NB = (ET + 4095) / 4096;      // hist/part blocks
  const int NBUCK = (N + 255) >> 8;       // buckets (dst>>8)
  const int SL = NBUCK * NB;              // scan length
  const int nsb = (SL + 1023) / 1024;     // scan blocks

  char* ws = (char*)d_ws;
  size_t off = 0;
  auto alloc = [&](size_t bytes) -> void* {
    void* p = ws + off;
    off += (bytes + 255) & ~(size_t)255;
    return p;
  };
  ushort_t* bufA = (ushort_t*)alloc((size_t)N * 128 * 2);
  ushort_t* bufB = (ushort_t*)alloc((size_t)N * 128 * 2);
  float* als   = (float*)alloc((size_t)N * 4 * 4);
  float* ald   = (float*)alloc((size_t)N * 4 * 4);
  int* ts      = (int*)alloc((size_t)SL * 4);
  int* bsum    = (int*)alloc((size_t)1024 * 4);
  uint_t* tmp  = (uint_t*)alloc((size_t)ET * 4);
  int* rowptr  = (int*)alloc((size_t)(N + 1) * 4);
  int* esrc    = (int*)alloc((size_t)ET * 4);
  ushort_t* wt2 = (ushort_t*)alloc((size_t)128 * 128 * 2);
  ushort_t* wt3 = (ushort_t*)alloc((size_t)64 * 128 * 2);

  const int ggrid = (N + 63) / 64;
  const int aggrid = (N + 7) / 8;

  // 1. fused: gemm layer1 + al epilogue || histogram || WT prep
  k_gemm1_hist<<<ggrid + NB + 3, 256, 0, stream>>>(x, w1, bufA, as1, ad1, als, ald, N,
                                                   ei, ts, E, NB, NBUCK,
                                                   w2, w3, wt2, wt3, ggrid);
  // 2-3. scan of ts
  scan1<<<nsb, 256, 0, stream>>>(ts, bsum, SL);
  scan2<<<1, 1024, 0, stream>>>(bsum, nsb);
  // 4-5. partition + per-bucket counting sort
  part_kernel<<<NB, 256, 0, stream>>>(ei, ts, bsum, tmp, E, N, NB, NBUCK);
  bucket_kernel<<<NBUCK, 256, 0, stream>>>(tmp, ts, bsum, rowptr, esrc, N, NB, NBUCK, ET);

  // 6. layer 1 aggregation
  gat_agg128<<<aggrid, 256, 0, stream>>>(bufA, als, ald, rowptr, esrc, b1, bufB, N);

  // 7-8. layer 2 (MFMA gemm + fused al)
  mfma_gemm<128><<<ggrid, 256, 0, stream>>>(bufB, wt2, bufA, as2, ad2, als, ald, N);
  gat_agg128<<<aggrid, 256, 0, stream>>>(bufA, als, ald, rowptr, esrc, b2, bufB, N);

  // 9-10. layer 3 (MFMA gemm + fused al)
  mfma_gemm<64><<<ggrid, 256, 0, stream>>>(bufB, wt3, bufA, as3, ad3, als, ald, N);
  gat_agg64_lsm<<<aggrid, 256, 0, stream>>>(bufA, als, ald, rowptr, esrc, b3, out, N);
}